// Round 1
// baseline (901.273 us; speedup 1.0000x reference)
//
#include <hip/hip_runtime.h>
#include <stdint.h>

#define NODES  50000
#define MPAD   50048      // 391 * 128
#define NGRAPH 8
#define NP_G   6250
#define EDGES  800000
#define KKEEP  5000
#define HID    256
#define CIN    512
#define H3     768

using f32x4  = __attribute__((ext_vector_type(4))) float;
using bf16x8 = __attribute__((ext_vector_type(8))) short;
typedef unsigned short u16;

__device__ __forceinline__ float bf2f(u16 u) {
    return __uint_as_float(((uint32_t)u) << 16);
}
__device__ __forceinline__ u16 f2bf(float f) {     // RNE
    uint32_t u = __float_as_uint(f);
    u += 0x7fffu + ((u >> 16) & 1u);
    return (u16)(u >> 16);
}

// ---------------- casts ----------------
__global__ void cast_x_kernel(const float* __restrict__ x, u16* __restrict__ A0) {
    size_t i4 = (size_t)blockIdx.x * blockDim.x + threadIdx.x;
    size_t base = i4 * 4;
    if (base >= (size_t)MPAD * CIN) return;
    int row = (int)(base >> 9);   // /512
    ushort4 o;
    if (row < NODES) {
        float4 v = *(const float4*)(x + base);
        o.x = f2bf(v.x); o.y = f2bf(v.y); o.z = f2bf(v.z); o.w = f2bf(v.w);
    } else {
        o.x = 0; o.y = 0; o.z = 0; o.w = 0;
    }
    *(ushort4*)(A0 + base) = o;
}

// W [K,N] f32 -> Wt [N,K] bf16
__global__ void cast_w_kernel(const float* __restrict__ W, u16* __restrict__ Wt,
                              int K, int N) {
    int id = blockIdx.x * blockDim.x + threadIdx.x;
    if (id >= N * K) return;
    int n = id / K, k = id - n * K;
    Wt[id] = f2bf(W[(size_t)k * N + n]);
}

__global__ void pwnorm_kernel(const float* __restrict__ pw, float* __restrict__ invn) {
    __shared__ float sh[256];
    int t = threadIdx.x;
    float s = 0.f;
    for (int i = t; i < H3; i += 256) { float v = pw[i]; s += v * v; }
    sh[t] = s; __syncthreads();
    for (int off = 128; off; off >>= 1) {
        if (t < off) sh[t] += sh[t + off];
        __syncthreads();
    }
    if (t == 0) invn[0] = rsqrtf(sh[0]);
}

// ---------------- graph prep ----------------
__global__ void edge_pass1(const int* __restrict__ ei, const float* __restrict__ ew,
                           float* __restrict__ deg, int* __restrict__ cnt) {
    int e = blockIdx.x * blockDim.x + threadIdx.x;
    if (e >= EDGES) return;
    int d = ei[EDGES + e];
    atomicAdd(&deg[d], ew[e]);
    atomicAdd(&cnt[d], 1);
}

__global__ void dinv_kernel(const float* __restrict__ deg, float* __restrict__ dinv) {
    int n = blockIdx.x * blockDim.x + threadIdx.x;
    if (n >= NODES) return;
    dinv[n] = rsqrtf(deg[n] + 1.0f);
}

__global__ __launch_bounds__(1024) void scan_kernel(const int* __restrict__ cnt,
                                                    int* __restrict__ rowptr) {
    __shared__ int sh[1024];
    int t = threadIdx.x;
    int base = t * 49;
    int end = base + 49; if (end > NODES) end = NODES;
    int s = 0;
    for (int i = base; i < end; ++i) s += cnt[i];
    sh[t] = s; __syncthreads();
    for (int off = 1; off < 1024; off <<= 1) {
        int v = 0;
        if (t >= off) v = sh[t - off];
        __syncthreads();
        if (t >= off) sh[t] += v;
        __syncthreads();
    }
    int run = (t == 0) ? 0 : sh[t - 1];
    for (int i = base; i < end; ++i) { rowptr[i] = run; run += cnt[i]; }
    if (t == 0) rowptr[NODES] = EDGES;
}

__global__ void fill_kernel(const int* __restrict__ ei, const float* __restrict__ ew,
                            const float* __restrict__ dinv, const int* __restrict__ rowptr,
                            int* __restrict__ cur, int* __restrict__ col,
                            float* __restrict__ nrm) {
    int e = blockIdx.x * blockDim.x + threadIdx.x;
    if (e >= EDGES) return;
    int s = ei[e], d = ei[EDGES + e];
    int pos = rowptr[d] + atomicAdd(&cur[d], 1);
    col[pos] = s;
    nrm[pos] = dinv[s] * ew[e] * dinv[d];
}

// ---------------- GEMM: C[M,N] = A[M,K] @ Bt[N,K]^T  (all bf16, fp32 acc) ---------
__global__ __launch_bounds__(256) void gemm_bt(const u16* __restrict__ A,
                                               const u16* __restrict__ Bt,
                                               u16* __restrict__ C,
                                               int M, int N, int K) {
    __shared__ u16 As[128 * 32];
    __shared__ u16 Bs[128 * 32];
    const int tid  = threadIdx.x;
    const int wave = tid >> 6, lane = tid & 63;
    const int wm = wave >> 1, wn = wave & 1;       // 2x2 waves over 128x128
    const int quad = lane >> 4, l16 = lane & 15;
    const int bm = blockIdx.x, bn = blockIdx.y;

    const int sr = tid >> 2;                        // staging row 0..63 (+64 second)
    const int sc = tid & 3;                         // 16B chunk within 64B row
    const int swz = (sc ^ ((sr >> 1) & 3)) * 8;     // (sr+64)>>1 has same low bits
    const int rphys = (quad ^ ((l16 >> 1) & 3)) * 8;

    const u16* Ag = A + (size_t)(bm * 128 + sr) * K + sc * 8;
    const u16* Bg = Bt + (size_t)(bn * 128 + sr) * K + sc * 8;

    f32x4 acc[4][4];
#pragma unroll
    for (int i = 0; i < 4; i++)
#pragma unroll
        for (int j = 0; j < 4; j++) { f32x4 z = {0.f, 0.f, 0.f, 0.f}; acc[i][j] = z; }

    for (int k0 = 0; k0 < K; k0 += 32) {
        int4 av0 = *(const int4*)(Ag + k0);
        int4 av1 = *(const int4*)(Ag + (size_t)64 * K + k0);
        int4 bv0 = *(const int4*)(Bg + k0);
        int4 bv1 = *(const int4*)(Bg + (size_t)64 * K + k0);
        __syncthreads();
        *(int4*)(As + sr * 32 + swz)        = av0;
        *(int4*)(As + (sr + 64) * 32 + swz) = av1;
        *(int4*)(Bs + sr * 32 + swz)        = bv0;
        *(int4*)(Bs + (sr + 64) * 32 + swz) = bv1;
        __syncthreads();
        bf16x8 af[4], bfr[4];
#pragma unroll
        for (int i = 0; i < 4; i++)
            af[i] = *(const bf16x8*)(As + (wm * 64 + i * 16 + l16) * 32 + rphys);
#pragma unroll
        for (int j = 0; j < 4; j++)
            bfr[j] = *(const bf16x8*)(Bs + (wn * 64 + j * 16 + l16) * 32 + rphys);
#pragma unroll
        for (int i = 0; i < 4; i++)
#pragma unroll
            for (int j = 0; j < 4; j++)
                acc[i][j] = __builtin_amdgcn_mfma_f32_16x16x32_bf16(af[i], bfr[j], acc[i][j], 0, 0, 0);
    }

    const int crow0 = bm * 128 + wm * 64 + quad * 4;
    const int ccol0 = bn * 128 + wn * 64 + l16;
#pragma unroll
    for (int i = 0; i < 4; i++)
#pragma unroll
        for (int j = 0; j < 4; j++)
#pragma unroll
            for (int r = 0; r < 4; r++)
                C[(size_t)(crow0 + i * 16 + r) * N + ccol0 + j * 16] = f2bf(acc[i][j][r]);
}

// ---------------- aggregation: one wave per node ----------------
__global__ void agg_kernel(const u16* __restrict__ xw, u16* __restrict__ xo,
                           const int* __restrict__ rowptr, const int* __restrict__ col,
                           const float* __restrict__ nrm, const float* __restrict__ dinv,
                           const float* __restrict__ bias) {
    int w = (blockIdx.x * blockDim.x + threadIdx.x) >> 6;
    int lane = threadIdx.x & 63;
    if (w >= MPAD) return;
    int f = lane * 4;
    size_t ro = (size_t)w * HID + f;
    if (w >= NODES) {
        ushort4 z; z.x = 0; z.y = 0; z.z = 0; z.w = 0;
        *(ushort4*)(xo + ro) = z;
        return;
    }
    float di = dinv[w], sw = di * di;
    ushort4 sv = *(const ushort4*)(xw + ro);
    float a0 = sw * bf2f(sv.x), a1 = sw * bf2f(sv.y);
    float a2 = sw * bf2f(sv.z), a3 = sw * bf2f(sv.w);
    int p = rowptr[w], p1 = rowptr[w + 1];
    for (; p + 2 <= p1; p += 2) {
        int s0 = col[p], s1 = col[p + 1];
        float w0 = nrm[p], w1 = nrm[p + 1];
        ushort4 v0 = *(const ushort4*)(xw + (size_t)s0 * HID + f);
        ushort4 v1 = *(const ushort4*)(xw + (size_t)s1 * HID + f);
        a0 += w0 * bf2f(v0.x) + w1 * bf2f(v1.x);
        a1 += w0 * bf2f(v0.y) + w1 * bf2f(v1.y);
        a2 += w0 * bf2f(v0.z) + w1 * bf2f(v1.z);
        a3 += w0 * bf2f(v0.w) + w1 * bf2f(v1.w);
    }
    if (p < p1) {
        int s0 = col[p]; float w0 = nrm[p];
        ushort4 v0 = *(const ushort4*)(xw + (size_t)s0 * HID + f);
        a0 += w0 * bf2f(v0.x); a1 += w0 * bf2f(v0.y);
        a2 += w0 * bf2f(v0.z); a3 += w0 * bf2f(v0.w);
    }
    float4 b = *(const float4*)(bias + f);
    a0 = fmaxf(a0 + b.x, 0.f); a1 = fmaxf(a1 + b.y, 0.f);
    a2 = fmaxf(a2 + b.z, 0.f); a3 = fmaxf(a3 + b.w, 0.f);
    ushort4 o; o.x = f2bf(a0); o.y = f2bf(a1); o.z = f2bf(a2); o.w = f2bf(a3);
    *(ushort4*)(xo + ro) = o;
}

// ---------------- score + keys (one wave per node) ----------------
__global__ void score_kernel(const u16* __restrict__ x1, const u16* __restrict__ x2,
                             const u16* __restrict__ x3, const float* __restrict__ pw,
                             const float* __restrict__ invn, float* __restrict__ score,
                             unsigned long long* __restrict__ keys) {
    int w = (blockIdx.x * blockDim.x + threadIdx.x) >> 6;
    int lane = threadIdx.x & 63;
    if (w >= NODES) return;
    int f = lane * 4;
    float acc = 0.f;
    {
        ushort4 v = *(const ushort4*)(x1 + (size_t)w * HID + f);
        float4 q = *(const float4*)(pw + f);
        acc += bf2f(v.x) * q.x + bf2f(v.y) * q.y + bf2f(v.z) * q.z + bf2f(v.w) * q.w;
    }
    {
        ushort4 v = *(const ushort4*)(x2 + (size_t)w * HID + f);
        float4 q = *(const float4*)(pw + 256 + f);
        acc += bf2f(v.x) * q.x + bf2f(v.y) * q.y + bf2f(v.z) * q.z + bf2f(v.w) * q.w;
    }
    {
        ushort4 v = *(const ushort4*)(x3 + (size_t)w * HID + f);
        float4 q = *(const float4*)(pw + 512 + f);
        acc += bf2f(v.x) * q.x + bf2f(v.y) * q.y + bf2f(v.z) * q.z + bf2f(v.w) * q.w;
    }
    for (int off = 32; off; off >>= 1) acc += __shfl_down(acc, off);
    if (lane == 0) {
        float s = acc * invn[0];
        float sc = 1.f / (1.f + __expf(-s));
        score[w] = sc;
        int li = w % NP_G;
        keys[w] = ((unsigned long long)__float_as_uint(sc) << 13) |
                  (unsigned int)(NP_G - 1 - li);
    }
}

// ---------------- exact top-K threshold per graph (radix select, distinct keys) ----
__global__ void select_kernel(const unsigned long long* __restrict__ keys,
                              unsigned long long* __restrict__ kth) {
    int g = blockIdx.x, t = threadIdx.x;
    const unsigned long long* kk = keys + (size_t)g * NP_G;
    __shared__ unsigned int hist[256];
    __shared__ unsigned long long spref;
    __shared__ int swant;
    if (t == 0) { spref = 0ull; swant = KKEEP; }
    __syncthreads();
    unsigned long long mask = 0ull;
    for (int shift = 40; shift >= 0; shift -= 8) {
        hist[t] = 0u;
        __syncthreads();
        unsigned long long pref = spref;
        for (int i = t; i < NP_G; i += 256) {
            unsigned long long key = kk[i];
            if ((key & mask) == pref)
                atomicAdd(&hist[(unsigned int)(key >> shift) & 255u], 1u);
        }
        __syncthreads();
        if (t == 0) {
            int want = swant, c = 0, digit = 0;
            for (int b = 255; b >= 0; --b) {
                int nc = c + (int)hist[b];
                if (nc >= want) { digit = b; swant = want - c; break; }
                c = nc;
            }
            spref = pref | ((unsigned long long)digit << shift);
        }
        __syncthreads();
        mask |= (255ull << shift);
    }
    if (t == 0) kth[g] = spref;
}

// ---------------- readout: mean & max of selected rows * score ----------------
__global__ void readout_kernel(const u16* __restrict__ x1, const u16* __restrict__ x2,
                               const u16* __restrict__ x3, const float* __restrict__ score,
                               const unsigned long long* __restrict__ keys,
                               const unsigned long long* __restrict__ kth,
                               float* __restrict__ sumbuf, int* __restrict__ maxbuf) {
    int g = blockIdx.x, tpart = blockIdx.y, c = blockIdx.z;
    int fcol = threadIdx.x;
    const u16* xt = (tpart == 0) ? x1 : ((tpart == 1) ? x2 : x3);
    unsigned long long kg = kth[g];
    float sum = 0.f, mx = 0.f;
    int i0 = c * 250;
    for (int i = i0; i < i0 + 250; ++i) {
        int n = g * NP_G + i;
        if (keys[n] >= kg) {
            float s = score[n];
            float v = bf2f(xt[(size_t)n * HID + fcol]) * s;
            sum += v;
            mx = fmaxf(mx, v);
        }
    }
    int o = (g * 3 + tpart) * HID + fcol;
    atomicAdd(&sumbuf[o], sum);
    atomicMax(&maxbuf[o], __float_as_int(mx));   // all v >= 0, int order == float order
}

// ---------------- final MLP: [8,1536] -> 256 -> 128 -> 3 ----------------
__global__ __launch_bounds__(256) void mlp_kernel(const float* __restrict__ sumbuf,
                                                  const int* __restrict__ maxbuf,
                                                  const float* __restrict__ lw1,
                                                  const float* __restrict__ lb1,
                                                  const float* __restrict__ lw2,
                                                  const float* __restrict__ lb2,
                                                  const float* __restrict__ lw3,
                                                  const float* __restrict__ lb3,
                                                  float* __restrict__ out) {
    __shared__ float r[1536];
    __shared__ float h1[256];
    __shared__ float h2[128];
    int g = blockIdx.x, t = threadIdx.x;
    for (int i = t; i < 768; i += 256) {
        r[i]       = sumbuf[g * 768 + i] * (1.f / 5000.f);
        r[768 + i] = __int_as_float(maxbuf[g * 768 + i]);
    }
    __syncthreads();
    float a = lb1[t];
    for (int i = 0; i < 1536; ++i) a += r[i] * lw1[(size_t)i * 256 + t];
    h1[t] = fmaxf(a, 0.f);
    __syncthreads();
    if (t < 128) {
        float a2 = lb2[t];
        for (int i = 0; i < 256; ++i) a2 += h1[i] * lw2[i * 128 + t];
        h2[t] = fmaxf(a2, 0.f);
    }
    __syncthreads();
    if (t < 3) {
        float a3 = lb3[t];
        for (int i = 0; i < 128; ++i) a3 += h2[i] * lw3[i * 3 + t];
        out[g * 3 + t] = a3;
    }
}

extern "C" void kernel_launch(void* const* d_in, const int* in_sizes, int n_in,
                              void* d_out, int out_size, void* d_ws, size_t ws_size,
                              hipStream_t stream) {
    const float* x   = (const float*)d_in[0];
    const int*   ei  = (const int*)d_in[1];
    const float* ew  = (const float*)d_in[2];
    const float* W1  = (const float*)d_in[4];
    const float* b1  = (const float*)d_in[5];
    const float* W2  = (const float*)d_in[6];
    const float* b2  = (const float*)d_in[7];
    const float* pw  = (const float*)d_in[8];
    const float* lw1 = (const float*)d_in[9];
    const float* lb1 = (const float*)d_in[10];
    const float* lw2 = (const float*)d_in[11];
    const float* lb2 = (const float*)d_in[12];
    const float* lw3 = (const float*)d_in[13];
    const float* lb3 = (const float*)d_in[14];
    float* out = (float*)d_out;

    char* p = (char*)d_ws;
    auto alloc = [&](size_t bytes) -> char* {
        char* r = p;
        p += (bytes + 255) & ~(size_t)255;
        return r;
    };
    u16* A0  = (u16*)alloc((size_t)MPAD * CIN * 2);   // x bf16; x1/x2 alias after GEMM1
    u16* x3  = (u16*)alloc((size_t)MPAD * HID * 2);
    u16* xw  = (u16*)alloc((size_t)MPAD * HID * 2);
    u16* Wt1 = (u16*)alloc((size_t)HID * CIN * 2);
    u16* Wt2 = (u16*)alloc((size_t)HID * HID * 2);
    int*   col    = (int*)alloc((size_t)EDGES * 4);
    float* nrm    = (float*)alloc((size_t)EDGES * 4);
    int*   rowptr = (int*)alloc((size_t)(NODES + 1) * 4);
    unsigned long long* keys = (unsigned long long*)alloc((size_t)NODES * 8);
    float* score = (float*)alloc((size_t)NODES * 4);
    float* dinv  = (float*)alloc((size_t)NODES * 4);
    unsigned long long* kth = (unsigned long long*)alloc(64);
    float* invn = (float*)alloc(256);
    char* zbase = p;                                  // everything below is zero-init
    float* deg   = (float*)alloc((size_t)NODES * 4);
    int*   cnt   = (int*)alloc((size_t)NODES * 4);
    int*   cur   = (int*)alloc((size_t)NODES * 4);
    float* sumbuf = (float*)alloc(6144 * 4);
    int*   maxbuf = (int*)alloc(6144 * 4);
    size_t zbytes = (size_t)(p - zbase);

    u16* x1 = A0;                         // reuse A0 after GEMM1 consumed it
    u16* x2 = A0 + (size_t)MPAD * HID;

    hipMemsetAsync(zbase, 0, zbytes, stream);

    cast_x_kernel<<<(MPAD * CIN / 4 + 255) / 256, 256, 0, stream>>>(x, A0);
    cast_w_kernel<<<(HID * CIN + 255) / 256, 256, 0, stream>>>(W1, Wt1, CIN, HID);
    cast_w_kernel<<<(HID * HID + 255) / 256, 256, 0, stream>>>(W2, Wt2, HID, HID);
    pwnorm_kernel<<<1, 256, 0, stream>>>(pw, invn);

    edge_pass1<<<(EDGES + 255) / 256, 256, 0, stream>>>(ei, ew, deg, cnt);
    dinv_kernel<<<(NODES + 255) / 256, 256, 0, stream>>>(deg, dinv);
    scan_kernel<<<1, 1024, 0, stream>>>(cnt, rowptr);
    fill_kernel<<<(EDGES + 255) / 256, 256, 0, stream>>>(ei, ew, dinv, rowptr, cur, col, nrm);

    dim3 gg(MPAD / 128, HID / 128);
    int aggBlocks = (MPAD * 64 + 255) / 256;

    gemm_bt<<<gg, 256, 0, stream>>>(A0, Wt1, xw, MPAD, HID, CIN);
    agg_kernel<<<aggBlocks, 256, 0, stream>>>(xw, x1, rowptr, col, nrm, dinv, b1);
    gemm_bt<<<gg, 256, 0, stream>>>(x1, Wt2, xw, MPAD, HID, HID);
    agg_kernel<<<aggBlocks, 256, 0, stream>>>(xw, x2, rowptr, col, nrm, dinv, b2);
    gemm_bt<<<gg, 256, 0, stream>>>(x2, Wt2, xw, MPAD, HID, HID);
    agg_kernel<<<aggBlocks, 256, 0, stream>>>(xw, x3, rowptr, col, nrm, dinv, b2);

    int scBlocks = (NODES * 64 + 255) / 256;
    score_kernel<<<scBlocks, 256, 0, stream>>>(x1, x2, x3, pw, invn, score, keys);
    select_kernel<<<NGRAPH, 256, 0, stream>>>(keys, kth);
    readout_kernel<<<dim3(NGRAPH, 3, 25), 256, 0, stream>>>(x1, x2, x3, score, keys, kth,
                                                            sumbuf, maxbuf);
    mlp_kernel<<<NGRAPH, 256, 0, stream>>>(sumbuf, maxbuf, lw1, lb1, lw2, lb2, lw3, lb3, out);
}

// Round 2
// 771.305 us; speedup vs baseline: 1.1685x; 1.1685x over previous
//
#include <hip/hip_runtime.h>
#include <stdint.h>

#define NODES  50000
#define MPAD   50048      // 391 * 128
#define NGRAPH 8
#define NP_G   6250
#define EDGES  800000
#define KKEEP  5000
#define HID    256
#define CIN    512
#define H3     768

using f32x4  = __attribute__((ext_vector_type(4))) float;
using bf16x8 = __attribute__((ext_vector_type(8))) short;
typedef unsigned short u16;

__device__ __forceinline__ float bf2f(u16 u) {
    return __uint_as_float(((uint32_t)u) << 16);
}
__device__ __forceinline__ u16 f2bf(float f) {     // RNE
    uint32_t u = __float_as_uint(f);
    u += 0x7fffu + ((u >> 16) & 1u);
    return (u16)(u >> 16);
}

// ---------------- casts ----------------
__global__ void cast_x_kernel(const float* __restrict__ x, u16* __restrict__ A0) {
    size_t i4 = (size_t)blockIdx.x * blockDim.x + threadIdx.x;
    size_t base = i4 * 4;
    if (base >= (size_t)MPAD * CIN) return;
    int row = (int)(base >> 9);   // /512
    ushort4 o;
    if (row < NODES) {
        float4 v = *(const float4*)(x + base);
        o.x = f2bf(v.x); o.y = f2bf(v.y); o.z = f2bf(v.z); o.w = f2bf(v.w);
    } else {
        o.x = 0; o.y = 0; o.z = 0; o.w = 0;
    }
    *(ushort4*)(A0 + base) = o;
}

// W [K,N] f32 -> Wt [N,K] bf16
__global__ void cast_w_kernel(const float* __restrict__ W, u16* __restrict__ Wt,
                              int K, int N) {
    int id = blockIdx.x * blockDim.x + threadIdx.x;
    if (id >= N * K) return;
    int n = id / K, k = id - n * K;
    Wt[id] = f2bf(W[(size_t)k * N + n]);
}

__global__ void pwnorm_kernel(const float* __restrict__ pw, float* __restrict__ invn) {
    __shared__ float sh[256];
    int t = threadIdx.x;
    float s = 0.f;
    for (int i = t; i < H3; i += 256) { float v = pw[i]; s += v * v; }
    sh[t] = s; __syncthreads();
    for (int off = 128; off; off >>= 1) {
        if (t < off) sh[t] += sh[t + off];
        __syncthreads();
    }
    if (t == 0) invn[0] = rsqrtf(sh[0]);
}

// ---------------- graph prep ----------------
__global__ void edge_pass1(const int* __restrict__ ei, const float* __restrict__ ew,
                           float* __restrict__ deg, int* __restrict__ cnt) {
    int e = blockIdx.x * blockDim.x + threadIdx.x;
    if (e >= EDGES) return;
    int d = ei[EDGES + e];
    atomicAdd(&deg[d], ew[e]);
    atomicAdd(&cnt[d], 1);
}

__global__ void dinv_kernel(const float* __restrict__ deg, float* __restrict__ dinv) {
    int n = blockIdx.x * blockDim.x + threadIdx.x;
    if (n >= NODES) return;
    dinv[n] = rsqrtf(deg[n] + 1.0f);
}

__global__ __launch_bounds__(1024) void scan_kernel(const int* __restrict__ cnt,
                                                    int* __restrict__ rowptr) {
    __shared__ int sh[1024];
    int t = threadIdx.x;
    int base = t * 49;
    int end = base + 49; if (end > NODES) end = NODES;
    int s = 0;
    for (int i = base; i < end; ++i) s += cnt[i];
    sh[t] = s; __syncthreads();
    for (int off = 1; off < 1024; off <<= 1) {
        int v = 0;
        if (t >= off) v = sh[t - off];
        __syncthreads();
        if (t >= off) sh[t] += v;
        __syncthreads();
    }
    int run = (t == 0) ? 0 : sh[t - 1];
    for (int i = base; i < end; ++i) { rowptr[i] = run; run += cnt[i]; }
    if (t == 0) rowptr[NODES] = EDGES;
}

__global__ void fill_kernel(const int* __restrict__ ei, const float* __restrict__ ew,
                            const float* __restrict__ dinv, const int* __restrict__ rowptr,
                            int* __restrict__ cur, int* __restrict__ col,
                            float* __restrict__ nrm) {
    int e = blockIdx.x * blockDim.x + threadIdx.x;
    if (e >= EDGES) return;
    int s = ei[e], d = ei[EDGES + e];
    int pos = rowptr[d] + atomicAdd(&cur[d], 1);
    col[pos] = s;
    nrm[pos] = dinv[s] * ew[e] * dinv[d];
}

// ---------------- GEMM: C[M,N] = A[M,K] @ Bt[N,K]^T  (all bf16, fp32 acc) ---------
__global__ __launch_bounds__(256) void gemm_bt(const u16* __restrict__ A,
                                               const u16* __restrict__ Bt,
                                               u16* __restrict__ C,
                                               int M, int N, int K) {
    __shared__ u16 As[128 * 32];
    __shared__ u16 Bs[128 * 32];
    const int tid  = threadIdx.x;
    const int wave = tid >> 6, lane = tid & 63;
    const int wm = wave >> 1, wn = wave & 1;       // 2x2 waves over 128x128
    const int quad = lane >> 4, l16 = lane & 15;
    const int bm = blockIdx.x, bn = blockIdx.y;

    const int sr = tid >> 2;                        // staging row 0..63 (+64 second)
    const int sc = tid & 3;                         // 16B chunk within 64B row
    const int swz = (sc ^ ((sr >> 1) & 3)) * 8;     // (sr+64)>>1 has same low bits
    const int rphys = (quad ^ ((l16 >> 1) & 3)) * 8;

    const u16* Ag = A + (size_t)(bm * 128 + sr) * K + sc * 8;
    const u16* Bg = Bt + (size_t)(bn * 128 + sr) * K + sc * 8;

    f32x4 acc[4][4];
#pragma unroll
    for (int i = 0; i < 4; i++)
#pragma unroll
        for (int j = 0; j < 4; j++) { f32x4 z = {0.f, 0.f, 0.f, 0.f}; acc[i][j] = z; }

    for (int k0 = 0; k0 < K; k0 += 32) {
        int4 av0 = *(const int4*)(Ag + k0);
        int4 av1 = *(const int4*)(Ag + (size_t)64 * K + k0);
        int4 bv0 = *(const int4*)(Bg + k0);
        int4 bv1 = *(const int4*)(Bg + (size_t)64 * K + k0);
        __syncthreads();
        *(int4*)(As + sr * 32 + swz)        = av0;
        *(int4*)(As + (sr + 64) * 32 + swz) = av1;
        *(int4*)(Bs + sr * 32 + swz)        = bv0;
        *(int4*)(Bs + (sr + 64) * 32 + swz) = bv1;
        __syncthreads();
        bf16x8 af[4], bfr[4];
#pragma unroll
        for (int i = 0; i < 4; i++)
            af[i] = *(const bf16x8*)(As + (wm * 64 + i * 16 + l16) * 32 + rphys);
#pragma unroll
        for (int j = 0; j < 4; j++)
            bfr[j] = *(const bf16x8*)(Bs + (wn * 64 + j * 16 + l16) * 32 + rphys);
#pragma unroll
        for (int i = 0; i < 4; i++)
#pragma unroll
            for (int j = 0; j < 4; j++)
                acc[i][j] = __builtin_amdgcn_mfma_f32_16x16x32_bf16(af[i], bfr[j], acc[i][j], 0, 0, 0);
    }

    const int crow0 = bm * 128 + wm * 64 + quad * 4;
    const int ccol0 = bn * 128 + wn * 64 + l16;
#pragma unroll
    for (int i = 0; i < 4; i++)
#pragma unroll
        for (int j = 0; j < 4; j++)
#pragma unroll
            for (int r = 0; r < 4; r++)
                C[(size_t)(crow0 + i * 16 + r) * N + ccol0 + j * 16] = f2bf(acc[i][j][r]);
}

// ---------------- aggregation: one wave per node ----------------
__global__ void agg_kernel(const u16* __restrict__ xw, u16* __restrict__ xo,
                           const int* __restrict__ rowptr, const int* __restrict__ col,
                           const float* __restrict__ nrm, const float* __restrict__ dinv,
                           const float* __restrict__ bias) {
    int w = (blockIdx.x * blockDim.x + threadIdx.x) >> 6;
    int lane = threadIdx.x & 63;
    if (w >= MPAD) return;
    int f = lane * 4;
    size_t ro = (size_t)w * HID + f;
    if (w >= NODES) {
        ushort4 z; z.x = 0; z.y = 0; z.z = 0; z.w = 0;
        *(ushort4*)(xo + ro) = z;
        return;
    }
    float di = dinv[w], sw = di * di;
    ushort4 sv = *(const ushort4*)(xw + ro);
    float a0 = sw * bf2f(sv.x), a1 = sw * bf2f(sv.y);
    float a2 = sw * bf2f(sv.z), a3 = sw * bf2f(sv.w);
    int p = rowptr[w], p1 = rowptr[w + 1];
    for (; p + 4 <= p1; p += 4) {
        int s0 = col[p], s1 = col[p + 1], s2 = col[p + 2], s3 = col[p + 3];
        float w0 = nrm[p], w1 = nrm[p + 1], w2 = nrm[p + 2], w3 = nrm[p + 3];
        ushort4 v0 = *(const ushort4*)(xw + (size_t)s0 * HID + f);
        ushort4 v1 = *(const ushort4*)(xw + (size_t)s1 * HID + f);
        ushort4 v2 = *(const ushort4*)(xw + (size_t)s2 * HID + f);
        ushort4 v3 = *(const ushort4*)(xw + (size_t)s3 * HID + f);
        a0 += w0 * bf2f(v0.x) + w1 * bf2f(v1.x) + w2 * bf2f(v2.x) + w3 * bf2f(v3.x);
        a1 += w0 * bf2f(v0.y) + w1 * bf2f(v1.y) + w2 * bf2f(v2.y) + w3 * bf2f(v3.y);
        a2 += w0 * bf2f(v0.z) + w1 * bf2f(v1.z) + w2 * bf2f(v2.z) + w3 * bf2f(v3.z);
        a3 += w0 * bf2f(v0.w) + w1 * bf2f(v1.w) + w2 * bf2f(v2.w) + w3 * bf2f(v3.w);
    }
    for (; p < p1; ++p) {
        int s0 = col[p]; float w0 = nrm[p];
        ushort4 v0 = *(const ushort4*)(xw + (size_t)s0 * HID + f);
        a0 += w0 * bf2f(v0.x); a1 += w0 * bf2f(v0.y);
        a2 += w0 * bf2f(v0.z); a3 += w0 * bf2f(v0.w);
    }
    float4 b = *(const float4*)(bias + f);
    a0 = fmaxf(a0 + b.x, 0.f); a1 = fmaxf(a1 + b.y, 0.f);
    a2 = fmaxf(a2 + b.z, 0.f); a3 = fmaxf(a3 + b.w, 0.f);
    ushort4 o; o.x = f2bf(a0); o.y = f2bf(a1); o.z = f2bf(a2); o.w = f2bf(a3);
    *(ushort4*)(xo + ro) = o;
}

// ---------------- score + keys (one wave per node) ----------------
__global__ void score_kernel(const u16* __restrict__ x1, const u16* __restrict__ x2,
                             const u16* __restrict__ x3, const float* __restrict__ pw,
                             const float* __restrict__ invn, float* __restrict__ score,
                             unsigned long long* __restrict__ keys) {
    int w = (blockIdx.x * blockDim.x + threadIdx.x) >> 6;
    int lane = threadIdx.x & 63;
    if (w >= NODES) return;
    int f = lane * 4;
    float acc = 0.f;
    {
        ushort4 v = *(const ushort4*)(x1 + (size_t)w * HID + f);
        float4 q = *(const float4*)(pw + f);
        acc += bf2f(v.x) * q.x + bf2f(v.y) * q.y + bf2f(v.z) * q.z + bf2f(v.w) * q.w;
    }
    {
        ushort4 v = *(const ushort4*)(x2 + (size_t)w * HID + f);
        float4 q = *(const float4*)(pw + 256 + f);
        acc += bf2f(v.x) * q.x + bf2f(v.y) * q.y + bf2f(v.z) * q.z + bf2f(v.w) * q.w;
    }
    {
        ushort4 v = *(const ushort4*)(x3 + (size_t)w * HID + f);
        float4 q = *(const float4*)(pw + 512 + f);
        acc += bf2f(v.x) * q.x + bf2f(v.y) * q.y + bf2f(v.z) * q.z + bf2f(v.w) * q.w;
    }
    for (int off = 32; off; off >>= 1) acc += __shfl_down(acc, off);
    if (lane == 0) {
        float s = acc * invn[0];
        float sc = 1.f / (1.f + __expf(-s));
        score[w] = sc;
        int li = w % NP_G;
        keys[w] = ((unsigned long long)__float_as_uint(sc) << 13) |
                  (unsigned int)(NP_G - 1 - li);
    }
}

// ---------------- exact top-K threshold per graph (radix select, distinct keys) ----
// v2: keys staged in LDS, 1024 threads, 4 sub-histograms, parallel suffix scan.
__global__ __launch_bounds__(1024) void select_kernel(
        const unsigned long long* __restrict__ keys,
        unsigned long long* __restrict__ kth) {
    __shared__ unsigned long long kk[NP_G];          // 50 KB
    __shared__ unsigned int hist[4][256];
    __shared__ unsigned int sfx[257];
    __shared__ unsigned long long spref;
    __shared__ unsigned int swant;
    int g = blockIdx.x, t = threadIdx.x;
    const unsigned long long* kg = keys + (size_t)g * NP_G;
    for (int i = t; i < NP_G; i += 1024) kk[i] = kg[i];
    if (t == 0) { spref = 0ull; swant = KKEEP; }
    const int wgrp = (t >> 8) & 3;                   // 4 groups of 4 waves
    unsigned long long mask = 0ull;
    __syncthreads();
    for (int shift = 40; shift >= 0; shift -= 8) {
        if (t < 256) { hist[0][t] = 0; hist[1][t] = 0; hist[2][t] = 0; hist[3][t] = 0; }
        __syncthreads();
        unsigned long long pref = spref;
        for (int i = t; i < NP_G; i += 1024) {
            unsigned long long key = kk[i];
            if ((key & mask) == pref)
                atomicAdd(&hist[wgrp][(unsigned int)(key >> shift) & 255u], 1u);
        }
        __syncthreads();
        if (t < 256) sfx[t] = hist[0][t] + hist[1][t] + hist[2][t] + hist[3][t];
        if (t == 0) sfx[256] = 0;
        __syncthreads();
        // reversed Hillis-Steele inclusive scan: sfx[t] = sum_{b>=t} cnt[b]
        for (int off = 1; off < 256; off <<= 1) {
            unsigned int v = 0;
            if (t < 256 && t + off < 256) v = sfx[t + off];
            __syncthreads();
            if (t < 256 && t + off < 256) sfx[t] += v;
            __syncthreads();
        }
        unsigned int want = swant;                   // all read before any write
        __syncthreads();
        if (t < 256) {
            unsigned int s0 = sfx[t], s1 = sfx[t + 1];
            if (s0 >= want && s1 < want) {           // unique t (sfx nonincreasing)
                spref = pref | ((unsigned long long)t << shift);
                swant = want - s1;
            }
        }
        __syncthreads();
        mask |= (255ull << shift);
    }
    if (t == 0) kth[g] = spref;
}

// ---------------- readout: mean & max of selected rows * score ----------------
__global__ void readout_kernel(const u16* __restrict__ x1, const u16* __restrict__ x2,
                               const u16* __restrict__ x3, const float* __restrict__ score,
                               const unsigned long long* __restrict__ keys,
                               const unsigned long long* __restrict__ kth,
                               float* __restrict__ sumbuf, int* __restrict__ maxbuf) {
    int g = blockIdx.x, tpart = blockIdx.y, c = blockIdx.z;
    int fcol = threadIdx.x;
    const u16* xt = (tpart == 0) ? x1 : ((tpart == 1) ? x2 : x3);
    unsigned long long kg = kth[g];
    float sum = 0.f, mx = 0.f;
    int i0 = c * 250;
    for (int i = i0; i < i0 + 250; ++i) {
        int n = g * NP_G + i;
        if (keys[n] >= kg) {
            float s = score[n];
            float v = bf2f(xt[(size_t)n * HID + fcol]) * s;
            sum += v;
            mx = fmaxf(mx, v);
        }
    }
    int o = (g * 3 + tpart) * HID + fcol;
    atomicAdd(&sumbuf[o], sum);
    atomicMax(&maxbuf[o], __float_as_int(mx));   // all v >= 0, int order == float order
}

// ---------------- final MLP: [8,1536] -> 256 -> 128 -> 3 ----------------
__global__ __launch_bounds__(256) void mlp_kernel(const float* __restrict__ sumbuf,
                                                  const int* __restrict__ maxbuf,
                                                  const float* __restrict__ lw1,
                                                  const float* __restrict__ lb1,
                                                  const float* __restrict__ lw2,
                                                  const float* __restrict__ lb2,
                                                  const float* __restrict__ lw3,
                                                  const float* __restrict__ lb3,
                                                  float* __restrict__ out) {
    __shared__ float r[1536];
    __shared__ float h1[256];
    __shared__ float h2[128];
    int g = blockIdx.x, t = threadIdx.x;
    for (int i = t; i < 768; i += 256) {
        r[i]       = sumbuf[g * 768 + i] * (1.f / 5000.f);
        r[768 + i] = __int_as_float(maxbuf[g * 768 + i]);
    }
    __syncthreads();
    float a = lb1[t];
    for (int i = 0; i < 1536; ++i) a += r[i] * lw1[(size_t)i * 256 + t];
    h1[t] = fmaxf(a, 0.f);
    __syncthreads();
    if (t < 128) {
        float a2 = lb2[t];
        for (int i = 0; i < 256; ++i) a2 += h1[i] * lw2[i * 128 + t];
        h2[t] = fmaxf(a2, 0.f);
    }
    __syncthreads();
    if (t < 3) {
        float a3 = lb3[t];
        for (int i = 0; i < 128; ++i) a3 += h2[i] * lw3[i * 3 + t];
        out[g * 3 + t] = a3;
    }
}

extern "C" void kernel_launch(void* const* d_in, const int* in_sizes, int n_in,
                              void* d_out, int out_size, void* d_ws, size_t ws_size,
                              hipStream_t stream) {
    const float* x   = (const float*)d_in[0];
    const int*   ei  = (const int*)d_in[1];
    const float* ew  = (const float*)d_in[2];
    const float* W1  = (const float*)d_in[4];
    const float* b1  = (const float*)d_in[5];
    const float* W2  = (const float*)d_in[6];
    const float* b2  = (const float*)d_in[7];
    const float* pw  = (const float*)d_in[8];
    const float* lw1 = (const float*)d_in[9];
    const float* lb1 = (const float*)d_in[10];
    const float* lw2 = (const float*)d_in[11];
    const float* lb2 = (const float*)d_in[12];
    const float* lw3 = (const float*)d_in[13];
    const float* lb3 = (const float*)d_in[14];
    float* out = (float*)d_out;

    char* p = (char*)d_ws;
    auto alloc = [&](size_t bytes) -> char* {
        char* r = p;
        p += (bytes + 255) & ~(size_t)255;
        return r;
    };
    u16* A0  = (u16*)alloc((size_t)MPAD * CIN * 2);   // x bf16; x1/x2 alias after GEMM1
    u16* x3  = (u16*)alloc((size_t)MPAD * HID * 2);
    u16* xw  = (u16*)alloc((size_t)MPAD * HID * 2);
    u16* Wt1 = (u16*)alloc((size_t)HID * CIN * 2);
    u16* Wt2 = (u16*)alloc((size_t)HID * HID * 2);
    int*   col    = (int*)alloc((size_t)EDGES * 4);
    float* nrm    = (float*)alloc((size_t)EDGES * 4);
    int*   rowptr = (int*)alloc((size_t)(NODES + 1) * 4);
    unsigned long long* keys = (unsigned long long*)alloc((size_t)NODES * 8);
    float* score = (float*)alloc((size_t)NODES * 4);
    float* dinv  = (float*)alloc((size_t)NODES * 4);
    unsigned long long* kth = (unsigned long long*)alloc(64);
    float* invn = (float*)alloc(256);
    char* zbase = p;                                  // everything below is zero-init
    float* deg   = (float*)alloc((size_t)NODES * 4);
    int*   cnt   = (int*)alloc((size_t)NODES * 4);
    int*   cur   = (int*)alloc((size_t)NODES * 4);
    float* sumbuf = (float*)alloc(6144 * 4);
    int*   maxbuf = (int*)alloc(6144 * 4);
    size_t zbytes = (size_t)(p - zbase);

    u16* x1 = A0;                         // reuse A0 after GEMM1 consumed it
    u16* x2 = A0 + (size_t)MPAD * HID;

    hipMemsetAsync(zbase, 0, zbytes, stream);

    cast_x_kernel<<<(MPAD * CIN / 4 + 255) / 256, 256, 0, stream>>>(x, A0);
    cast_w_kernel<<<(HID * CIN + 255) / 256, 256, 0, stream>>>(W1, Wt1, CIN, HID);
    cast_w_kernel<<<(HID * HID + 255) / 256, 256, 0, stream>>>(W2, Wt2, HID, HID);
    pwnorm_kernel<<<1, 256, 0, stream>>>(pw, invn);

    edge_pass1<<<(EDGES + 255) / 256, 256, 0, stream>>>(ei, ew, deg, cnt);
    dinv_kernel<<<(NODES + 255) / 256, 256, 0, stream>>>(deg, dinv);
    scan_kernel<<<1, 1024, 0, stream>>>(cnt, rowptr);
    fill_kernel<<<(EDGES + 255) / 256, 256, 0, stream>>>(ei, ew, dinv, rowptr, cur, col, nrm);

    dim3 gg(MPAD / 128, HID / 128);
    int aggBlocks = (MPAD * 64 + 255) / 256;

    gemm_bt<<<gg, 256, 0, stream>>>(A0, Wt1, xw, MPAD, HID, CIN);
    agg_kernel<<<aggBlocks, 256, 0, stream>>>(xw, x1, rowptr, col, nrm, dinv, b1);
    gemm_bt<<<gg, 256, 0, stream>>>(x1, Wt2, xw, MPAD, HID, HID);
    agg_kernel<<<aggBlocks, 256, 0, stream>>>(xw, x2, rowptr, col, nrm, dinv, b2);
    gemm_bt<<<gg, 256, 0, stream>>>(x2, Wt2, xw, MPAD, HID, HID);
    agg_kernel<<<aggBlocks, 256, 0, stream>>>(xw, x3, rowptr, col, nrm, dinv, b2);

    int scBlocks = (NODES * 64 + 255) / 256;
    score_kernel<<<scBlocks, 256, 0, stream>>>(x1, x2, x3, pw, invn, score, keys);
    select_kernel<<<NGRAPH, 1024, 0, stream>>>(keys, kth);
    readout_kernel<<<dim3(NGRAPH, 3, 25), 256, 0, stream>>>(x1, x2, x3, score, keys, kth,
                                                            sumbuf, maxbuf);
    mlp_kernel<<<NGRAPH, 256, 0, stream>>>(sumbuf, maxbuf, lw1, lb1, lw2, lb2, lw3, lb3, out);
}

// Round 3
// 668.517 us; speedup vs baseline: 1.3482x; 1.1538x over previous
//
#include <hip/hip_runtime.h>
#include <stdint.h>

#define NODES  50000
#define MPAD   50048      // 391 * 128
#define NGRAPH 8
#define NP_G   6250
#define EDGES  800000
#define KKEEP  5000
#define HID    256
#define CIN    512
#define H3     768
#define SCANB  196        // 196*256 = 50176 >= NODES

using f32x4  = __attribute__((ext_vector_type(4))) float;
using bf16x8 = __attribute__((ext_vector_type(8))) short;
typedef unsigned short u16;
typedef unsigned long long u64;

__device__ __forceinline__ float bf2f(u16 u) {
    return __uint_as_float(((uint32_t)u) << 16);
}
__device__ __forceinline__ u16 f2bf(float f) {     // RNE
    uint32_t u = __float_as_uint(f);
    u += 0x7fffu + ((u >> 16) & 1u);
    return (u16)(u >> 16);
}

// ---------------- casts ----------------
__global__ void cast_x_kernel(const float* __restrict__ x, u16* __restrict__ A0) {
    size_t i4 = (size_t)blockIdx.x * blockDim.x + threadIdx.x;
    size_t base = i4 * 4;
    if (base >= (size_t)MPAD * CIN) return;
    int row = (int)(base >> 9);   // /512
    ushort4 o;
    if (row < NODES) {
        float4 v = *(const float4*)(x + base);
        o.x = f2bf(v.x); o.y = f2bf(v.y); o.z = f2bf(v.z); o.w = f2bf(v.w);
    } else {
        o.x = 0; o.y = 0; o.z = 0; o.w = 0;
    }
    *(ushort4*)(A0 + base) = o;
}

// W [K,N] f32 -> Wt [N,K] bf16
__global__ void cast_w_kernel(const float* __restrict__ W, u16* __restrict__ Wt,
                              int K, int N) {
    int id = blockIdx.x * blockDim.x + threadIdx.x;
    if (id >= N * K) return;
    int n = id / K, k = id - n * K;
    Wt[id] = f2bf(W[(size_t)k * N + n]);
}

__global__ void pwnorm_kernel(const float* __restrict__ pw, float* __restrict__ invn) {
    __shared__ float sh[256];
    int t = threadIdx.x;
    float s = 0.f;
    for (int i = t; i < H3; i += 256) { float v = pw[i]; s += v * v; }
    sh[t] = s; __syncthreads();
    for (int off = 128; off; off >>= 1) {
        if (t < off) sh[t] += sh[t + off];
        __syncthreads();
    }
    if (t == 0) invn[0] = rsqrtf(sh[0]);
}

// ---------------- graph prep ----------------
// one u64 atomic per edge: (count << 48) | fixed-point(ew, 2^-32)
__global__ void edge_pass1(const int* __restrict__ ei, const float* __restrict__ ew,
                           u64* __restrict__ degcnt) {
    int e = blockIdx.x * blockDim.x + threadIdx.x;
    if (e >= EDGES) return;
    int d = ei[EDGES + e];
    u64 enc = (1ull << 48) | (u64)(ew[e] * 4294967296.0f);
    atomicAdd(&degcnt[d], enc);
}

__global__ void dinv_kernel(const u64* __restrict__ degcnt, float* __restrict__ dinv) {
    int n = blockIdx.x * blockDim.x + threadIdx.x;
    if (n >= NODES) return;
    float deg = (float)(degcnt[n] & 0xFFFFFFFFFFFFull) * (1.0f / 4294967296.0f);
    dinv[n] = rsqrtf(deg + 1.0f);
}

// ---- hierarchical exclusive scan of per-node counts -> rowptr (+ rowcur copy) ----
__global__ void scan1_kernel(const u64* __restrict__ degcnt,
                             int* __restrict__ iscan, int* __restrict__ bsum) {
    int b = blockIdx.x, t = threadIdx.x;
    int i = b * 256 + t;
    int c = (i < NODES) ? (int)(degcnt[i] >> 48) : 0;
    int lane = t & 63, wv = t >> 6;
    int v = c;
    for (int off = 1; off < 64; off <<= 1) {
        int u = __shfl_up(v, off);
        if (lane >= off) v += u;
    }
    __shared__ int ws[4];
    if (lane == 63) ws[wv] = v;
    __syncthreads();
    if (t == 0) { int s = 0; for (int k = 0; k < 4; k++) { int tmp = ws[k]; ws[k] = s; s += tmp; } }
    __syncthreads();
    v += ws[wv];
    if (i < NODES) iscan[i] = v;          // block-local inclusive scan
    if (t == 255) bsum[b] = v;            // block total (OOB lanes contribute 0)
}

__global__ void scan2_kernel(const int* __restrict__ bsum, int* __restrict__ boff) {
    int t = threadIdx.x;
    int c = (t < SCANB) ? bsum[t] : 0;
    int lane = t & 63, wv = t >> 6;
    int v = c;
    for (int off = 1; off < 64; off <<= 1) {
        int u = __shfl_up(v, off);
        if (lane >= off) v += u;
    }
    __shared__ int ws[4];
    if (lane == 63) ws[wv] = v;
    __syncthreads();
    if (t == 0) { int s = 0; for (int k = 0; k < 4; k++) { int tmp = ws[k]; ws[k] = s; s += tmp; } }
    __syncthreads();
    v += ws[wv];
    if (t < SCANB) boff[t] = v - c;       // exclusive
}

__global__ void scan3_kernel(const u64* __restrict__ degcnt,
                             const int* __restrict__ iscan, const int* __restrict__ boff,
                             int* __restrict__ rowptr, int* __restrict__ rowcur) {
    int b = blockIdx.x, t = threadIdx.x;
    int i = b * 256 + t;
    if (i > NODES) return;
    if (i == NODES) { rowptr[NODES] = EDGES; return; }
    int c = (int)(degcnt[i] >> 48);
    int v = boff[b] + iscan[i] - c;       // global exclusive scan
    rowptr[i] = v;
    rowcur[i] = v;
}

__global__ void fill_kernel(const int* __restrict__ ei, const float* __restrict__ ew,
                            const float* __restrict__ dinv,
                            int* __restrict__ rowcur, int* __restrict__ col,
                            float* __restrict__ nrm) {
    int e = blockIdx.x * blockDim.x + threadIdx.x;
    if (e >= EDGES) return;
    int s = ei[e], d = ei[EDGES + e];
    int pos = atomicAdd(&rowcur[d], 1);
    col[pos] = s;
    nrm[pos] = dinv[s] * ew[e] * dinv[d];
}

// ---------------- GEMM: C[M,N] = A[M,K] @ Bt[N,K]^T  (all bf16, fp32 acc) ---------
__global__ __launch_bounds__(256) void gemm_bt(const u16* __restrict__ A,
                                               const u16* __restrict__ Bt,
                                               u16* __restrict__ C,
                                               int M, int N, int K) {
    __shared__ u16 As[128 * 32];
    __shared__ u16 Bs[128 * 32];
    const int tid  = threadIdx.x;
    const int wave = tid >> 6, lane = tid & 63;
    const int wm = wave >> 1, wn = wave & 1;       // 2x2 waves over 128x128
    const int quad = lane >> 4, l16 = lane & 15;
    const int bm = blockIdx.x, bn = blockIdx.y;

    const int sr = tid >> 2;                        // staging row 0..63 (+64 second)
    const int sc = tid & 3;                         // 16B chunk within 64B row
    const int swz = (sc ^ ((sr >> 1) & 3)) * 8;     // (sr+64)>>1 has same low bits
    const int rphys = (quad ^ ((l16 >> 1) & 3)) * 8;

    const u16* Ag = A + (size_t)(bm * 128 + sr) * K + sc * 8;
    const u16* Bg = Bt + (size_t)(bn * 128 + sr) * K + sc * 8;

    f32x4 acc[4][4];
#pragma unroll
    for (int i = 0; i < 4; i++)
#pragma unroll
        for (int j = 0; j < 4; j++) { f32x4 z = {0.f, 0.f, 0.f, 0.f}; acc[i][j] = z; }

    for (int k0 = 0; k0 < K; k0 += 32) {
        int4 av0 = *(const int4*)(Ag + k0);
        int4 av1 = *(const int4*)(Ag + (size_t)64 * K + k0);
        int4 bv0 = *(const int4*)(Bg + k0);
        int4 bv1 = *(const int4*)(Bg + (size_t)64 * K + k0);
        __syncthreads();
        *(int4*)(As + sr * 32 + swz)        = av0;
        *(int4*)(As + (sr + 64) * 32 + swz) = av1;
        *(int4*)(Bs + sr * 32 + swz)        = bv0;
        *(int4*)(Bs + (sr + 64) * 32 + swz) = bv1;
        __syncthreads();
        bf16x8 af[4], bfr[4];
#pragma unroll
        for (int i = 0; i < 4; i++)
            af[i] = *(const bf16x8*)(As + (wm * 64 + i * 16 + l16) * 32 + rphys);
#pragma unroll
        for (int j = 0; j < 4; j++)
            bfr[j] = *(const bf16x8*)(Bs + (wn * 64 + j * 16 + l16) * 32 + rphys);
#pragma unroll
        for (int i = 0; i < 4; i++)
#pragma unroll
            for (int j = 0; j < 4; j++)
                acc[i][j] = __builtin_amdgcn_mfma_f32_16x16x32_bf16(af[i], bfr[j], acc[i][j], 0, 0, 0);
    }

    const int crow0 = bm * 128 + wm * 64 + quad * 4;
    const int ccol0 = bn * 128 + wn * 64 + l16;
#pragma unroll
    for (int i = 0; i < 4; i++)
#pragma unroll
        for (int j = 0; j < 4; j++)
#pragma unroll
            for (int r = 0; r < 4; r++)
                C[(size_t)(crow0 + i * 16 + r) * N + ccol0 + j * 16] = f2bf(acc[i][j][r]);
}

// ---------------- aggregation: one wave per node ----------------
__global__ void agg_kernel(const u16* __restrict__ xw, u16* __restrict__ xo,
                           const int* __restrict__ rowptr, const int* __restrict__ col,
                           const float* __restrict__ nrm, const float* __restrict__ dinv,
                           const float* __restrict__ bias) {
    int w = (blockIdx.x * blockDim.x + threadIdx.x) >> 6;
    int lane = threadIdx.x & 63;
    if (w >= MPAD) return;
    int f = lane * 4;
    size_t ro = (size_t)w * HID + f;
    if (w >= NODES) {
        ushort4 z; z.x = 0; z.y = 0; z.z = 0; z.w = 0;
        *(ushort4*)(xo + ro) = z;
        return;
    }
    float di = dinv[w], sw = di * di;
    ushort4 sv = *(const ushort4*)(xw + ro);
    float a0 = sw * bf2f(sv.x), a1 = sw * bf2f(sv.y);
    float a2 = sw * bf2f(sv.z), a3 = sw * bf2f(sv.w);
    int p = rowptr[w], p1 = rowptr[w + 1];
    for (; p + 4 <= p1; p += 4) {
        int s0 = col[p], s1 = col[p + 1], s2 = col[p + 2], s3 = col[p + 3];
        float w0 = nrm[p], w1 = nrm[p + 1], w2 = nrm[p + 2], w3 = nrm[p + 3];
        ushort4 v0 = *(const ushort4*)(xw + (size_t)s0 * HID + f);
        ushort4 v1 = *(const ushort4*)(xw + (size_t)s1 * HID + f);
        ushort4 v2 = *(const ushort4*)(xw + (size_t)s2 * HID + f);
        ushort4 v3 = *(const ushort4*)(xw + (size_t)s3 * HID + f);
        a0 += w0 * bf2f(v0.x) + w1 * bf2f(v1.x) + w2 * bf2f(v2.x) + w3 * bf2f(v3.x);
        a1 += w0 * bf2f(v0.y) + w1 * bf2f(v1.y) + w2 * bf2f(v2.y) + w3 * bf2f(v3.y);
        a2 += w0 * bf2f(v0.z) + w1 * bf2f(v1.z) + w2 * bf2f(v2.z) + w3 * bf2f(v3.z);
        a3 += w0 * bf2f(v0.w) + w1 * bf2f(v1.w) + w2 * bf2f(v2.w) + w3 * bf2f(v3.w);
    }
    for (; p < p1; ++p) {
        int s0 = col[p]; float w0 = nrm[p];
        ushort4 v0 = *(const ushort4*)(xw + (size_t)s0 * HID + f);
        a0 += w0 * bf2f(v0.x); a1 += w0 * bf2f(v0.y);
        a2 += w0 * bf2f(v0.z); a3 += w0 * bf2f(v0.w);
    }
    float4 b = *(const float4*)(bias + f);
    a0 = fmaxf(a0 + b.x, 0.f); a1 = fmaxf(a1 + b.y, 0.f);
    a2 = fmaxf(a2 + b.z, 0.f); a3 = fmaxf(a3 + b.w, 0.f);
    ushort4 o; o.x = f2bf(a0); o.y = f2bf(a1); o.z = f2bf(a2); o.w = f2bf(a3);
    *(ushort4*)(xo + ro) = o;
}

// ---------------- score + keys (one wave per node) ----------------
__global__ void score_kernel(const u16* __restrict__ x1, const u16* __restrict__ x2,
                             const u16* __restrict__ x3, const float* __restrict__ pw,
                             const float* __restrict__ invn, float* __restrict__ score,
                             unsigned long long* __restrict__ keys) {
    int w = (blockIdx.x * blockDim.x + threadIdx.x) >> 6;
    int lane = threadIdx.x & 63;
    if (w >= NODES) return;
    int f = lane * 4;
    float acc = 0.f;
    {
        ushort4 v = *(const ushort4*)(x1 + (size_t)w * HID + f);
        float4 q = *(const float4*)(pw + f);
        acc += bf2f(v.x) * q.x + bf2f(v.y) * q.y + bf2f(v.z) * q.z + bf2f(v.w) * q.w;
    }
    {
        ushort4 v = *(const ushort4*)(x2 + (size_t)w * HID + f);
        float4 q = *(const float4*)(pw + 256 + f);
        acc += bf2f(v.x) * q.x + bf2f(v.y) * q.y + bf2f(v.z) * q.z + bf2f(v.w) * q.w;
    }
    {
        ushort4 v = *(const ushort4*)(x3 + (size_t)w * HID + f);
        float4 q = *(const float4*)(pw + 512 + f);
        acc += bf2f(v.x) * q.x + bf2f(v.y) * q.y + bf2f(v.z) * q.z + bf2f(v.w) * q.w;
    }
    for (int off = 32; off; off >>= 1) acc += __shfl_down(acc, off);
    if (lane == 0) {
        float s = acc * invn[0];
        float sc = 1.f / (1.f + __expf(-s));
        score[w] = sc;
        int li = w % NP_G;
        keys[w] = ((unsigned long long)__float_as_uint(sc) << 13) |
                  (unsigned int)(NP_G - 1 - li);
    }
}

// ---------------- exact top-K threshold per graph (radix select, distinct keys) ----
__global__ __launch_bounds__(1024) void select_kernel(
        const unsigned long long* __restrict__ keys,
        unsigned long long* __restrict__ kth) {
    __shared__ unsigned long long kk[NP_G];          // 50 KB
    __shared__ unsigned int hist[4][256];
    __shared__ unsigned int sfx[257];
    __shared__ unsigned long long spref;
    __shared__ unsigned int swant;
    int g = blockIdx.x, t = threadIdx.x;
    const unsigned long long* kg = keys + (size_t)g * NP_G;
    for (int i = t; i < NP_G; i += 1024) kk[i] = kg[i];
    if (t == 0) { spref = 0ull; swant = KKEEP; }
    const int wgrp = (t >> 8) & 3;                   // 4 groups of 4 waves
    unsigned long long mask = 0ull;
    __syncthreads();
    for (int shift = 40; shift >= 0; shift -= 8) {
        if (t < 256) { hist[0][t] = 0; hist[1][t] = 0; hist[2][t] = 0; hist[3][t] = 0; }
        __syncthreads();
        unsigned long long pref = spref;
        for (int i = t; i < NP_G; i += 1024) {
            unsigned long long key = kk[i];
            if ((key & mask) == pref)
                atomicAdd(&hist[wgrp][(unsigned int)(key >> shift) & 255u], 1u);
        }
        __syncthreads();
        if (t < 256) sfx[t] = hist[0][t] + hist[1][t] + hist[2][t] + hist[3][t];
        if (t == 0) sfx[256] = 0;
        __syncthreads();
        // reversed Hillis-Steele inclusive scan: sfx[t] = sum_{b>=t} cnt[b]
        for (int off = 1; off < 256; off <<= 1) {
            unsigned int v = 0;
            if (t < 256 && t + off < 256) v = sfx[t + off];
            __syncthreads();
            if (t < 256 && t + off < 256) sfx[t] += v;
            __syncthreads();
        }
        unsigned int want = swant;                   // all read before any write
        __syncthreads();
        if (t < 256) {
            unsigned int s0 = sfx[t], s1 = sfx[t + 1];
            if (s0 >= want && s1 < want) {           // unique t (sfx nonincreasing)
                spref = pref | ((unsigned long long)t << shift);
                swant = want - s1;
            }
        }
        __syncthreads();
        mask |= (255ull << shift);
    }
    if (t == 0) kth[g] = spref;
}

// ---------------- readout: mean & max of selected rows * score ----------------
__global__ void readout_kernel(const u16* __restrict__ x1, const u16* __restrict__ x2,
                               const u16* __restrict__ x3, const float* __restrict__ score,
                               const unsigned long long* __restrict__ keys,
                               const unsigned long long* __restrict__ kth,
                               float* __restrict__ sumbuf, int* __restrict__ maxbuf) {
    int g = blockIdx.x, tpart = blockIdx.y, c = blockIdx.z;
    int fcol = threadIdx.x;
    const u16* xt = (tpart == 0) ? x1 : ((tpart == 1) ? x2 : x3);
    unsigned long long kg = kth[g];
    float sum = 0.f, mx = 0.f;
    int i0 = c * 250;
    for (int i = i0; i < i0 + 250; ++i) {
        int n = g * NP_G + i;
        if (keys[n] >= kg) {
            float s = score[n];
            float v = bf2f(xt[(size_t)n * HID + fcol]) * s;
            sum += v;
            mx = fmaxf(mx, v);
        }
    }
    int o = (g * 3 + tpart) * HID + fcol;
    atomicAdd(&sumbuf[o], sum);
    atomicMax(&maxbuf[o], __float_as_int(mx));   // all v >= 0, int order == float order
}

// ---------------- final MLP: [8,1536] -> 256 -> 128 -> 3 ----------------
__global__ __launch_bounds__(256) void mlp_kernel(const float* __restrict__ sumbuf,
                                                  const int* __restrict__ maxbuf,
                                                  const float* __restrict__ lw1,
                                                  const float* __restrict__ lb1,
                                                  const float* __restrict__ lw2,
                                                  const float* __restrict__ lb2,
                                                  const float* __restrict__ lw3,
                                                  const float* __restrict__ lb3,
                                                  float* __restrict__ out) {
    __shared__ float r[1536];
    __shared__ float h1[256];
    __shared__ float h2[128];
    int g = blockIdx.x, t = threadIdx.x;
    for (int i = t; i < 768; i += 256) {
        r[i]       = sumbuf[g * 768 + i] * (1.f / 5000.f);
        r[768 + i] = __int_as_float(maxbuf[g * 768 + i]);
    }
    __syncthreads();
    float a = lb1[t];
    for (int i = 0; i < 1536; ++i) a += r[i] * lw1[(size_t)i * 256 + t];
    h1[t] = fmaxf(a, 0.f);
    __syncthreads();
    if (t < 128) {
        float a2 = lb2[t];
        for (int i = 0; i < 256; ++i) a2 += h1[i] * lw2[i * 128 + t];
        h2[t] = fmaxf(a2, 0.f);
    }
    __syncthreads();
    if (t < 3) {
        float a3 = lb3[t];
        for (int i = 0; i < 128; ++i) a3 += h2[i] * lw3[i * 3 + t];
        out[g * 3 + t] = a3;
    }
}

extern "C" void kernel_launch(void* const* d_in, const int* in_sizes, int n_in,
                              void* d_out, int out_size, void* d_ws, size_t ws_size,
                              hipStream_t stream) {
    const float* x   = (const float*)d_in[0];
    const int*   ei  = (const int*)d_in[1];
    const float* ew  = (const float*)d_in[2];
    const float* W1  = (const float*)d_in[4];
    const float* b1  = (const float*)d_in[5];
    const float* W2  = (const float*)d_in[6];
    const float* b2  = (const float*)d_in[7];
    const float* pw  = (const float*)d_in[8];
    const float* lw1 = (const float*)d_in[9];
    const float* lb1 = (const float*)d_in[10];
    const float* lw2 = (const float*)d_in[11];
    const float* lb2 = (const float*)d_in[12];
    const float* lw3 = (const float*)d_in[13];
    const float* lb3 = (const float*)d_in[14];
    float* out = (float*)d_out;

    char* p = (char*)d_ws;
    auto alloc = [&](size_t bytes) -> char* {
        char* r = p;
        p += (bytes + 255) & ~(size_t)255;
        return r;
    };
    u16* A0  = (u16*)alloc((size_t)MPAD * CIN * 2);   // x bf16; x1/x2 alias after GEMM1
    u16* x3  = (u16*)alloc((size_t)MPAD * HID * 2);
    u16* xw  = (u16*)alloc((size_t)MPAD * HID * 2);
    u16* Wt1 = (u16*)alloc((size_t)HID * CIN * 2);
    u16* Wt2 = (u16*)alloc((size_t)HID * HID * 2);
    int*   col    = (int*)alloc((size_t)EDGES * 4);
    float* nrm    = (float*)alloc((size_t)EDGES * 4);
    int*   rowptr = (int*)alloc((size_t)(NODES + 1) * 4);
    int*   rowcur = (int*)alloc((size_t)NODES * 4);
    int*   iscan  = (int*)alloc((size_t)NODES * 4);
    int*   bsum   = (int*)alloc((size_t)SCANB * 4);
    int*   boff   = (int*)alloc((size_t)SCANB * 4);
    unsigned long long* keys = (unsigned long long*)alloc((size_t)NODES * 8);
    float* score = (float*)alloc((size_t)NODES * 4);
    float* dinv  = (float*)alloc((size_t)NODES * 4);
    unsigned long long* kth = (unsigned long long*)alloc(64);
    float* invn = (float*)alloc(256);
    char* zbase = p;                                  // everything below is zero-init
    u64*   degcnt = (u64*)alloc((size_t)NODES * 8);
    float* sumbuf = (float*)alloc(6144 * 4);
    int*   maxbuf = (int*)alloc(6144 * 4);
    size_t zbytes = (size_t)(p - zbase);

    u16* x1 = A0;                         // reuse A0 after GEMM1 consumed it
    u16* x2 = A0 + (size_t)MPAD * HID;

    hipMemsetAsync(zbase, 0, zbytes, stream);

    cast_x_kernel<<<(MPAD * CIN / 4 + 255) / 256, 256, 0, stream>>>(x, A0);
    cast_w_kernel<<<(HID * CIN + 255) / 256, 256, 0, stream>>>(W1, Wt1, CIN, HID);
    cast_w_kernel<<<(HID * HID + 255) / 256, 256, 0, stream>>>(W2, Wt2, HID, HID);
    pwnorm_kernel<<<1, 256, 0, stream>>>(pw, invn);

    edge_pass1<<<(EDGES + 255) / 256, 256, 0, stream>>>(ei, ew, degcnt);
    dinv_kernel<<<(NODES + 255) / 256, 256, 0, stream>>>(degcnt, dinv);
    scan1_kernel<<<SCANB, 256, 0, stream>>>(degcnt, iscan, bsum);
    scan2_kernel<<<1, 256, 0, stream>>>(bsum, boff);
    scan3_kernel<<<SCANB + 1, 256, 0, stream>>>(degcnt, iscan, boff, rowptr, rowcur);
    fill_kernel<<<(EDGES + 255) / 256, 256, 0, stream>>>(ei, ew, dinv, rowcur, col, nrm);

    dim3 gg(MPAD / 128, HID / 128);
    int aggBlocks = (MPAD * 64 + 255) / 256;

    gemm_bt<<<gg, 256, 0, stream>>>(A0, Wt1, xw, MPAD, HID, CIN);
    agg_kernel<<<aggBlocks, 256, 0, stream>>>(xw, x1, rowptr, col, nrm, dinv, b1);
    gemm_bt<<<gg, 256, 0, stream>>>(x1, Wt2, xw, MPAD, HID, HID);
    agg_kernel<<<aggBlocks, 256, 0, stream>>>(xw, x2, rowptr, col, nrm, dinv, b2);
    gemm_bt<<<gg, 256, 0, stream>>>(x2, Wt2, xw, MPAD, HID, HID);
    agg_kernel<<<aggBlocks, 256, 0, stream>>>(xw, x3, rowptr, col, nrm, dinv, b2);

    int scBlocks = (NODES * 64 + 255) / 256;
    score_kernel<<<scBlocks, 256, 0, stream>>>(x1, x2, x3, pw, invn, score, keys);
    select_kernel<<<NGRAPH, 1024, 0, stream>>>(keys, kth);
    readout_kernel<<<dim3(NGRAPH, 3, 25), 256, 0, stream>>>(x1, x2, x3, score, keys, kth,
                                                            sumbuf, maxbuf);
    mlp_kernel<<<NGRAPH, 256, 0, stream>>>(sumbuf, maxbuf, lw1, lb1, lw2, lb2, lw3, lb3, out);
}

// Round 4
// 622.664 us; speedup vs baseline: 1.4474x; 1.0736x over previous
//
#include <hip/hip_runtime.h>
#include <stdint.h>

#define NODES  50000
#define MPAD   50048      // 391 * 128
#define NGRAPH 8
#define NP_G   6250
#define EDGES  800000
#define KKEEP  5000
#define HID    256
#define CIN    512
#define H3     768
#define SCANB  196        // 196*256 = 50176 >= NODES
#define RCHUNK 200        // KKEEP / 25

using f32x4  = __attribute__((ext_vector_type(4))) float;
using bf16x8 = __attribute__((ext_vector_type(8))) short;
typedef unsigned short u16;
typedef unsigned long long u64;

__device__ __forceinline__ float bf2f(u16 u) {
    return __uint_as_float(((uint32_t)u) << 16);
}
__device__ __forceinline__ u16 f2bf(float f) {     // RNE
    uint32_t u = __float_as_uint(f);
    u += 0x7fffu + ((u >> 16) & 1u);
    return (u16)(u >> 16);
}

// ---------------- casts ----------------
__global__ void cast_x_kernel(const float* __restrict__ x, u16* __restrict__ A0) {
    size_t i4 = (size_t)blockIdx.x * blockDim.x + threadIdx.x;
    size_t base = i4 * 4;
    if (base >= (size_t)MPAD * CIN) return;
    int row = (int)(base >> 9);   // /512
    ushort4 o;
    if (row < NODES) {
        float4 v = *(const float4*)(x + base);
        o.x = f2bf(v.x); o.y = f2bf(v.y); o.z = f2bf(v.z); o.w = f2bf(v.w);
    } else {
        o.x = 0; o.y = 0; o.z = 0; o.w = 0;
    }
    *(ushort4*)(A0 + base) = o;
}

// W [K,N] f32 -> Wt [N,K] bf16
__global__ void cast_w_kernel(const float* __restrict__ W, u16* __restrict__ Wt,
                              int K, int N) {
    int id = blockIdx.x * blockDim.x + threadIdx.x;
    if (id >= N * K) return;
    int n = id / K, k = id - n * K;
    Wt[id] = f2bf(W[(size_t)k * N + n]);
}

// zero the padding rows of x1/x2/x3 (agg no longer writes them)
__global__ void zero_pad_kernel(u16* __restrict__ a, u16* __restrict__ b,
                                u16* __restrict__ c) {
    int i = blockIdx.x * blockDim.x + threadIdx.x;   // 0 .. 48*256-1
    if (i >= (MPAD - NODES) * HID) return;
    size_t o = (size_t)NODES * HID + i;
    a[o] = 0; b[o] = 0; c[o] = 0;
}

__global__ void pwnorm_kernel(const float* __restrict__ pw, float* __restrict__ invn) {
    __shared__ float sh[256];
    int t = threadIdx.x;
    float s = 0.f;
    for (int i = t; i < H3; i += 256) { float v = pw[i]; s += v * v; }
    sh[t] = s; __syncthreads();
    for (int off = 128; off; off >>= 1) {
        if (t < off) sh[t] += sh[t + off];
        __syncthreads();
    }
    if (t == 0) invn[0] = rsqrtf(sh[0]);
}

// ---------------- graph prep ----------------
// one u64 atomic per edge: (count << 48) | fixed-point(ew, 2^-32)
__global__ void edge_pass1(const int* __restrict__ ei, const float* __restrict__ ew,
                           u64* __restrict__ degcnt) {
    int e = blockIdx.x * blockDim.x + threadIdx.x;
    if (e >= EDGES) return;
    int d = ei[EDGES + e];
    u64 enc = (1ull << 48) | (u64)(ew[e] * 4294967296.0f);
    atomicAdd(&degcnt[d], enc);
}

__global__ void dinv_kernel(const u64* __restrict__ degcnt, float* __restrict__ dinv) {
    int n = blockIdx.x * blockDim.x + threadIdx.x;
    if (n >= NODES) return;
    float deg = (float)(degcnt[n] & 0xFFFFFFFFFFFFull) * (1.0f / 4294967296.0f);
    dinv[n] = rsqrtf(deg + 1.0f);
}

// ---- hierarchical exclusive scan of per-node counts -> rowptr (+ rowcur copy) ----
__global__ void scan1_kernel(const u64* __restrict__ degcnt,
                             int* __restrict__ iscan, int* __restrict__ bsum) {
    int b = blockIdx.x, t = threadIdx.x;
    int i = b * 256 + t;
    int c = (i < NODES) ? (int)(degcnt[i] >> 48) : 0;
    int lane = t & 63, wv = t >> 6;
    int v = c;
    for (int off = 1; off < 64; off <<= 1) {
        int u = __shfl_up(v, off);
        if (lane >= off) v += u;
    }
    __shared__ int ws[4];
    if (lane == 63) ws[wv] = v;
    __syncthreads();
    if (t == 0) { int s = 0; for (int k = 0; k < 4; k++) { int tmp = ws[k]; ws[k] = s; s += tmp; } }
    __syncthreads();
    v += ws[wv];
    if (i < NODES) iscan[i] = v;          // block-local inclusive scan
    if (t == 255) bsum[b] = v;            // block total (OOB lanes contribute 0)
}

__global__ void scan2_kernel(const int* __restrict__ bsum, int* __restrict__ boff) {
    int t = threadIdx.x;
    int c = (t < SCANB) ? bsum[t] : 0;
    int lane = t & 63, wv = t >> 6;
    int v = c;
    for (int off = 1; off < 64; off <<= 1) {
        int u = __shfl_up(v, off);
        if (lane >= off) v += u;
    }
    __shared__ int ws[4];
    if (lane == 63) ws[wv] = v;
    __syncthreads();
    if (t == 0) { int s = 0; for (int k = 0; k < 4; k++) { int tmp = ws[k]; ws[k] = s; s += tmp; } }
    __syncthreads();
    v += ws[wv];
    if (t < SCANB) boff[t] = v - c;       // exclusive
}

__global__ void scan3_kernel(const u64* __restrict__ degcnt,
                             const int* __restrict__ iscan, const int* __restrict__ boff,
                             int* __restrict__ rowptr, int* __restrict__ rowcur) {
    int b = blockIdx.x, t = threadIdx.x;
    int i = b * 256 + t;
    if (i > NODES) return;
    if (i == NODES) { rowptr[NODES] = EDGES; return; }
    int c = (int)(degcnt[i] >> 48);
    int v = boff[b] + iscan[i] - c;       // global exclusive scan
    rowptr[i] = v;
    rowcur[i] = v;
}

__global__ void fill_kernel(const int* __restrict__ ei, const float* __restrict__ ew,
                            const float* __restrict__ dinv,
                            int* __restrict__ rowcur, int* __restrict__ col,
                            float* __restrict__ nrm) {
    int e = blockIdx.x * blockDim.x + threadIdx.x;
    if (e >= EDGES) return;
    int s = ei[e], d = ei[EDGES + e];
    int pos = atomicAdd(&rowcur[d], 1);
    col[pos] = s;
    nrm[pos] = dinv[s] * ew[e] * dinv[d];
}

// ---------------- GEMM: C[M,N] = A[M,K] @ Bt[N,K]^T  (all bf16, fp32 acc) ---------
__global__ __launch_bounds__(256) void gemm_bt(const u16* __restrict__ A,
                                               const u16* __restrict__ Bt,
                                               u16* __restrict__ C,
                                               int M, int N, int K) {
    __shared__ u16 As[128 * 32];
    __shared__ u16 Bs[128 * 32];
    const int tid  = threadIdx.x;
    const int wave = tid >> 6, lane = tid & 63;
    const int wm = wave >> 1, wn = wave & 1;       // 2x2 waves over 128x128
    const int quad = lane >> 4, l16 = lane & 15;
    const int bm = blockIdx.x, bn = blockIdx.y;

    const int sr = tid >> 2;                        // staging row 0..63 (+64 second)
    const int sc = tid & 3;                         // 16B chunk within 64B row
    const int swz = (sc ^ ((sr >> 1) & 3)) * 8;     // (sr+64)>>1 has same low bits
    const int rphys = (quad ^ ((l16 >> 1) & 3)) * 8;

    const u16* Ag = A + (size_t)(bm * 128 + sr) * K + sc * 8;
    const u16* Bg = Bt + (size_t)(bn * 128 + sr) * K + sc * 8;

    f32x4 acc[4][4];
#pragma unroll
    for (int i = 0; i < 4; i++)
#pragma unroll
        for (int j = 0; j < 4; j++) { f32x4 z = {0.f, 0.f, 0.f, 0.f}; acc[i][j] = z; }

    for (int k0 = 0; k0 < K; k0 += 32) {
        int4 av0 = *(const int4*)(Ag + k0);
        int4 av1 = *(const int4*)(Ag + (size_t)64 * K + k0);
        int4 bv0 = *(const int4*)(Bg + k0);
        int4 bv1 = *(const int4*)(Bg + (size_t)64 * K + k0);
        __syncthreads();
        *(int4*)(As + sr * 32 + swz)        = av0;
        *(int4*)(As + (sr + 64) * 32 + swz) = av1;
        *(int4*)(Bs + sr * 32 + swz)        = bv0;
        *(int4*)(Bs + (sr + 64) * 32 + swz) = bv1;
        __syncthreads();
        bf16x8 af[4], bfr[4];
#pragma unroll
        for (int i = 0; i < 4; i++)
            af[i] = *(const bf16x8*)(As + (wm * 64 + i * 16 + l16) * 32 + rphys);
#pragma unroll
        for (int j = 0; j < 4; j++)
            bfr[j] = *(const bf16x8*)(Bs + (wn * 64 + j * 16 + l16) * 32 + rphys);
#pragma unroll
        for (int i = 0; i < 4; i++)
#pragma unroll
            for (int j = 0; j < 4; j++)
                acc[i][j] = __builtin_amdgcn_mfma_f32_16x16x32_bf16(af[i], bfr[j], acc[i][j], 0, 0, 0);
    }

    const int crow0 = bm * 128 + wm * 64 + quad * 4;
    const int ccol0 = bn * 128 + wn * 64 + l16;
#pragma unroll
    for (int i = 0; i < 4; i++)
#pragma unroll
        for (int j = 0; j < 4; j++)
#pragma unroll
            for (int r = 0; r < 4; r++)
                C[(size_t)(crow0 + i * 16 + r) * N + ccol0 + j * 16] = f2bf(acc[i][j][r]);
}

// ---------------- aggregation: one wave per node, XCD-pinned per graph -----------
// graph = blockIdx & 7 so (heuristic round-robin) all waves of graph g land on
// XCD g: the graph's 3.2 MB xw slice fits that XCD's 4 MiB L2.
__global__ void agg_kernel(const u16* __restrict__ xw, u16* __restrict__ xo,
                           const int* __restrict__ rowptr, const int* __restrict__ col,
                           const float* __restrict__ nrm, const float* __restrict__ dinv,
                           const float* __restrict__ bias) {
    int wave = threadIdx.x >> 6;
    int lane = threadIdx.x & 63;
    int g  = blockIdx.x & 7;
    int nl = (blockIdx.x >> 3) * 4 + wave;
    if (nl >= NP_G) return;
    int w = g * NP_G + nl;
    int f = lane * 4;
    size_t ro = (size_t)w * HID + f;
    float di = dinv[w], sw = di * di;
    ushort4 sv = *(const ushort4*)(xw + ro);
    float a0 = sw * bf2f(sv.x), a1 = sw * bf2f(sv.y);
    float a2 = sw * bf2f(sv.z), a3 = sw * bf2f(sv.w);
    int p = rowptr[w], p1 = rowptr[w + 1];
    for (; p + 4 <= p1; p += 4) {
        int s0 = col[p], s1 = col[p + 1], s2 = col[p + 2], s3 = col[p + 3];
        float w0 = nrm[p], w1 = nrm[p + 1], w2 = nrm[p + 2], w3 = nrm[p + 3];
        ushort4 v0 = *(const ushort4*)(xw + (size_t)s0 * HID + f);
        ushort4 v1 = *(const ushort4*)(xw + (size_t)s1 * HID + f);
        ushort4 v2 = *(const ushort4*)(xw + (size_t)s2 * HID + f);
        ushort4 v3 = *(const ushort4*)(xw + (size_t)s3 * HID + f);
        a0 += w0 * bf2f(v0.x) + w1 * bf2f(v1.x) + w2 * bf2f(v2.x) + w3 * bf2f(v3.x);
        a1 += w0 * bf2f(v0.y) + w1 * bf2f(v1.y) + w2 * bf2f(v2.y) + w3 * bf2f(v3.y);
        a2 += w0 * bf2f(v0.z) + w1 * bf2f(v1.z) + w2 * bf2f(v2.z) + w3 * bf2f(v3.z);
        a3 += w0 * bf2f(v0.w) + w1 * bf2f(v1.w) + w2 * bf2f(v2.w) + w3 * bf2f(v3.w);
    }
    for (; p < p1; ++p) {
        int s0 = col[p]; float w0 = nrm[p];
        ushort4 v0 = *(const ushort4*)(xw + (size_t)s0 * HID + f);
        a0 += w0 * bf2f(v0.x); a1 += w0 * bf2f(v0.y);
        a2 += w0 * bf2f(v0.z); a3 += w0 * bf2f(v0.w);
    }
    float4 b = *(const float4*)(bias + f);
    a0 = fmaxf(a0 + b.x, 0.f); a1 = fmaxf(a1 + b.y, 0.f);
    a2 = fmaxf(a2 + b.z, 0.f); a3 = fmaxf(a3 + b.w, 0.f);
    ushort4 o; o.x = f2bf(a0); o.y = f2bf(a1); o.z = f2bf(a2); o.w = f2bf(a3);
    *(ushort4*)(xo + ro) = o;
}

// ---------------- score + keys (one wave per node) ----------------
__global__ void score_kernel(const u16* __restrict__ x1, const u16* __restrict__ x2,
                             const u16* __restrict__ x3, const float* __restrict__ pw,
                             const float* __restrict__ invn, float* __restrict__ score,
                             unsigned long long* __restrict__ keys) {
    int w = (blockIdx.x * blockDim.x + threadIdx.x) >> 6;
    int lane = threadIdx.x & 63;
    if (w >= NODES) return;
    int f = lane * 4;
    float acc = 0.f;
    {
        ushort4 v = *(const ushort4*)(x1 + (size_t)w * HID + f);
        float4 q = *(const float4*)(pw + f);
        acc += bf2f(v.x) * q.x + bf2f(v.y) * q.y + bf2f(v.z) * q.z + bf2f(v.w) * q.w;
    }
    {
        ushort4 v = *(const ushort4*)(x2 + (size_t)w * HID + f);
        float4 q = *(const float4*)(pw + 256 + f);
        acc += bf2f(v.x) * q.x + bf2f(v.y) * q.y + bf2f(v.z) * q.z + bf2f(v.w) * q.w;
    }
    {
        ushort4 v = *(const ushort4*)(x3 + (size_t)w * HID + f);
        float4 q = *(const float4*)(pw + 512 + f);
        acc += bf2f(v.x) * q.x + bf2f(v.y) * q.y + bf2f(v.z) * q.z + bf2f(v.w) * q.w;
    }
    for (int off = 32; off; off >>= 1) acc += __shfl_down(acc, off);
    if (lane == 0) {
        float s = acc * invn[0];
        float sc = 1.f / (1.f + __expf(-s));
        score[w] = sc;
        int li = w % NP_G;
        keys[w] = ((unsigned long long)__float_as_uint(sc) << 13) |
                  (unsigned int)(NP_G - 1 - li);
    }
}

// ---------------- exact top-K threshold per graph (radix select, distinct keys) ----
__global__ __launch_bounds__(1024) void select_kernel(
        const unsigned long long* __restrict__ keys,
        unsigned long long* __restrict__ kth) {
    __shared__ unsigned long long kk[NP_G];          // 50 KB
    __shared__ unsigned int hist[4][256];
    __shared__ unsigned int sfx[257];
    __shared__ unsigned long long spref;
    __shared__ unsigned int swant;
    int g = blockIdx.x, t = threadIdx.x;
    const unsigned long long* kg = keys + (size_t)g * NP_G;
    for (int i = t; i < NP_G; i += 1024) kk[i] = kg[i];
    if (t == 0) { spref = 0ull; swant = KKEEP; }
    const int wgrp = (t >> 8) & 3;                   // 4 groups of 4 waves
    unsigned long long mask = 0ull;
    __syncthreads();
    for (int shift = 40; shift >= 0; shift -= 8) {
        if (t < 256) { hist[0][t] = 0; hist[1][t] = 0; hist[2][t] = 0; hist[3][t] = 0; }
        __syncthreads();
        unsigned long long pref = spref;
        for (int i = t; i < NP_G; i += 1024) {
            unsigned long long key = kk[i];
            if ((key & mask) == pref)
                atomicAdd(&hist[wgrp][(unsigned int)(key >> shift) & 255u], 1u);
        }
        __syncthreads();
        if (t < 256) sfx[t] = hist[0][t] + hist[1][t] + hist[2][t] + hist[3][t];
        if (t == 0) sfx[256] = 0;
        __syncthreads();
        // reversed Hillis-Steele inclusive scan: sfx[t] = sum_{b>=t} cnt[b]
        for (int off = 1; off < 256; off <<= 1) {
            unsigned int v = 0;
            if (t < 256 && t + off < 256) v = sfx[t + off];
            __syncthreads();
            if (t < 256 && t + off < 256) sfx[t] += v;
            __syncthreads();
        }
        unsigned int want = swant;                   // all read before any write
        __syncthreads();
        if (t < 256) {
            unsigned int s0 = sfx[t], s1 = sfx[t + 1];
            if (s0 >= want && s1 < want) {           // unique t (sfx nonincreasing)
                spref = pref | ((unsigned long long)t << shift);
                swant = want - s1;
            }
        }
        __syncthreads();
        mask |= (255ull << shift);
    }
    if (t == 0) kth[g] = spref;
}

// ---------------- stable compaction of selected nodes (sorted by node id) --------
__global__ __launch_bounds__(1024) void compact_kernel(
        const unsigned long long* __restrict__ keys,
        const unsigned long long* __restrict__ kth,
        const float* __restrict__ score,
        int* __restrict__ selidx, float* __restrict__ selscr) {
    int g = blockIdx.x, t = threadIdx.x;
    int lane = t & 63, wv = t >> 6;
    __shared__ int wsum[16];
    __shared__ int base;
    if (t == 0) base = 0;
    unsigned long long kg = kth[g];
    __syncthreads();
    for (int k = 0; k < (NP_G + 1023) / 1024; ++k) {
        int i = k * 1024 + t;
        bool sel = false; int n = 0; float sc = 0.f;
        if (i < NP_G) {
            n = g * NP_G + i;
            sel = keys[n] >= kg;
            if (sel) sc = score[n];
        }
        u64 bal = __ballot(sel);
        int prefix = __popcll(bal & ((1ull << lane) - 1ull));
        if (lane == 0) wsum[wv] = __popcll(bal);
        __syncthreads();
        if (t == 0) {
            int s = base;
            for (int j = 0; j < 16; ++j) { int tmp = wsum[j]; wsum[j] = s; s += tmp; }
            base = s;
        }
        __syncthreads();
        if (sel) {
            int pos = wsum[wv] + prefix;
            selidx[g * KKEEP + pos] = n;
            selscr[g * KKEEP + pos] = sc;
        }
        __syncthreads();
    }
}

// ---------------- readout: branch-free gather over compacted list ----------------
__global__ __launch_bounds__(256) void readout_kernel(
        const u16* __restrict__ x1, const u16* __restrict__ x2,
        const u16* __restrict__ x3,
        const int* __restrict__ selidx, const float* __restrict__ selscr,
        float* __restrict__ sumbuf, int* __restrict__ maxbuf) {
    int g = blockIdx.x, tpart = blockIdx.y, c = blockIdx.z;
    int fcol = threadIdx.x;
    const u16* xt = (tpart == 0) ? x1 : ((tpart == 1) ? x2 : x3);
    __shared__ int   sidx[RCHUNK];
    __shared__ float sscr[RCHUNK];
    int base = g * KKEEP + c * RCHUNK;
    if (fcol < RCHUNK) { sidx[fcol] = selidx[base + fcol]; sscr[fcol] = selscr[base + fcol]; }
    __syncthreads();
    float sum = 0.f, mx = 0.f;
#pragma unroll 1
    for (int j = 0; j < RCHUNK; j += 4) {
        int n0 = sidx[j], n1 = sidx[j + 1], n2 = sidx[j + 2], n3 = sidx[j + 3];
        float s0 = sscr[j], s1 = sscr[j + 1], s2 = sscr[j + 2], s3 = sscr[j + 3];
        float v0 = bf2f(xt[(size_t)n0 * HID + fcol]) * s0;
        float v1 = bf2f(xt[(size_t)n1 * HID + fcol]) * s1;
        float v2 = bf2f(xt[(size_t)n2 * HID + fcol]) * s2;
        float v3 = bf2f(xt[(size_t)n3 * HID + fcol]) * s3;
        sum += v0 + v1 + v2 + v3;
        mx = fmaxf(mx, fmaxf(fmaxf(v0, v1), fmaxf(v2, v3)));
    }
    int o = (g * 3 + tpart) * HID + fcol;
    atomicAdd(&sumbuf[o], sum);
    atomicMax(&maxbuf[o], __float_as_int(mx));   // all v >= 0, int order == float order
}

// ---------------- final MLP: [8,1536] -> 256 -> 128 -> 3 ----------------
__global__ __launch_bounds__(256) void mlp_kernel(const float* __restrict__ sumbuf,
                                                  const int* __restrict__ maxbuf,
                                                  const float* __restrict__ lw1,
                                                  const float* __restrict__ lb1,
                                                  const float* __restrict__ lw2,
                                                  const float* __restrict__ lb2,
                                                  const float* __restrict__ lw3,
                                                  const float* __restrict__ lb3,
                                                  float* __restrict__ out) {
    __shared__ float r[1536];
    __shared__ float h1[256];
    __shared__ float h2[128];
    int g = blockIdx.x, t = threadIdx.x;
    for (int i = t; i < 768; i += 256) {
        r[i]       = sumbuf[g * 768 + i] * (1.f / 5000.f);
        r[768 + i] = __int_as_float(maxbuf[g * 768 + i]);
    }
    __syncthreads();
    float a = lb1[t];
    for (int i = 0; i < 1536; ++i) a += r[i] * lw1[(size_t)i * 256 + t];
    h1[t] = fmaxf(a, 0.f);
    __syncthreads();
    if (t < 128) {
        float a2 = lb2[t];
        for (int i = 0; i < 256; ++i) a2 += h1[i] * lw2[i * 128 + t];
        h2[t] = fmaxf(a2, 0.f);
    }
    __syncthreads();
    if (t < 3) {
        float a3 = lb3[t];
        for (int i = 0; i < 128; ++i) a3 += h2[i] * lw3[i * 3 + t];
        out[g * 3 + t] = a3;
    }
}

extern "C" void kernel_launch(void* const* d_in, const int* in_sizes, int n_in,
                              void* d_out, int out_size, void* d_ws, size_t ws_size,
                              hipStream_t stream) {
    const float* x   = (const float*)d_in[0];
    const int*   ei  = (const int*)d_in[1];
    const float* ew  = (const float*)d_in[2];
    const float* W1  = (const float*)d_in[4];
    const float* b1  = (const float*)d_in[5];
    const float* W2  = (const float*)d_in[6];
    const float* b2  = (const float*)d_in[7];
    const float* pw  = (const float*)d_in[8];
    const float* lw1 = (const float*)d_in[9];
    const float* lb1 = (const float*)d_in[10];
    const float* lw2 = (const float*)d_in[11];
    const float* lb2 = (const float*)d_in[12];
    const float* lw3 = (const float*)d_in[13];
    const float* lb3 = (const float*)d_in[14];
    float* out = (float*)d_out;

    char* p = (char*)d_ws;
    auto alloc = [&](size_t bytes) -> char* {
        char* r = p;
        p += (bytes + 255) & ~(size_t)255;
        return r;
    };
    u16* A0  = (u16*)alloc((size_t)MPAD * CIN * 2);   // x bf16; x1/x2 alias after GEMM1
    u16* x3  = (u16*)alloc((size_t)MPAD * HID * 2);
    u16* xw  = (u16*)alloc((size_t)MPAD * HID * 2);
    u16* Wt1 = (u16*)alloc((size_t)HID * CIN * 2);
    u16* Wt2 = (u16*)alloc((size_t)HID * HID * 2);
    int*   col    = (int*)alloc((size_t)EDGES * 4);
    float* nrm    = (float*)alloc((size_t)EDGES * 4);
    int*   rowptr = (int*)alloc((size_t)(NODES + 1) * 4);
    int*   rowcur = (int*)alloc((size_t)NODES * 4);
    int*   iscan  = (int*)alloc((size_t)NODES * 4);
    int*   bsum   = (int*)alloc((size_t)SCANB * 4);
    int*   boff   = (int*)alloc((size_t)SCANB * 4);
    unsigned long long* keys = (unsigned long long*)alloc((size_t)NODES * 8);
    float* score = (float*)alloc((size_t)NODES * 4);
    float* dinv  = (float*)alloc((size_t)NODES * 4);
    int*   selidx = (int*)alloc((size_t)NGRAPH * KKEEP * 4);
    float* selscr = (float*)alloc((size_t)NGRAPH * KKEEP * 4);
    unsigned long long* kth = (unsigned long long*)alloc(64);
    float* invn = (float*)alloc(256);
    char* zbase = p;                                  // everything below is zero-init
    u64*   degcnt = (u64*)alloc((size_t)NODES * 8);
    float* sumbuf = (float*)alloc(6144 * 4);
    int*   maxbuf = (int*)alloc(6144 * 4);
    size_t zbytes = (size_t)(p - zbase);

    u16* x1 = A0;                         // reuse A0 after GEMM1 consumed it
    u16* x2 = A0 + (size_t)MPAD * HID;

    hipMemsetAsync(zbase, 0, zbytes, stream);

    cast_x_kernel<<<(MPAD * CIN / 4 + 255) / 256, 256, 0, stream>>>(x, A0);
    cast_w_kernel<<<(HID * CIN + 255) / 256, 256, 0, stream>>>(W1, Wt1, CIN, HID);
    cast_w_kernel<<<(HID * HID + 255) / 256, 256, 0, stream>>>(W2, Wt2, HID, HID);
    pwnorm_kernel<<<1, 256, 0, stream>>>(pw, invn);
    zero_pad_kernel<<<48, 256, 0, stream>>>(x1, x2, x3);

    edge_pass1<<<(EDGES + 255) / 256, 256, 0, stream>>>(ei, ew, degcnt);
    dinv_kernel<<<(NODES + 255) / 256, 256, 0, stream>>>(degcnt, dinv);
    scan1_kernel<<<SCANB, 256, 0, stream>>>(degcnt, iscan, bsum);
    scan2_kernel<<<1, 256, 0, stream>>>(bsum, boff);
    scan3_kernel<<<SCANB + 1, 256, 0, stream>>>(degcnt, iscan, boff, rowptr, rowcur);
    fill_kernel<<<(EDGES + 255) / 256, 256, 0, stream>>>(ei, ew, dinv, rowcur, col, nrm);

    dim3 gg(MPAD / 128, HID / 128);
    int aggBlocks = 8 * ((NP_G + 3) / 4);   // graph = blockIdx & 7 (XCD pinning)

    gemm_bt<<<gg, 256, 0, stream>>>(A0, Wt1, xw, MPAD, HID, CIN);
    agg_kernel<<<aggBlocks, 256, 0, stream>>>(xw, x1, rowptr, col, nrm, dinv, b1);
    gemm_bt<<<gg, 256, 0, stream>>>(x1, Wt2, xw, MPAD, HID, HID);
    agg_kernel<<<aggBlocks, 256, 0, stream>>>(xw, x2, rowptr, col, nrm, dinv, b2);
    gemm_bt<<<gg, 256, 0, stream>>>(x2, Wt2, xw, MPAD, HID, HID);
    agg_kernel<<<aggBlocks, 256, 0, stream>>>(xw, x3, rowptr, col, nrm, dinv, b2);

    int scBlocks = (NODES * 64 + 255) / 256;
    score_kernel<<<scBlocks, 256, 0, stream>>>(x1, x2, x3, pw, invn, score, keys);
    select_kernel<<<NGRAPH, 1024, 0, stream>>>(keys, kth);
    compact_kernel<<<NGRAPH, 1024, 0, stream>>>(keys, kth, score, selidx, selscr);
    readout_kernel<<<dim3(NGRAPH, 3, KKEEP / RCHUNK), 256, 0, stream>>>(
        x1, x2, x3, selidx, selscr, sumbuf, maxbuf);
    mlp_kernel<<<NGRAPH, 256, 0, stream>>>(sumbuf, maxbuf, lw1, lb1, lw2, lb2, lw3, lb3, out);
}

// Round 5
// 584.082 us; speedup vs baseline: 1.5431x; 1.0661x over previous
//
#include <hip/hip_runtime.h>
#include <stdint.h>

#define NODES  50000
#define MPAD   50048      // 391 * 128
#define NGRAPH 8
#define NP_G   6250
#define EDGES  800000
#define KKEEP  5000
#define HID    256
#define CIN    512
#define H3     768
#define SCANB  196        // 196*256 = 50176 >= NODES
#define RCHUNK 200        // KKEEP / 25
#define MLPCH  24         // layer-1 k-chunks
#define MLPCK  64         // 1536 / 24

using f32x4  = __attribute__((ext_vector_type(4))) float;
using bf16x8 = __attribute__((ext_vector_type(8))) short;
typedef unsigned short u16;
typedef unsigned long long u64;

__device__ __forceinline__ float bf2f(u16 u) {
    return __uint_as_float(((uint32_t)u) << 16);
}
__device__ __forceinline__ u16 f2bf(float f) {     // RNE
    uint32_t u = __float_as_uint(f);
    u += 0x7fffu + ((u >> 16) & 1u);
    return (u16)(u >> 16);
}

// ---------------- casts ----------------
__global__ void cast_x_kernel(const float* __restrict__ x, u16* __restrict__ A0) {
    size_t i4 = (size_t)blockIdx.x * blockDim.x + threadIdx.x;
    size_t base = i4 * 4;
    if (base >= (size_t)MPAD * CIN) return;
    int row = (int)(base >> 9);   // /512
    ushort4 o;
    if (row < NODES) {
        float4 v = *(const float4*)(x + base);
        o.x = f2bf(v.x); o.y = f2bf(v.y); o.z = f2bf(v.z); o.w = f2bf(v.w);
    } else {
        o.x = 0; o.y = 0; o.z = 0; o.w = 0;
    }
    *(ushort4*)(A0 + base) = o;
}

// W [K,N] f32 -> Wt [N,K] bf16
__global__ void cast_w_kernel(const float* __restrict__ W, u16* __restrict__ Wt,
                              int K, int N) {
    int id = blockIdx.x * blockDim.x + threadIdx.x;
    if (id >= N * K) return;
    int n = id / K, k = id - n * K;
    Wt[id] = f2bf(W[(size_t)k * N + n]);
}

// zero the padding rows of x1/x2/x3 (agg no longer writes them)
__global__ void zero_pad_kernel(u16* __restrict__ a, u16* __restrict__ b,
                                u16* __restrict__ c) {
    int i = blockIdx.x * blockDim.x + threadIdx.x;   // 0 .. 48*256-1
    if (i >= (MPAD - NODES) * HID) return;
    size_t o = (size_t)NODES * HID + i;
    a[o] = 0; b[o] = 0; c[o] = 0;
}

__global__ void pwnorm_kernel(const float* __restrict__ pw, float* __restrict__ invn) {
    __shared__ float sh[256];
    int t = threadIdx.x;
    float s = 0.f;
    for (int i = t; i < H3; i += 256) { float v = pw[i]; s += v * v; }
    sh[t] = s; __syncthreads();
    for (int off = 128; off; off >>= 1) {
        if (t < off) sh[t] += sh[t + off];
        __syncthreads();
    }
    if (t == 0) invn[0] = rsqrtf(sh[0]);
}

// ---------------- graph prep ----------------
// one u64 atomic per edge: (count << 48) | fixed-point(ew, 2^-32)
__global__ void edge_pass1(const int* __restrict__ ei, const float* __restrict__ ew,
                           u64* __restrict__ degcnt) {
    int e = blockIdx.x * blockDim.x + threadIdx.x;
    if (e >= EDGES) return;
    int d = ei[EDGES + e];
    u64 enc = (1ull << 48) | (u64)(ew[e] * 4294967296.0f);
    atomicAdd(&degcnt[d], enc);
}

__global__ void dinv_kernel(const u64* __restrict__ degcnt, float* __restrict__ dinv) {
    int n = blockIdx.x * blockDim.x + threadIdx.x;
    if (n >= NODES) return;
    float deg = (float)(degcnt[n] & 0xFFFFFFFFFFFFull) * (1.0f / 4294967296.0f);
    dinv[n] = rsqrtf(deg + 1.0f);
}

// ---- hierarchical exclusive scan of per-node counts -> rowptr (+ rowcur copy) ----
__global__ void scan1_kernel(const u64* __restrict__ degcnt,
                             int* __restrict__ iscan, int* __restrict__ bsum) {
    int b = blockIdx.x, t = threadIdx.x;
    int i = b * 256 + t;
    int c = (i < NODES) ? (int)(degcnt[i] >> 48) : 0;
    int lane = t & 63, wv = t >> 6;
    int v = c;
    for (int off = 1; off < 64; off <<= 1) {
        int u = __shfl_up(v, off);
        if (lane >= off) v += u;
    }
    __shared__ int ws[4];
    if (lane == 63) ws[wv] = v;
    __syncthreads();
    if (t == 0) { int s = 0; for (int k = 0; k < 4; k++) { int tmp = ws[k]; ws[k] = s; s += tmp; } }
    __syncthreads();
    v += ws[wv];
    if (i < NODES) iscan[i] = v;          // block-local inclusive scan
    if (t == 255) bsum[b] = v;            // block total (OOB lanes contribute 0)
}

__global__ void scan2_kernel(const int* __restrict__ bsum, int* __restrict__ boff) {
    int t = threadIdx.x;
    int c = (t < SCANB) ? bsum[t] : 0;
    int lane = t & 63, wv = t >> 6;
    int v = c;
    for (int off = 1; off < 64; off <<= 1) {
        int u = __shfl_up(v, off);
        if (lane >= off) v += u;
    }
    __shared__ int ws[4];
    if (lane == 63) ws[wv] = v;
    __syncthreads();
    if (t == 0) { int s = 0; for (int k = 0; k < 4; k++) { int tmp = ws[k]; ws[k] = s; s += tmp; } }
    __syncthreads();
    v += ws[wv];
    if (t < SCANB) boff[t] = v - c;       // exclusive
}

__global__ void scan3_kernel(const u64* __restrict__ degcnt,
                             const int* __restrict__ iscan, const int* __restrict__ boff,
                             int* __restrict__ rowptr, int* __restrict__ rowcur) {
    int b = blockIdx.x, t = threadIdx.x;
    int i = b * 256 + t;
    if (i > NODES) return;
    if (i == NODES) { rowptr[NODES] = EDGES; return; }
    int c = (int)(degcnt[i] >> 48);
    int v = boff[b] + iscan[i] - c;       // global exclusive scan
    rowptr[i] = v;
    rowcur[i] = v;
}

__global__ void fill_kernel(const int* __restrict__ ei, const float* __restrict__ ew,
                            const float* __restrict__ dinv,
                            int* __restrict__ rowcur, int* __restrict__ col,
                            float* __restrict__ nrm) {
    int e = blockIdx.x * blockDim.x + threadIdx.x;
    if (e >= EDGES) return;
    int s = ei[e], d = ei[EDGES + e];
    int pos = atomicAdd(&rowcur[d], 1);
    col[pos] = s;
    nrm[pos] = dinv[s] * ew[e] * dinv[d];
}

// ---------------- GEMM: C[M,N] = A[M,K] @ Bt[N,K]^T  (all bf16, fp32 acc) ---------
__global__ __launch_bounds__(256) void gemm_bt(const u16* __restrict__ A,
                                               const u16* __restrict__ Bt,
                                               u16* __restrict__ C,
                                               int M, int N, int K) {
    __shared__ u16 As[128 * 32];
    __shared__ u16 Bs[128 * 32];
    const int tid  = threadIdx.x;
    const int wave = tid >> 6, lane = tid & 63;
    const int wm = wave >> 1, wn = wave & 1;       // 2x2 waves over 128x128
    const int quad = lane >> 4, l16 = lane & 15;
    const int bm = blockIdx.x, bn = blockIdx.y;

    const int sr = tid >> 2;                        // staging row 0..63 (+64 second)
    const int sc = tid & 3;                         // 16B chunk within 64B row
    const int swz = (sc ^ ((sr >> 1) & 3)) * 8;     // (sr+64)>>1 has same low bits
    const int rphys = (quad ^ ((l16 >> 1) & 3)) * 8;

    const u16* Ag = A + (size_t)(bm * 128 + sr) * K + sc * 8;
    const u16* Bg = Bt + (size_t)(bn * 128 + sr) * K + sc * 8;

    f32x4 acc[4][4];
#pragma unroll
    for (int i = 0; i < 4; i++)
#pragma unroll
        for (int j = 0; j < 4; j++) { f32x4 z = {0.f, 0.f, 0.f, 0.f}; acc[i][j] = z; }

    for (int k0 = 0; k0 < K; k0 += 32) {
        int4 av0 = *(const int4*)(Ag + k0);
        int4 av1 = *(const int4*)(Ag + (size_t)64 * K + k0);
        int4 bv0 = *(const int4*)(Bg + k0);
        int4 bv1 = *(const int4*)(Bg + (size_t)64 * K + k0);
        __syncthreads();
        *(int4*)(As + sr * 32 + swz)        = av0;
        *(int4*)(As + (sr + 64) * 32 + swz) = av1;
        *(int4*)(Bs + sr * 32 + swz)        = bv0;
        *(int4*)(Bs + (sr + 64) * 32 + swz) = bv1;
        __syncthreads();
        bf16x8 af[4], bfr[4];
#pragma unroll
        for (int i = 0; i < 4; i++)
            af[i] = *(const bf16x8*)(As + (wm * 64 + i * 16 + l16) * 32 + rphys);
#pragma unroll
        for (int j = 0; j < 4; j++)
            bfr[j] = *(const bf16x8*)(Bs + (wn * 64 + j * 16 + l16) * 32 + rphys);
#pragma unroll
        for (int i = 0; i < 4; i++)
#pragma unroll
            for (int j = 0; j < 4; j++)
                acc[i][j] = __builtin_amdgcn_mfma_f32_16x16x32_bf16(af[i], bfr[j], acc[i][j], 0, 0, 0);
    }

    const int crow0 = bm * 128 + wm * 64 + quad * 4;
    const int ccol0 = bn * 128 + wn * 64 + l16;
#pragma unroll
    for (int i = 0; i < 4; i++)
#pragma unroll
        for (int j = 0; j < 4; j++)
#pragma unroll
            for (int r = 0; r < 4; r++)
                C[(size_t)(crow0 + i * 16 + r) * N + ccol0 + j * 16] = f2bf(acc[i][j][r]);
}

// ---------------- aggregation: one wave per node, XCD-pinned per graph -----------
__global__ void agg_kernel(const u16* __restrict__ xw, u16* __restrict__ xo,
                           const int* __restrict__ rowptr, const int* __restrict__ col,
                           const float* __restrict__ nrm, const float* __restrict__ dinv,
                           const float* __restrict__ bias) {
    int wave = threadIdx.x >> 6;
    int lane = threadIdx.x & 63;
    int g  = blockIdx.x & 7;
    int nl = (blockIdx.x >> 3) * 4 + wave;
    if (nl >= NP_G) return;
    int w = g * NP_G + nl;
    int f = lane * 4;
    size_t ro = (size_t)w * HID + f;
    float di = dinv[w], sw = di * di;
    ushort4 sv = *(const ushort4*)(xw + ro);
    float a0 = sw * bf2f(sv.x), a1 = sw * bf2f(sv.y);
    float a2 = sw * bf2f(sv.z), a3 = sw * bf2f(sv.w);
    int p = rowptr[w], p1 = rowptr[w + 1];
    for (; p + 4 <= p1; p += 4) {
        int s0 = col[p], s1 = col[p + 1], s2 = col[p + 2], s3 = col[p + 3];
        float w0 = nrm[p], w1 = nrm[p + 1], w2 = nrm[p + 2], w3 = nrm[p + 3];
        ushort4 v0 = *(const ushort4*)(xw + (size_t)s0 * HID + f);
        ushort4 v1 = *(const ushort4*)(xw + (size_t)s1 * HID + f);
        ushort4 v2 = *(const ushort4*)(xw + (size_t)s2 * HID + f);
        ushort4 v3 = *(const ushort4*)(xw + (size_t)s3 * HID + f);
        a0 += w0 * bf2f(v0.x) + w1 * bf2f(v1.x) + w2 * bf2f(v2.x) + w3 * bf2f(v3.x);
        a1 += w0 * bf2f(v0.y) + w1 * bf2f(v1.y) + w2 * bf2f(v2.y) + w3 * bf2f(v3.y);
        a2 += w0 * bf2f(v0.z) + w1 * bf2f(v1.z) + w2 * bf2f(v2.z) + w3 * bf2f(v3.z);
        a3 += w0 * bf2f(v0.w) + w1 * bf2f(v1.w) + w2 * bf2f(v2.w) + w3 * bf2f(v3.w);
    }
    for (; p < p1; ++p) {
        int s0 = col[p]; float w0 = nrm[p];
        ushort4 v0 = *(const ushort4*)(xw + (size_t)s0 * HID + f);
        a0 += w0 * bf2f(v0.x); a1 += w0 * bf2f(v0.y);
        a2 += w0 * bf2f(v0.z); a3 += w0 * bf2f(v0.w);
    }
    float4 b = *(const float4*)(bias + f);
    a0 = fmaxf(a0 + b.x, 0.f); a1 = fmaxf(a1 + b.y, 0.f);
    a2 = fmaxf(a2 + b.z, 0.f); a3 = fmaxf(a3 + b.w, 0.f);
    ushort4 o; o.x = f2bf(a0); o.y = f2bf(a1); o.z = f2bf(a2); o.w = f2bf(a3);
    *(ushort4*)(xo + ro) = o;
}

// ---------------- score + keys (one wave per node) ----------------
__global__ void score_kernel(const u16* __restrict__ x1, const u16* __restrict__ x2,
                             const u16* __restrict__ x3, const float* __restrict__ pw,
                             const float* __restrict__ invn, float* __restrict__ score,
                             unsigned long long* __restrict__ keys) {
    int w = (blockIdx.x * blockDim.x + threadIdx.x) >> 6;
    int lane = threadIdx.x & 63;
    if (w >= NODES) return;
    int f = lane * 4;
    float acc = 0.f;
    {
        ushort4 v = *(const ushort4*)(x1 + (size_t)w * HID + f);
        float4 q = *(const float4*)(pw + f);
        acc += bf2f(v.x) * q.x + bf2f(v.y) * q.y + bf2f(v.z) * q.z + bf2f(v.w) * q.w;
    }
    {
        ushort4 v = *(const ushort4*)(x2 + (size_t)w * HID + f);
        float4 q = *(const float4*)(pw + 256 + f);
        acc += bf2f(v.x) * q.x + bf2f(v.y) * q.y + bf2f(v.z) * q.z + bf2f(v.w) * q.w;
    }
    {
        ushort4 v = *(const ushort4*)(x3 + (size_t)w * HID + f);
        float4 q = *(const float4*)(pw + 512 + f);
        acc += bf2f(v.x) * q.x + bf2f(v.y) * q.y + bf2f(v.z) * q.z + bf2f(v.w) * q.w;
    }
    for (int off = 32; off; off >>= 1) acc += __shfl_down(acc, off);
    if (lane == 0) {
        float s = acc * invn[0];
        float sc = 1.f / (1.f + __expf(-s));
        score[w] = sc;
        int li = w % NP_G;
        keys[w] = ((unsigned long long)__float_as_uint(sc) << 13) |
                  (unsigned int)(NP_G - 1 - li);
    }
}

// ---------------- exact top-K threshold per graph (radix select, distinct keys) ----
__global__ __launch_bounds__(1024) void select_kernel(
        const unsigned long long* __restrict__ keys,
        unsigned long long* __restrict__ kth) {
    __shared__ unsigned long long kk[NP_G];          // 50 KB
    __shared__ unsigned int hist[4][256];
    __shared__ unsigned int sfx[257];
    __shared__ unsigned long long spref;
    __shared__ unsigned int swant;
    int g = blockIdx.x, t = threadIdx.x;
    const unsigned long long* kg = keys + (size_t)g * NP_G;
    for (int i = t; i < NP_G; i += 1024) kk[i] = kg[i];
    if (t == 0) { spref = 0ull; swant = KKEEP; }
    const int wgrp = (t >> 8) & 3;                   // 4 groups of 4 waves
    unsigned long long mask = 0ull;
    __syncthreads();
    for (int shift = 40; shift >= 0; shift -= 8) {
        if (t < 256) { hist[0][t] = 0; hist[1][t] = 0; hist[2][t] = 0; hist[3][t] = 0; }
        __syncthreads();
        unsigned long long pref = spref;
        for (int i = t; i < NP_G; i += 1024) {
            unsigned long long key = kk[i];
            if ((key & mask) == pref)
                atomicAdd(&hist[wgrp][(unsigned int)(key >> shift) & 255u], 1u);
        }
        __syncthreads();
        if (t < 256) sfx[t] = hist[0][t] + hist[1][t] + hist[2][t] + hist[3][t];
        if (t == 0) sfx[256] = 0;
        __syncthreads();
        // reversed Hillis-Steele inclusive scan: sfx[t] = sum_{b>=t} cnt[b]
        for (int off = 1; off < 256; off <<= 1) {
            unsigned int v = 0;
            if (t < 256 && t + off < 256) v = sfx[t + off];
            __syncthreads();
            if (t < 256 && t + off < 256) sfx[t] += v;
            __syncthreads();
        }
        unsigned int want = swant;                   // all read before any write
        __syncthreads();
        if (t < 256) {
            unsigned int s0 = sfx[t], s1 = sfx[t + 1];
            if (s0 >= want && s1 < want) {           // unique t (sfx nonincreasing)
                spref = pref | ((unsigned long long)t << shift);
                swant = want - s1;
            }
        }
        __syncthreads();
        mask |= (255ull << shift);
    }
    if (t == 0) kth[g] = spref;
}

// ---------------- stable compaction of selected nodes (sorted by node id) --------
__global__ __launch_bounds__(1024) void compact_kernel(
        const unsigned long long* __restrict__ keys,
        const unsigned long long* __restrict__ kth,
        const float* __restrict__ score,
        int* __restrict__ selidx, float* __restrict__ selscr) {
    int g = blockIdx.x, t = threadIdx.x;
    int lane = t & 63, wv = t >> 6;
    __shared__ int wsum[16];
    __shared__ int base;
    if (t == 0) base = 0;
    unsigned long long kg = kth[g];
    __syncthreads();
    for (int k = 0; k < (NP_G + 1023) / 1024; ++k) {
        int i = k * 1024 + t;
        bool sel = false; int n = 0; float sc = 0.f;
        if (i < NP_G) {
            n = g * NP_G + i;
            sel = keys[n] >= kg;
            if (sel) sc = score[n];
        }
        u64 bal = __ballot(sel);
        int prefix = __popcll(bal & ((1ull << lane) - 1ull));
        if (lane == 0) wsum[wv] = __popcll(bal);
        __syncthreads();
        if (t == 0) {
            int s = base;
            for (int j = 0; j < 16; ++j) { int tmp = wsum[j]; wsum[j] = s; s += tmp; }
            base = s;
        }
        __syncthreads();
        if (sel) {
            int pos = wsum[wv] + prefix;
            selidx[g * KKEEP + pos] = n;
            selscr[g * KKEEP + pos] = sc;
        }
        __syncthreads();
    }
}

// ---------------- readout: branch-free gather over compacted list ----------------
__global__ __launch_bounds__(256) void readout_kernel(
        const u16* __restrict__ x1, const u16* __restrict__ x2,
        const u16* __restrict__ x3,
        const int* __restrict__ selidx, const float* __restrict__ selscr,
        float* __restrict__ sumbuf, int* __restrict__ maxbuf) {
    int g = blockIdx.x, tpart = blockIdx.y, c = blockIdx.z;
    int fcol = threadIdx.x;
    const u16* xt = (tpart == 0) ? x1 : ((tpart == 1) ? x2 : x3);
    __shared__ int   sidx[RCHUNK];
    __shared__ float sscr[RCHUNK];
    int base = g * KKEEP + c * RCHUNK;
    if (fcol < RCHUNK) { sidx[fcol] = selidx[base + fcol]; sscr[fcol] = selscr[base + fcol]; }
    __syncthreads();
    float sum = 0.f, mx = 0.f;
#pragma unroll 1
    for (int j = 0; j < RCHUNK; j += 4) {
        int n0 = sidx[j], n1 = sidx[j + 1], n2 = sidx[j + 2], n3 = sidx[j + 3];
        float s0 = sscr[j], s1 = sscr[j + 1], s2 = sscr[j + 2], s3 = sscr[j + 3];
        float v0 = bf2f(xt[(size_t)n0 * HID + fcol]) * s0;
        float v1 = bf2f(xt[(size_t)n1 * HID + fcol]) * s1;
        float v2 = bf2f(xt[(size_t)n2 * HID + fcol]) * s2;
        float v3 = bf2f(xt[(size_t)n3 * HID + fcol]) * s3;
        sum += v0 + v1 + v2 + v3;
        mx = fmaxf(mx, fmaxf(fmaxf(v0, v1), fmaxf(v2, v3)));
    }
    int o = (g * 3 + tpart) * HID + fcol;
    atomicAdd(&sumbuf[o], sum);
    atomicMax(&maxbuf[o], __float_as_int(mx));   // all v >= 0, int order == float order
}

// ---------------- MLP layer 1, k-split: h1acc[g][t] += sum over 64-chunk ---------
__global__ __launch_bounds__(256) void mlp1_kernel(const float* __restrict__ sumbuf,
                                                   const int* __restrict__ maxbuf,
                                                   const float* __restrict__ lw1,
                                                   float* __restrict__ h1acc) {
    int g = blockIdx.x, ch = blockIdx.y, t = threadIdx.x;
    __shared__ float r[MLPCK];
    int k0 = ch * MLPCK;
    if (t < MLPCK) {
        int i = k0 + t;
        // chunks 0..11 cover mean (sumbuf), 12..23 cover max (maxbuf); no chunk straddles
        r[t] = (i < 768) ? sumbuf[g * 768 + i] * (1.f / 5000.f)
                         : __int_as_float(maxbuf[g * 768 + (i - 768)]);
    }
    __syncthreads();
    float a0 = 0.f, a1 = 0.f, a2 = 0.f, a3 = 0.f;
#pragma unroll
    for (int i = 0; i < MLPCK; i += 4) {
        a0 += r[i]     * lw1[(size_t)(k0 + i)     * 256 + t];
        a1 += r[i + 1] * lw1[(size_t)(k0 + i + 1) * 256 + t];
        a2 += r[i + 2] * lw1[(size_t)(k0 + i + 2) * 256 + t];
        a3 += r[i + 3] * lw1[(size_t)(k0 + i + 3) * 256 + t];
    }
    atomicAdd(&h1acc[g * 256 + t], (a0 + a1) + (a2 + a3));
}

// ---------------- MLP layers 2+3 ----------------
__global__ __launch_bounds__(256) void mlp2_kernel(const float* __restrict__ h1acc,
                                                   const float* __restrict__ lb1,
                                                   const float* __restrict__ lw2,
                                                   const float* __restrict__ lb2,
                                                   const float* __restrict__ lw3,
                                                   const float* __restrict__ lb3,
                                                   float* __restrict__ out) {
    __shared__ float h1[256];
    __shared__ float part[256];
    __shared__ float h2[128];
    int g = blockIdx.x, t = threadIdx.x;
    h1[t] = fmaxf(h1acc[g * 256 + t] + lb1[t], 0.f);
    __syncthreads();
    int col = t & 127, half = t >> 7;    // 2-way k-split of the 256-reduction
    float a = 0.f;
#pragma unroll
    for (int i = 0; i < 128; i += 4) {
        int k = half * 128 + i;
        a += h1[k]     * lw2[k * 128 + col]
           + h1[k + 1] * lw2[(k + 1) * 128 + col]
           + h1[k + 2] * lw2[(k + 2) * 128 + col]
           + h1[k + 3] * lw2[(k + 3) * 128 + col];
    }
    part[t] = a;
    __syncthreads();
    if (t < 128) h2[t] = fmaxf(part[t] + part[t + 128] + lb2[t], 0.f);
    __syncthreads();
    if (t < 3) {
        float a3 = lb3[t];
        for (int i = 0; i < 128; ++i) a3 += h2[i] * lw3[i * 3 + t];
        out[g * 3 + t] = a3;
    }
}

extern "C" void kernel_launch(void* const* d_in, const int* in_sizes, int n_in,
                              void* d_out, int out_size, void* d_ws, size_t ws_size,
                              hipStream_t stream) {
    const float* x   = (const float*)d_in[0];
    const int*   ei  = (const int*)d_in[1];
    const float* ew  = (const float*)d_in[2];
    const float* W1  = (const float*)d_in[4];
    const float* b1  = (const float*)d_in[5];
    const float* W2  = (const float*)d_in[6];
    const float* b2  = (const float*)d_in[7];
    const float* pw  = (const float*)d_in[8];
    const float* lw1 = (const float*)d_in[9];
    const float* lb1 = (const float*)d_in[10];
    const float* lw2 = (const float*)d_in[11];
    const float* lb2 = (const float*)d_in[12];
    const float* lw3 = (const float*)d_in[13];
    const float* lb3 = (const float*)d_in[14];
    float* out = (float*)d_out;

    char* p = (char*)d_ws;
    auto alloc = [&](size_t bytes) -> char* {
        char* r = p;
        p += (bytes + 255) & ~(size_t)255;
        return r;
    };
    u16* A0  = (u16*)alloc((size_t)MPAD * CIN * 2);   // x bf16; x1/x2 alias after GEMM1
    u16* x3  = (u16*)alloc((size_t)MPAD * HID * 2);
    u16* xw  = (u16*)alloc((size_t)MPAD * HID * 2);
    u16* Wt1 = (u16*)alloc((size_t)HID * CIN * 2);
    u16* Wt2 = (u16*)alloc((size_t)HID * HID * 2);
    int*   col    = (int*)alloc((size_t)EDGES * 4);
    float* nrm    = (float*)alloc((size_t)EDGES * 4);
    int*   rowptr = (int*)alloc((size_t)(NODES + 1) * 4);
    int*   rowcur = (int*)alloc((size_t)NODES * 4);
    int*   iscan  = (int*)alloc((size_t)NODES * 4);
    int*   bsum   = (int*)alloc((size_t)SCANB * 4);
    int*   boff   = (int*)alloc((size_t)SCANB * 4);
    unsigned long long* keys = (unsigned long long*)alloc((size_t)NODES * 8);
    float* score = (float*)alloc((size_t)NODES * 4);
    float* dinv  = (float*)alloc((size_t)NODES * 4);
    int*   selidx = (int*)alloc((size_t)NGRAPH * KKEEP * 4);
    float* selscr = (float*)alloc((size_t)NGRAPH * KKEEP * 4);
    unsigned long long* kth = (unsigned long long*)alloc(64);
    float* invn = (float*)alloc(256);
    char* zbase = p;                                  // everything below is zero-init
    u64*   degcnt = (u64*)alloc((size_t)NODES * 8);
    float* sumbuf = (float*)alloc(6144 * 4);
    int*   maxbuf = (int*)alloc(6144 * 4);
    float* h1acc  = (float*)alloc((size_t)NGRAPH * 256 * 4);
    size_t zbytes = (size_t)(p - zbase);

    u16* x1 = A0;                         // reuse A0 after GEMM1 consumed it
    u16* x2 = A0 + (size_t)MPAD * HID;

    hipMemsetAsync(zbase, 0, zbytes, stream);

    cast_x_kernel<<<(MPAD * CIN / 4 + 255) / 256, 256, 0, stream>>>(x, A0);
    cast_w_kernel<<<(HID * CIN + 255) / 256, 256, 0, stream>>>(W1, Wt1, CIN, HID);
    cast_w_kernel<<<(HID * HID + 255) / 256, 256, 0, stream>>>(W2, Wt2, HID, HID);
    pwnorm_kernel<<<1, 256, 0, stream>>>(pw, invn);
    zero_pad_kernel<<<48, 256, 0, stream>>>(x1, x2, x3);

    edge_pass1<<<(EDGES + 255) / 256, 256, 0, stream>>>(ei, ew, degcnt);
    dinv_kernel<<<(NODES + 255) / 256, 256, 0, stream>>>(degcnt, dinv);
    scan1_kernel<<<SCANB, 256, 0, stream>>>(degcnt, iscan, bsum);
    scan2_kernel<<<1, 256, 0, stream>>>(bsum, boff);
    scan3_kernel<<<SCANB + 1, 256, 0, stream>>>(degcnt, iscan, boff, rowptr, rowcur);
    fill_kernel<<<(EDGES + 255) / 256, 256, 0, stream>>>(ei, ew, dinv, rowcur, col, nrm);

    dim3 gg(MPAD / 128, HID / 128);
    int aggBlocks = 8 * ((NP_G + 3) / 4);   // graph = blockIdx & 7 (XCD pinning)

    gemm_bt<<<gg, 256, 0, stream>>>(A0, Wt1, xw, MPAD, HID, CIN);
    agg_kernel<<<aggBlocks, 256, 0, stream>>>(xw, x1, rowptr, col, nrm, dinv, b1);
    gemm_bt<<<gg, 256, 0, stream>>>(x1, Wt2, xw, MPAD, HID, HID);
    agg_kernel<<<aggBlocks, 256, 0, stream>>>(xw, x2, rowptr, col, nrm, dinv, b2);
    gemm_bt<<<gg, 256, 0, stream>>>(x2, Wt2, xw, MPAD, HID, HID);
    agg_kernel<<<aggBlocks, 256, 0, stream>>>(xw, x3, rowptr, col, nrm, dinv, b2);

    int scBlocks = (NODES * 64 + 255) / 256;
    score_kernel<<<scBlocks, 256, 0, stream>>>(x1, x2, x3, pw, invn, score, keys);
    select_kernel<<<NGRAPH, 1024, 0, stream>>>(keys, kth);
    compact_kernel<<<NGRAPH, 1024, 0, stream>>>(keys, kth, score, selidx, selscr);
    readout_kernel<<<dim3(NGRAPH, 3, KKEEP / RCHUNK), 256, 0, stream>>>(
        x1, x2, x3, selidx, selscr, sumbuf, maxbuf);
    mlp1_kernel<<<dim3(NGRAPH, MLPCH), 256, 0, stream>>>(sumbuf, maxbuf, lw1, h1acc);
    mlp2_kernel<<<NGRAPH, 256, 0, stream>>>(h1acc, lb1, lw2, lb2, lw3, lb3, out);
}

// Round 6
// 552.146 us; speedup vs baseline: 1.6323x; 1.0578x over previous
//
#include <hip/hip_runtime.h>
#include <stdint.h>

#define NODES  50000
#define MPAD   50048      // 391 * 128
#define NGRAPH 8
#define NP_G   6250
#define EDGES  800000
#define KKEEP  5000
#define HID    256
#define CIN    512
#define H3     768
#define SCANB  196        // 196*256 = 50176 >= NODES
#define RCHUNK 200        // KKEEP / 25
#define MLPCH  24         // layer-1 k-chunks
#define MLPCK  64         // 1536 / 24

using f32x4  = __attribute__((ext_vector_type(4))) float;
using bf16x8 = __attribute__((ext_vector_type(8))) short;
using u16x8  = __attribute__((ext_vector_type(8))) unsigned short;
typedef unsigned short u16;
typedef unsigned long long u64;

__device__ __forceinline__ float bf2f(u16 u) {
    return __uint_as_float(((uint32_t)u) << 16);
}
__device__ __forceinline__ u16 f2bf(float f) {     // RNE
    uint32_t u = __float_as_uint(f);
    u += 0x7fffu + ((u >> 16) & 1u);
    return (u16)(u >> 16);
}

// ---------------- casts ----------------
__global__ void cast_x_kernel(const float* __restrict__ x, u16* __restrict__ A0) {
    size_t i4 = (size_t)blockIdx.x * blockDim.x + threadIdx.x;
    size_t base = i4 * 4;
    if (base >= (size_t)MPAD * CIN) return;
    int row = (int)(base >> 9);   // /512
    ushort4 o;
    if (row < NODES) {
        float4 v = *(const float4*)(x + base);
        o.x = f2bf(v.x); o.y = f2bf(v.y); o.z = f2bf(v.z); o.w = f2bf(v.w);
    } else {
        o.x = 0; o.y = 0; o.z = 0; o.w = 0;
    }
    *(ushort4*)(A0 + base) = o;
}

// fused: cast W1 (blocks 0..511), cast W2 (512..767), zero pad rows (768..815),
// pwnorm (816)
__global__ __launch_bounds__(256) void prep_kernel(
        const float* __restrict__ W1, const float* __restrict__ W2,
        const float* __restrict__ pw,
        u16* __restrict__ Wt1, u16* __restrict__ Wt2, float* __restrict__ invn,
        u16* __restrict__ x1, u16* __restrict__ x2, u16* __restrict__ x3) {
    __shared__ float sh[256];
    int b = blockIdx.x, t = threadIdx.x;
    if (b < 512) {                       // Wt1[n*512+k] = W1[k*256+n]
        int id = b * 256 + t;
        int n = id >> 9, k = id & 511;
        Wt1[id] = f2bf(W1[(size_t)k * HID + n]);
    } else if (b < 768) {                // Wt2[n*256+k] = W2[k*256+n]
        int id = (b - 512) * 256 + t;
        int n = id >> 8, k = id & 255;
        Wt2[id] = f2bf(W2[(size_t)k * HID + n]);
    } else if (b < 816) {                // zero pad rows of x1/x2/x3
        int i = (b - 768) * 256 + t;
        size_t o = (size_t)NODES * HID + i;
        x1[o] = 0; x2[o] = 0; x3[o] = 0;
    } else {                             // pwnorm
        float s = 0.f;
        for (int i = t; i < H3; i += 256) { float v = pw[i]; s += v * v; }
        sh[t] = s; __syncthreads();
        for (int off = 128; off; off >>= 1) {
            if (t < off) sh[t] += sh[t + off];
            __syncthreads();
        }
        if (t == 0) invn[0] = rsqrtf(sh[0]);
    }
}

// ---------------- graph prep ----------------
// one u64 atomic per edge: (count << 48) | fixed-point(ew, 2^-32)
__global__ void edge_pass1(const int* __restrict__ ei, const float* __restrict__ ew,
                           u64* __restrict__ degcnt) {
    int e = blockIdx.x * blockDim.x + threadIdx.x;
    if (e >= EDGES) return;
    int d = ei[EDGES + e];
    u64 enc = (1ull << 48) | (u64)(ew[e] * 4294967296.0f);
    atomicAdd(&degcnt[d], enc);
}

// ---- hierarchical exclusive scan of per-node counts -> rowptr (+ dinv fused) ----
__global__ void scan1_kernel(const u64* __restrict__ degcnt,
                             int* __restrict__ iscan, int* __restrict__ bsum,
                             float* __restrict__ dinv) {
    int b = blockIdx.x, t = threadIdx.x;
    int i = b * 256 + t;
    int c = 0;
    if (i < NODES) {
        u64 dc = degcnt[i];
        c = (int)(dc >> 48);
        float deg = (float)(dc & 0xFFFFFFFFFFFFull) * (1.0f / 4294967296.0f);
        dinv[i] = rsqrtf(deg + 1.0f);
    }
    int lane = t & 63, wv = t >> 6;
    int v = c;
    for (int off = 1; off < 64; off <<= 1) {
        int u = __shfl_up(v, off);
        if (lane >= off) v += u;
    }
    __shared__ int ws[4];
    if (lane == 63) ws[wv] = v;
    __syncthreads();
    if (t == 0) { int s = 0; for (int k = 0; k < 4; k++) { int tmp = ws[k]; ws[k] = s; s += tmp; } }
    __syncthreads();
    v += ws[wv];
    if (i < NODES) iscan[i] = v;          // block-local inclusive scan
    if (t == 255) bsum[b] = v;            // block total (OOB lanes contribute 0)
}

__global__ void scan2_kernel(const int* __restrict__ bsum, int* __restrict__ boff) {
    int t = threadIdx.x;
    int c = (t < SCANB) ? bsum[t] : 0;
    int lane = t & 63, wv = t >> 6;
    int v = c;
    for (int off = 1; off < 64; off <<= 1) {
        int u = __shfl_up(v, off);
        if (lane >= off) v += u;
    }
    __shared__ int ws[4];
    if (lane == 63) ws[wv] = v;
    __syncthreads();
    if (t == 0) { int s = 0; for (int k = 0; k < 4; k++) { int tmp = ws[k]; ws[k] = s; s += tmp; } }
    __syncthreads();
    v += ws[wv];
    if (t < SCANB) boff[t] = v - c;       // exclusive
}

__global__ void scan3_kernel(const u64* __restrict__ degcnt,
                             const int* __restrict__ iscan, const int* __restrict__ boff,
                             int* __restrict__ rowptr, int* __restrict__ rowcur) {
    int b = blockIdx.x, t = threadIdx.x;
    int i = b * 256 + t;
    if (i > NODES) return;
    if (i == NODES) { rowptr[NODES] = EDGES; return; }
    int c = (int)(degcnt[i] >> 48);
    int v = boff[b] + iscan[i] - c;       // global exclusive scan
    rowptr[i] = v;
    rowcur[i] = v;
}

// interleaved CSR: csr[pos] = (src, bitcast(norm)) — one 8B scattered store
__global__ void fill_kernel(const int* __restrict__ ei, const float* __restrict__ ew,
                            const float* __restrict__ dinv,
                            int* __restrict__ rowcur, int2* __restrict__ csr) {
    int e = blockIdx.x * blockDim.x + threadIdx.x;
    if (e >= EDGES) return;
    int s = ei[e], d = ei[EDGES + e];
    int pos = atomicAdd(&rowcur[d], 1);
    csr[pos] = make_int2(s, __float_as_int(dinv[s] * ew[e] * dinv[d]));
}

// ---------------- GEMM: C[M,N] = A[M,K] @ Bt[N,K]^T  (all bf16, fp32 acc) ---------
__global__ __launch_bounds__(256) void gemm_bt(const u16* __restrict__ A,
                                               const u16* __restrict__ Bt,
                                               u16* __restrict__ C,
                                               int M, int N, int K) {
    __shared__ u16 As[128 * 32];
    __shared__ u16 Bs[128 * 32];
    const int tid  = threadIdx.x;
    const int wave = tid >> 6, lane = tid & 63;
    const int wm = wave >> 1, wn = wave & 1;       // 2x2 waves over 128x128
    const int quad = lane >> 4, l16 = lane & 15;
    const int bm = blockIdx.x, bn = blockIdx.y;

    const int sr = tid >> 2;                        // staging row 0..63 (+64 second)
    const int sc = tid & 3;                         // 16B chunk within 64B row
    const int swz = (sc ^ ((sr >> 1) & 3)) * 8;     // (sr+64)>>1 has same low bits
    const int rphys = (quad ^ ((l16 >> 1) & 3)) * 8;

    const u16* Ag = A + (size_t)(bm * 128 + sr) * K + sc * 8;
    const u16* Bg = Bt + (size_t)(bn * 128 + sr) * K + sc * 8;

    f32x4 acc[4][4];
#pragma unroll
    for (int i = 0; i < 4; i++)
#pragma unroll
        for (int j = 0; j < 4; j++) { f32x4 z = {0.f, 0.f, 0.f, 0.f}; acc[i][j] = z; }

    for (int k0 = 0; k0 < K; k0 += 32) {
        int4 av0 = *(const int4*)(Ag + k0);
        int4 av1 = *(const int4*)(Ag + (size_t)64 * K + k0);
        int4 bv0 = *(const int4*)(Bg + k0);
        int4 bv1 = *(const int4*)(Bg + (size_t)64 * K + k0);
        __syncthreads();
        *(int4*)(As + sr * 32 + swz)        = av0;
        *(int4*)(As + (sr + 64) * 32 + swz) = av1;
        *(int4*)(Bs + sr * 32 + swz)        = bv0;
        *(int4*)(Bs + (sr + 64) * 32 + swz) = bv1;
        __syncthreads();
        bf16x8 af[4], bfr[4];
#pragma unroll
        for (int i = 0; i < 4; i++)
            af[i] = *(const bf16x8*)(As + (wm * 64 + i * 16 + l16) * 32 + rphys);
#pragma unroll
        for (int j = 0; j < 4; j++)
            bfr[j] = *(const bf16x8*)(Bs + (wn * 64 + j * 16 + l16) * 32 + rphys);
#pragma unroll
        for (int i = 0; i < 4; i++)
#pragma unroll
            for (int j = 0; j < 4; j++)
                acc[i][j] = __builtin_amdgcn_mfma_f32_16x16x32_bf16(af[i], bfr[j], acc[i][j], 0, 0, 0);
    }

    const int crow0 = bm * 128 + wm * 64 + quad * 4;
    const int ccol0 = bn * 128 + wn * 64 + l16;
#pragma unroll
    for (int i = 0; i < 4; i++)
#pragma unroll
        for (int j = 0; j < 4; j++)
#pragma unroll
            for (int r = 0; r < 4; r++)
                C[(size_t)(crow0 + i * 16 + r) * N + ccol0 + j * 16] = f2bf(acc[i][j][r]);
}

// ---------------- aggregation v2: half-wave per edge-row, 16B loads --------------
// lanes 0..31 and 32..63 each own all 256 features (8/lane); the halves process
// different edges (2 pairs in flight), combined by 8 xor-shuffles at the end.
__global__ void agg_kernel(const u16* __restrict__ xw, u16* __restrict__ xo,
                           const int* __restrict__ rowptr, const int2* __restrict__ csr,
                           const float* __restrict__ nrm_unused,
                           const float* __restrict__ dinv,
                           const float* __restrict__ bias) {
    int wave = threadIdx.x >> 6;
    int lane = threadIdx.x & 63;
    int g  = blockIdx.x & 7;
    int nl = (blockIdx.x >> 3) * 4 + wave;
    if (nl >= NP_G) return;
    int w = g * NP_G + nl;
    int half = lane >> 5;              // which edge of a pair
    int f8 = (lane & 31) * 8;          // feature base (8 elems, 16 B)
    size_t ro = (size_t)w * HID + f8;

    float accA[8], accB[8];
#pragma unroll
    for (int j = 0; j < 8; ++j) { accA[j] = 0.f; accB[j] = 0.f; }

    int p = rowptr[w], p1 = rowptr[w + 1];
    for (; p + 4 <= p1; p += 4) {                  // 4 edges per iteration
        int2 eA = csr[p + half];
        int2 eB = csr[p + 2 + half];
        float wA = __int_as_float(eA.y), wB = __int_as_float(eB.y);
        u16x8 vA = *(const u16x8*)(xw + (size_t)eA.x * HID + f8);
        u16x8 vB = *(const u16x8*)(xw + (size_t)eB.x * HID + f8);
#pragma unroll
        for (int j = 0; j < 8; ++j) {
            accA[j] += wA * bf2f(vA[j]);
            accB[j] += wB * bf2f(vB[j]);
        }
    }
    for (; p < p1; p += 2) {                       // tail pairs (predicated)
        int idx = p + half;
        bool valid = idx < p1;
        int2 eA = csr[valid ? idx : p];
        float wA = valid ? __int_as_float(eA.y) : 0.f;
        u16x8 vA = *(const u16x8*)(xw + (size_t)eA.x * HID + f8);
#pragma unroll
        for (int j = 0; j < 8; ++j) accA[j] += wA * bf2f(vA[j]);
    }

#pragma unroll
    for (int j = 0; j < 8; ++j) {
        accA[j] += accB[j];
        accA[j] += __shfl(accA[j], lane ^ 32, 64);   // combine halves
    }

    float di = dinv[w], sw = di * di;
    u16x8 sv = *(const u16x8*)(xw + ro);             // self term (broadcast per pair)
    float bb[8];
    {
        float4 t0 = *(const float4*)(bias + f8);
        float4 t1 = *(const float4*)(bias + f8 + 4);
        bb[0] = t0.x; bb[1] = t0.y; bb[2] = t0.z; bb[3] = t0.w;
        bb[4] = t1.x; bb[5] = t1.y; bb[6] = t1.z; bb[7] = t1.w;
    }
    u16x8 o;
#pragma unroll
    for (int j = 0; j < 8; ++j) {
        float v = fmaxf(accA[j] + sw * bf2f(sv[j]) + bb[j], 0.f);
        o[j] = f2bf(v);
    }
    if (half == 0) *(u16x8*)(xo + ro) = o;
}

// ---------------- score + keys (one wave per node) ----------------
__global__ void score_kernel(const u16* __restrict__ x1, const u16* __restrict__ x2,
                             const u16* __restrict__ x3, const float* __restrict__ pw,
                             const float* __restrict__ invn, float* __restrict__ score,
                             unsigned long long* __restrict__ keys) {
    int w = (blockIdx.x * blockDim.x + threadIdx.x) >> 6;
    int lane = threadIdx.x & 63;
    if (w >= NODES) return;
    int f = lane * 4;
    float acc = 0.f;
    {
        ushort4 v = *(const ushort4*)(x1 + (size_t)w * HID + f);
        float4 q = *(const float4*)(pw + f);
        acc += bf2f(v.x) * q.x + bf2f(v.y) * q.y + bf2f(v.z) * q.z + bf2f(v.w) * q.w;
    }
    {
        ushort4 v = *(const ushort4*)(x2 + (size_t)w * HID + f);
        float4 q = *(const float4*)(pw + 256 + f);
        acc += bf2f(v.x) * q.x + bf2f(v.y) * q.y + bf2f(v.z) * q.z + bf2f(v.w) * q.w;
    }
    {
        ushort4 v = *(const ushort4*)(x3 + (size_t)w * HID + f);
        float4 q = *(const float4*)(pw + 512 + f);
        acc += bf2f(v.x) * q.x + bf2f(v.y) * q.y + bf2f(v.z) * q.z + bf2f(v.w) * q.w;
    }
    for (int off = 32; off; off >>= 1) acc += __shfl_down(acc, off);
    if (lane == 0) {
        float s = acc * invn[0];
        float sc = 1.f / (1.f + __expf(-s));
        score[w] = sc;
        int li = w % NP_G;
        keys[w] = ((unsigned long long)__float_as_uint(sc) << 13) |
                  (unsigned int)(NP_G - 1 - li);
    }
}

// ---------------- exact top-K threshold per graph (radix select, distinct keys) ----
__global__ __launch_bounds__(1024) void select_kernel(
        const unsigned long long* __restrict__ keys,
        unsigned long long* __restrict__ kth) {
    __shared__ unsigned long long kk[NP_G];          // 50 KB
    __shared__ unsigned int hist[4][256];
    __shared__ unsigned int sfx[257];
    __shared__ unsigned long long spref;
    __shared__ unsigned int swant;
    int g = blockIdx.x, t = threadIdx.x;
    const unsigned long long* kg = keys + (size_t)g * NP_G;
    for (int i = t; i < NP_G; i += 1024) kk[i] = kg[i];
    if (t == 0) { spref = 0ull; swant = KKEEP; }
    const int wgrp = (t >> 8) & 3;                   // 4 groups of 4 waves
    unsigned long long mask = 0ull;
    __syncthreads();
    for (int shift = 40; shift >= 0; shift -= 8) {
        if (t < 256) { hist[0][t] = 0; hist[1][t] = 0; hist[2][t] = 0; hist[3][t] = 0; }
        __syncthreads();
        unsigned long long pref = spref;
        for (int i = t; i < NP_G; i += 1024) {
            unsigned long long key = kk[i];
            if ((key & mask) == pref)
                atomicAdd(&hist[wgrp][(unsigned int)(key >> shift) & 255u], 1u);
        }
        __syncthreads();
        if (t < 256) sfx[t] = hist[0][t] + hist[1][t] + hist[2][t] + hist[3][t];
        if (t == 0) sfx[256] = 0;
        __syncthreads();
        // reversed Hillis-Steele inclusive scan: sfx[t] = sum_{b>=t} cnt[b]
        for (int off = 1; off < 256; off <<= 1) {
            unsigned int v = 0;
            if (t < 256 && t + off < 256) v = sfx[t + off];
            __syncthreads();
            if (t < 256 && t + off < 256) sfx[t] += v;
            __syncthreads();
        }
        unsigned int want = swant;                   // all read before any write
        __syncthreads();
        if (t < 256) {
            unsigned int s0 = sfx[t], s1 = sfx[t + 1];
            if (s0 >= want && s1 < want) {           // unique t (sfx nonincreasing)
                spref = pref | ((unsigned long long)t << shift);
                swant = want - s1;
            }
        }
        __syncthreads();
        mask |= (255ull << shift);
    }
    if (t == 0) kth[g] = spref;
}

// ---------------- stable compaction of selected nodes (sorted by node id) --------
__global__ __launch_bounds__(1024) void compact_kernel(
        const unsigned long long* __restrict__ keys,
        const unsigned long long* __restrict__ kth,
        const float* __restrict__ score,
        int* __restrict__ selidx, float* __restrict__ selscr) {
    int g = blockIdx.x, t = threadIdx.x;
    int lane = t & 63, wv = t >> 6;
    __shared__ int wsum[16];
    __shared__ int base;
    if (t == 0) base = 0;
    unsigned long long kg = kth[g];
    __syncthreads();
    for (int k = 0; k < (NP_G + 1023) / 1024; ++k) {
        int i = k * 1024 + t;
        bool sel = false; int n = 0; float sc = 0.f;
        if (i < NP_G) {
            n = g * NP_G + i;
            sel = keys[n] >= kg;
            if (sel) sc = score[n];
        }
        u64 bal = __ballot(sel);
        int prefix = __popcll(bal & ((1ull << lane) - 1ull));
        if (lane == 0) wsum[wv] = __popcll(bal);
        __syncthreads();
        if (t == 0) {
            int s = base;
            for (int j = 0; j < 16; ++j) { int tmp = wsum[j]; wsum[j] = s; s += tmp; }
            base = s;
        }
        __syncthreads();
        if (sel) {
            int pos = wsum[wv] + prefix;
            selidx[g * KKEEP + pos] = n;
            selscr[g * KKEEP + pos] = sc;
        }
        __syncthreads();
    }
}

// ---------------- readout: branch-free gather over compacted list ----------------
__global__ __launch_bounds__(256) void readout_kernel(
        const u16* __restrict__ x1, const u16* __restrict__ x2,
        const u16* __restrict__ x3,
        const int* __restrict__ selidx, const float* __restrict__ selscr,
        float* __restrict__ sumbuf, int* __restrict__ maxbuf) {
    int g = blockIdx.x, tpart = blockIdx.y, c = blockIdx.z;
    int fcol = threadIdx.x;
    const u16* xt = (tpart == 0) ? x1 : ((tpart == 1) ? x2 : x3);
    __shared__ int   sidx[RCHUNK];
    __shared__ float sscr[RCHUNK];
    int base = g * KKEEP + c * RCHUNK;
    if (fcol < RCHUNK) { sidx[fcol] = selidx[base + fcol]; sscr[fcol] = selscr[base + fcol]; }
    __syncthreads();
    float sum = 0.f, mx = 0.f;
#pragma unroll 1
    for (int j = 0; j < RCHUNK; j += 4) {
        int n0 = sidx[j], n1 = sidx[j + 1], n2 = sidx[j + 2], n3 = sidx[j + 3];
        float s0 = sscr[j], s1 = sscr[j + 1], s2 = sscr[j + 2], s3 = sscr[j + 3];
        float v0 = bf2f(xt[(size_t)n0 * HID + fcol]) * s0;
        float v1 = bf2f(xt[(size_t)n1 * HID + fcol]) * s1;
        float v2 = bf2f(xt[(size_t)n2 * HID + fcol]) * s2;
        float v3 = bf2f(xt[(size_t)n3 * HID + fcol]) * s3;
        sum += v0 + v1 + v2 + v3;
        mx = fmaxf(mx, fmaxf(fmaxf(v0, v1), fmaxf(v2, v3)));
    }
    int o = (g * 3 + tpart) * HID + fcol;
    atomicAdd(&sumbuf[o], sum);
    atomicMax(&maxbuf[o], __float_as_int(mx));   // all v >= 0, int order == float order
}

// ---------------- MLP layer 1, k-split: h1acc[g][t] += sum over 64-chunk ---------
__global__ __launch_bounds__(256) void mlp1_kernel(const float* __restrict__ sumbuf,
                                                   const int* __restrict__ maxbuf,
                                                   const float* __restrict__ lw1,
                                                   float* __restrict__ h1acc) {
    int g = blockIdx.x, ch = blockIdx.y, t = threadIdx.x;
    __shared__ float r[MLPCK];
    int k0 = ch * MLPCK;
    if (t < MLPCK) {
        int i = k0 + t;
        r[t] = (i < 768) ? sumbuf[g * 768 + i] * (1.f / 5000.f)
                         : __int_as_float(maxbuf[g * 768 + (i - 768)]);
    }
    __syncthreads();
    float a0 = 0.f, a1 = 0.f, a2 = 0.f, a3 = 0.f;
#pragma unroll
    for (int i = 0; i < MLPCK; i += 4) {
        a0 += r[i]     * lw1[(size_t)(k0 + i)     * 256 + t];
        a1 += r[i + 1] * lw1[(size_t)(k0 + i + 1) * 256 + t];
        a2 += r[i + 2] * lw1[(size_t)(k0 + i + 2) * 256 + t];
        a3 += r[i + 3] * lw1[(size_t)(k0 + i + 3) * 256 + t];
    }
    atomicAdd(&h1acc[g * 256 + t], (a0 + a1) + (a2 + a3));
}

// ---------------- MLP layers 2+3 ----------------
__global__ __launch_bounds__(256) void mlp2_kernel(const float* __restrict__ h1acc,
                                                   const float* __restrict__ lb1,
                                                   const float* __restrict__ lw2,
                                                   const float* __restrict__ lb2,
                                                   const float* __restrict__ lw3,
                                                   const float* __restrict__ lb3,
                                                   float* __restrict__ out) {
    __shared__ float h1[256];
    __shared__ float part[256];
    __shared__ float h2[128];
    int g = blockIdx.x, t = threadIdx.x;
    h1[t] = fmaxf(h1acc[g * 256 + t] + lb1[t], 0.f);
    __syncthreads();
    int col = t & 127, half = t >> 7;    // 2-way k-split of the 256-reduction
    float a = 0.f;
#pragma unroll
    for (int i = 0; i < 128; i += 4) {
        int k = half * 128 + i;
        a += h1[k]     * lw2[k * 128 + col]
           + h1[k + 1] * lw2[(k + 1) * 128 + col]
           + h1[k + 2] * lw2[(k + 2) * 128 + col]
           + h1[k + 3] * lw2[(k + 3) * 128 + col];
    }
    part[t] = a;
    __syncthreads();
    if (t < 128) h2[t] = fmaxf(part[t] + part[t + 128] + lb2[t], 0.f);
    __syncthreads();
    if (t < 3) {
        float a3 = lb3[t];
        for (int i = 0; i < 128; ++i) a3 += h2[i] * lw3[i * 3 + t];
        out[g * 3 + t] = a3;
    }
}

extern "C" void kernel_launch(void* const* d_in, const int* in_sizes, int n_in,
                              void* d_out, int out_size, void* d_ws, size_t ws_size,
                              hipStream_t stream) {
    const float* x   = (const float*)d_in[0];
    const int*   ei  = (const int*)d_in[1];
    const float* ew  = (const float*)d_in[2];
    const float* W1  = (const float*)d_in[4];
    const float* b1  = (const float*)d_in[5];
    const float* W2  = (const float*)d_in[6];
    const float* b2  = (const float*)d_in[7];
    const float* pw  = (const float*)d_in[8];
    const float* lw1 = (const float*)d_in[9];
    const float* lb1 = (const float*)d_in[10];
    const float* lw2 = (const float*)d_in[11];
    const float* lb2 = (const float*)d_in[12];
    const float* lw3 = (const float*)d_in[13];
    const float* lb3 = (const float*)d_in[14];
    float* out = (float*)d_out;

    char* p = (char*)d_ws;
    auto alloc = [&](size_t bytes) -> char* {
        char* r = p;
        p += (bytes + 255) & ~(size_t)255;
        return r;
    };
    u16* A0  = (u16*)alloc((size_t)MPAD * CIN * 2);   // x bf16; x1/x2 alias after GEMM1
    u16* x3  = (u16*)alloc((size_t)MPAD * HID * 2);
    u16* xw  = (u16*)alloc((size_t)MPAD * HID * 2);
    u16* Wt1 = (u16*)alloc((size_t)HID * CIN * 2);
    u16* Wt2 = (u16*)alloc((size_t)HID * HID * 2);
    int2*  csr    = (int2*)alloc((size_t)EDGES * 8);
    int*   rowptr = (int*)alloc((size_t)(NODES + 1) * 4);
    int*   rowcur = (int*)alloc((size_t)NODES * 4);
    int*   iscan  = (int*)alloc((size_t)NODES * 4);
    int*   bsum   = (int*)alloc((size_t)SCANB * 4);
    int*   boff   = (int*)alloc((size_t)SCANB * 4);
    unsigned long long* keys = (unsigned long long*)alloc((size_t)NODES * 8);
    float* score = (float*)alloc((size_t)NODES * 4);
    float* dinv  = (float*)alloc((size_t)NODES * 4);
    int*   selidx = (int*)alloc((size_t)NGRAPH * KKEEP * 4);
    float* selscr = (float*)alloc((size_t)NGRAPH * KKEEP * 4);
    unsigned long long* kth = (unsigned long long*)alloc(64);
    float* invn = (float*)alloc(256);
    char* zbase = p;                                  // everything below is zero-init
    u64*   degcnt = (u64*)alloc((size_t)NODES * 8);
    float* sumbuf = (float*)alloc(6144 * 4);
    int*   maxbuf = (int*)alloc(6144 * 4);
    float* h1acc  = (float*)alloc((size_t)NGRAPH * 256 * 4);
    size_t zbytes = (size_t)(p - zbase);

    u16* x1 = A0;                         // reuse A0 after GEMM1 consumed it
    u16* x2 = A0 + (size_t)MPAD * HID;

    hipMemsetAsync(zbase, 0, zbytes, stream);

    cast_x_kernel<<<(MPAD * CIN / 4 + 255) / 256, 256, 0, stream>>>(x, A0);
    prep_kernel<<<817, 256, 0, stream>>>(W1, W2, pw, Wt1, Wt2, invn, x1, x2, x3);

    edge_pass1<<<(EDGES + 255) / 256, 256, 0, stream>>>(ei, ew, degcnt);
    scan1_kernel<<<SCANB, 256, 0, stream>>>(degcnt, iscan, bsum, dinv);
    scan2_kernel<<<1, 256, 0, stream>>>(bsum, boff);
    scan3_kernel<<<SCANB + 1, 256, 0, stream>>>(degcnt, iscan, boff, rowptr, rowcur);
    fill_kernel<<<(EDGES + 255) / 256, 256, 0, stream>>>(ei, ew, dinv, rowcur, csr);

    dim3 gg(MPAD / 128, HID / 128);
    int aggBlocks = 8 * ((NP_G + 3) / 4);   // graph = blockIdx & 7 (XCD pinning)

    gemm_bt<<<gg, 256, 0, stream>>>(A0, Wt1, xw, MPAD, HID, CIN);
    agg_kernel<<<aggBlocks, 256, 0, stream>>>(xw, x1, rowptr, csr, nullptr, dinv, b1);
    gemm_bt<<<gg, 256, 0, stream>>>(x1, Wt2, xw, MPAD, HID, HID);
    agg_kernel<<<aggBlocks, 256, 0, stream>>>(xw, x2, rowptr, csr, nullptr, dinv, b2);
    gemm_bt<<<gg, 256, 0, stream>>>(x2, Wt2, xw, MPAD, HID, HID);
    agg_kernel<<<aggBlocks, 256, 0, stream>>>(xw, x3, rowptr, csr, nullptr, dinv, b2);

    int scBlocks = (NODES * 64 + 255) / 256;
    score_kernel<<<scBlocks, 256, 0, stream>>>(x1, x2, x3, pw, invn, score, keys);
    select_kernel<<<NGRAPH, 1024, 0, stream>>>(keys, kth);
    compact_kernel<<<NGRAPH, 1024, 0, stream>>>(keys, kth, score, selidx, selscr);
    readout_kernel<<<dim3(NGRAPH, 3, KKEEP / RCHUNK), 256, 0, stream>>>(
        x1, x2, x3, selidx, selscr, sumbuf, maxbuf);
    mlp1_kernel<<<dim3(NGRAPH, MLPCH), 256, 0, stream>>>(sumbuf, maxbuf, lw1, h1acc);
    mlp2_kernel<<<NGRAPH, 256, 0, stream>>>(h1acc, lb1, lw2, lb2, lw3, lb3, out);
}

// Round 7
// 520.821 us; speedup vs baseline: 1.7305x; 1.0601x over previous
//
#include <hip/hip_runtime.h>
#include <stdint.h>

#define NODES  50000
#define MPAD   50048      // 391 * 128
#define NGRAPH 8
#define NP_G   6250
#define EDGES  800000
#define KKEEP  5000
#define HID    256
#define CIN    512
#define H3     768
#define SCANB  196        // 196*256 = 50176 >= NODES
#define RCHUNK 200        // KKEEP / 25
#define MLPCH  24         // layer-1 k-chunks
#define MLPCK  64         // 1536 / 24

// K1 block ranges
#define K1_EDGE  3125
#define K1_CAST  25000    // 50000*512/(4*256)
#define K1_W1    512
#define K1_W2    256
#define K1_TOTAL (K1_EDGE + K1_CAST + K1_W1 + K1_W2 + 1)
// K2 block ranges
#define K2_GEMM  782      // 391*2
#define K2_TOTAL (K2_GEMM + 3125)

using f32x4  = __attribute__((ext_vector_type(4))) float;
using bf16x8 = __attribute__((ext_vector_type(8))) short;
using u16x8  = __attribute__((ext_vector_type(8))) unsigned short;
typedef unsigned short u16;
typedef unsigned long long u64;

__device__ __forceinline__ float bf2f(u16 u) {
    return __uint_as_float(((uint32_t)u) << 16);
}
__device__ __forceinline__ u16 f2bf(float f) {     // RNE
    uint32_t u = __float_as_uint(f);
    u += 0x7fffu + ((u >> 16) & 1u);
    return (u16)(u >> 16);
}

// ---------------- K1: edge-degree atomics + x cast + W casts + pwnorm -----------
// Independent pipelines co-scheduled in one launch: edge blocks are L2-atomic
// latency-bound, cast blocks are HBM-bound — they overlap instead of serializing.
__global__ __launch_bounds__(256) void k1_kernel(
        const int* __restrict__ ei, const float* __restrict__ ew,
        u64* __restrict__ degcnt,
        const float* __restrict__ x, u16* __restrict__ A0,
        const float* __restrict__ W1, const float* __restrict__ W2,
        const float* __restrict__ pw,
        u16* __restrict__ Wt1, u16* __restrict__ Wt2, float* __restrict__ invn) {
    __shared__ float sh[256];
    int b = blockIdx.x, t = threadIdx.x;
    if (b < K1_EDGE) {                           // edge pass: one u64 atomic/edge
        int e = b * 256 + t;                     // 3125*256 == EDGES exactly
        int d = ei[EDGES + e];
        u64 enc = (1ull << 48) | (u64)(ew[e] * 4294967296.0f);
        atomicAdd(&degcnt[d], enc);
    } else if (b < K1_EDGE + K1_CAST) {          // cast x -> bf16 (real rows only)
        size_t base = ((size_t)(b - K1_EDGE) * 256 + t) * 4;
        float4 v = *(const float4*)(x + base);
        ushort4 o;
        o.x = f2bf(v.x); o.y = f2bf(v.y); o.z = f2bf(v.z); o.w = f2bf(v.w);
        *(ushort4*)(A0 + base) = o;
    } else if (b < K1_EDGE + K1_CAST + K1_W1) {  // Wt1[n*512+k] = W1[k*256+n]
        int id = (b - K1_EDGE - K1_CAST) * 256 + t;
        int n = id >> 9, k = id & 511;
        Wt1[id] = f2bf(W1[(size_t)k * HID + n]);
    } else if (b < K1_TOTAL - 1) {               // Wt2[n*256+k] = W2[k*256+n]
        int id = (b - K1_EDGE - K1_CAST - K1_W1) * 256 + t;
        int n = id >> 8, k = id & 255;
        Wt2[id] = f2bf(W2[(size_t)k * HID + n]);
    } else {                                     // pwnorm
        float s = 0.f;
        for (int i = t; i < H3; i += 256) { float v = pw[i]; s += v * v; }
        sh[t] = s; __syncthreads();
        for (int off = 128; off; off >>= 1) {
            if (t < off) sh[t] += sh[t + off];
            __syncthreads();
        }
        if (t == 0) invn[0] = rsqrtf(sh[0]);
    }
}

// ---- hierarchical exclusive scan of per-node counts -> rowptr (+ dinv fused) ----
__global__ void scan1_kernel(const u64* __restrict__ degcnt,
                             int* __restrict__ iscan, int* __restrict__ bsum,
                             float* __restrict__ dinv) {
    int b = blockIdx.x, t = threadIdx.x;
    int i = b * 256 + t;
    int c = 0;
    if (i < NODES) {
        u64 dc = degcnt[i];
        c = (int)(dc >> 48);
        float deg = (float)(dc & 0xFFFFFFFFFFFFull) * (1.0f / 4294967296.0f);
        dinv[i] = rsqrtf(deg + 1.0f);
    }
    int lane = t & 63, wv = t >> 6;
    int v = c;
    for (int off = 1; off < 64; off <<= 1) {
        int u = __shfl_up(v, off);
        if (lane >= off) v += u;
    }
    __shared__ int ws[4];
    if (lane == 63) ws[wv] = v;
    __syncthreads();
    if (t == 0) { int s = 0; for (int k = 0; k < 4; k++) { int tmp = ws[k]; ws[k] = s; s += tmp; } }
    __syncthreads();
    v += ws[wv];
    if (i < NODES) iscan[i] = v;
    if (t == 255) bsum[b] = v;
}

__global__ void scan2_kernel(const int* __restrict__ bsum, int* __restrict__ boff) {
    int t = threadIdx.x;
    int c = (t < SCANB) ? bsum[t] : 0;
    int lane = t & 63, wv = t >> 6;
    int v = c;
    for (int off = 1; off < 64; off <<= 1) {
        int u = __shfl_up(v, off);
        if (lane >= off) v += u;
    }
    __shared__ int ws[4];
    if (lane == 63) ws[wv] = v;
    __syncthreads();
    if (t == 0) { int s = 0; for (int k = 0; k < 4; k++) { int tmp = ws[k]; ws[k] = s; s += tmp; } }
    __syncthreads();
    v += ws[wv];
    if (t < SCANB) boff[t] = v - c;
}

__global__ void scan3_kernel(const u64* __restrict__ degcnt,
                             const int* __restrict__ iscan, const int* __restrict__ boff,
                             int* __restrict__ rowptr, int* __restrict__ rowcur) {
    int b = blockIdx.x, t = threadIdx.x;
    int i = b * 256 + t;
    if (i > NODES) return;
    if (i == NODES) { rowptr[NODES] = EDGES; return; }
    int c = (int)(degcnt[i] >> 48);
    int v = boff[b] + iscan[i] - c;
    rowptr[i] = v;
    rowcur[i] = v;
}

// ---------------- K2: GEMM1 (A0 @ Wt1) + CSR fill, co-scheduled -------------------
__device__ __forceinline__ void gemm_body(const u16* __restrict__ A,
                                          const u16* __restrict__ Bt,
                                          u16* __restrict__ C,
                                          int K, int bm, int bn,
                                          u16* As, u16* Bs) {
    const int tid  = threadIdx.x;
    const int wave = tid >> 6, lane = tid & 63;
    const int wm = wave >> 1, wn = wave & 1;
    const int quad = lane >> 4, l16 = lane & 15;
    const int sr = tid >> 2;
    const int sc = tid & 3;
    const int swz = (sc ^ ((sr >> 1) & 3)) * 8;
    const int rphys = (quad ^ ((l16 >> 1) & 3)) * 8;

    const u16* Ag = A + (size_t)(bm * 128 + sr) * K + sc * 8;
    const u16* Bg = Bt + (size_t)(bn * 128 + sr) * K + sc * 8;

    f32x4 acc[4][4];
#pragma unroll
    for (int i = 0; i < 4; i++)
#pragma unroll
        for (int j = 0; j < 4; j++) { f32x4 z = {0.f, 0.f, 0.f, 0.f}; acc[i][j] = z; }

    for (int k0 = 0; k0 < K; k0 += 32) {
        int4 av0 = *(const int4*)(Ag + k0);
        int4 av1 = *(const int4*)(Ag + (size_t)64 * K + k0);
        int4 bv0 = *(const int4*)(Bg + k0);
        int4 bv1 = *(const int4*)(Bg + (size_t)64 * K + k0);
        __syncthreads();
        *(int4*)(As + sr * 32 + swz)        = av0;
        *(int4*)(As + (sr + 64) * 32 + swz) = av1;
        *(int4*)(Bs + sr * 32 + swz)        = bv0;
        *(int4*)(Bs + (sr + 64) * 32 + swz) = bv1;
        __syncthreads();
        bf16x8 af[4], bfr[4];
#pragma unroll
        for (int i = 0; i < 4; i++)
            af[i] = *(const bf16x8*)(As + (wm * 64 + i * 16 + l16) * 32 + rphys);
#pragma unroll
        for (int j = 0; j < 4; j++)
            bfr[j] = *(const bf16x8*)(Bs + (wn * 64 + j * 16 + l16) * 32 + rphys);
#pragma unroll
        for (int i = 0; i < 4; i++)
#pragma unroll
            for (int j = 0; j < 4; j++)
                acc[i][j] = __builtin_amdgcn_mfma_f32_16x16x32_bf16(af[i], bfr[j], acc[i][j], 0, 0, 0);
    }

    const int crow0 = bm * 128 + wm * 64 + quad * 4;
    const int ccol0 = bn * 128 + wn * 64 + l16;
#pragma unroll
    for (int i = 0; i < 4; i++)
#pragma unroll
        for (int j = 0; j < 4; j++)
#pragma unroll
            for (int r = 0; r < 4; r++)
                C[(size_t)(crow0 + i * 16 + r) * HID + ccol0 + j * 16] = f2bf(acc[i][j][r]);
}

__global__ __launch_bounds__(256) void k2_kernel(
        const u16* __restrict__ A0, const u16* __restrict__ Wt1, u16* __restrict__ xw,
        const int* __restrict__ ei, const float* __restrict__ ew,
        const float* __restrict__ dinv,
        int* __restrict__ rowcur, int2* __restrict__ csr) {
    __shared__ u16 As[128 * 32];
    __shared__ u16 Bs[128 * 32];
    int b = blockIdx.x;
    if (b < K2_GEMM) {
        gemm_body(A0, Wt1, xw, CIN, b >> 1, b & 1, As, Bs);
    } else {
        int e = (b - K2_GEMM) * 256 + threadIdx.x;   // 3125*256 == EDGES
        int s = ei[e], d = ei[EDGES + e];
        int pos = atomicAdd(&rowcur[d], 1);
        csr[pos] = make_int2(s, __float_as_int(dinv[s] * ew[e] * dinv[d]));
    }
}

// plain GEMM (layers 2,3)
__global__ __launch_bounds__(256) void gemm_bt(const u16* __restrict__ A,
                                               const u16* __restrict__ Bt,
                                               u16* __restrict__ C, int K) {
    __shared__ u16 As[128 * 32];
    __shared__ u16 Bs[128 * 32];
    gemm_body(A, Bt, C, K, blockIdx.x, blockIdx.y, As, Bs);
}

// ---------------- aggregation: half-wave 16B gathers; SCORE fuses TopK scoring ----
template<bool SCORE>
__global__ void agg_kernel(const u16* __restrict__ xw, u16* __restrict__ xo,
                           const int* __restrict__ rowptr, const int2* __restrict__ csr,
                           const float* __restrict__ dinv, const float* __restrict__ bias,
                           const u16* __restrict__ xs1, const u16* __restrict__ xs2,
                           const float* __restrict__ pw, const float* __restrict__ invn,
                           float* __restrict__ score, u64* __restrict__ keys) {
    int wave = threadIdx.x >> 6;
    int lane = threadIdx.x & 63;
    int g  = blockIdx.x & 7;
    int nl = (blockIdx.x >> 3) * 4 + wave;
    if (nl >= NP_G) return;
    int w = g * NP_G + nl;
    int half = lane >> 5;
    int f8 = (lane & 31) * 8;
    size_t ro = (size_t)w * HID + f8;

    float accA[8], accB[8];
#pragma unroll
    for (int j = 0; j < 8; ++j) { accA[j] = 0.f; accB[j] = 0.f; }

    int p = rowptr[w], p1 = rowptr[w + 1];
    for (; p + 4 <= p1; p += 4) {
        int2 eA = csr[p + half];
        int2 eB = csr[p + 2 + half];
        float wA = __int_as_float(eA.y), wB = __int_as_float(eB.y);
        u16x8 vA = *(const u16x8*)(xw + (size_t)eA.x * HID + f8);
        u16x8 vB = *(const u16x8*)(xw + (size_t)eB.x * HID + f8);
#pragma unroll
        for (int j = 0; j < 8; ++j) {
            accA[j] += wA * bf2f(vA[j]);
            accB[j] += wB * bf2f(vB[j]);
        }
    }
    for (; p < p1; p += 2) {
        int idx = p + half;
        bool valid = idx < p1;
        int2 eA = csr[valid ? idx : p];
        float wA = valid ? __int_as_float(eA.y) : 0.f;
        u16x8 vA = *(const u16x8*)(xw + (size_t)eA.x * HID + f8);
#pragma unroll
        for (int j = 0; j < 8; ++j) accA[j] += wA * bf2f(vA[j]);
    }

#pragma unroll
    for (int j = 0; j < 8; ++j) {
        accA[j] += accB[j];
        accA[j] += __shfl(accA[j], lane ^ 32, 64);
    }

    float di = dinv[w], sw = di * di;
    u16x8 sv = *(const u16x8*)(xw + ro);
    float bb[8];
    {
        float4 t0 = *(const float4*)(bias + f8);
        float4 t1 = *(const float4*)(bias + f8 + 4);
        bb[0] = t0.x; bb[1] = t0.y; bb[2] = t0.z; bb[3] = t0.w;
        bb[4] = t1.x; bb[5] = t1.y; bb[6] = t1.z; bb[7] = t1.w;
    }
    u16x8 o;
    float ov[8];
#pragma unroll
    for (int j = 0; j < 8; ++j) {
        float v = fmaxf(accA[j] + sw * bf2f(sv[j]) + bb[j], 0.f);
        o[j] = f2bf(v);
        ov[j] = bf2f(o[j]);               // post-rounding value (matches stored x3)
    }
    if (half == 0) *(u16x8*)(xo + ro) = o;

    if (SCORE) {
        // cat([x1,x2,x3]) . pw — each 32-lane half covers all 256 feats, so both
        // halves independently compute the full dot; 5 xor-shuffles reduce.
        u16x8 v1 = *(const u16x8*)(xs1 + ro);
        u16x8 v2 = *(const u16x8*)(xs2 + ro);
        float acc = 0.f;
#pragma unroll
        for (int j = 0; j < 8; ++j) {
            acc += bf2f(v1[j]) * pw[f8 + j];
            acc += bf2f(v2[j]) * pw[256 + f8 + j];
            acc += ov[j]       * pw[512 + f8 + j];
        }
#pragma unroll
        for (int off = 1; off < 32; off <<= 1) acc += __shfl_xor(acc, off, 64);
        if (lane == 0) {
            float s = acc * invn[0];
            float sc = 1.f / (1.f + __expf(-s));
            score[w] = sc;
            keys[w] = ((u64)__float_as_uint(sc) << 13) | (unsigned int)(NP_G - 1 - nl);
        }
    }
}

// ---------------- top-K radix select + stable compaction, one block per graph ----
__global__ __launch_bounds__(1024) void selcomp_kernel(
        const u64* __restrict__ keys, const float* __restrict__ score,
        int* __restrict__ selidx, float* __restrict__ selscr) {
    __shared__ u64 kk[NP_G];          // 50 KB
    __shared__ unsigned int hist[4][256];
    __shared__ unsigned int sfx[257];
    __shared__ u64 spref;
    __shared__ unsigned int swant;
    int g = blockIdx.x, t = threadIdx.x;
    const u64* kg = keys + (size_t)g * NP_G;
    for (int i = t; i < NP_G; i += 1024) kk[i] = kg[i];
    if (t == 0) { spref = 0ull; swant = KKEEP; }
    const int wgrp = (t >> 8) & 3;
    u64 mask = 0ull;
    __syncthreads();
    for (int shift = 40; shift >= 0; shift -= 8) {
        if (t < 256) { hist[0][t] = 0; hist[1][t] = 0; hist[2][t] = 0; hist[3][t] = 0; }
        __syncthreads();
        u64 pref = spref;
        for (int i = t; i < NP_G; i += 1024) {
            u64 key = kk[i];
            if ((key & mask) == pref)
                atomicAdd(&hist[wgrp][(unsigned int)(key >> shift) & 255u], 1u);
        }
        __syncthreads();
        if (t < 256) sfx[t] = hist[0][t] + hist[1][t] + hist[2][t] + hist[3][t];
        if (t == 0) sfx[256] = 0;
        __syncthreads();
        for (int off = 1; off < 256; off <<= 1) {
            unsigned int v = 0;
            if (t < 256 && t + off < 256) v = sfx[t + off];
            __syncthreads();
            if (t < 256 && t + off < 256) sfx[t] += v;
            __syncthreads();
        }
        unsigned int want = swant;
        __syncthreads();
        if (t < 256) {
            unsigned int s0 = sfx[t], s1 = sfx[t + 1];
            if (s0 >= want && s1 < want) {
                spref = pref | ((u64)t << shift);
                swant = want - s1;
            }
        }
        __syncthreads();
        mask |= (255ull << shift);
    }
    // ---- compaction from LDS keys (stable, ascending node id) ----
    u64 kth = spref;                      // sync'd by loop-final __syncthreads
    int lane = t & 63, wv = t >> 6;
    __shared__ int wsum[16];
    __shared__ int cbase;
    if (t == 0) cbase = 0;
    __syncthreads();
    for (int k = 0; k < (NP_G + 1023) / 1024; ++k) {
        int i = k * 1024 + t;
        bool sel = (i < NP_G) && (kk[i] >= kth);
        int n = g * NP_G + i;
        u64 bal = __ballot(sel);
        int prefix = __popcll(bal & ((1ull << lane) - 1ull));
        if (lane == 0) wsum[wv] = __popcll(bal);
        __syncthreads();
        if (t == 0) {
            int s = cbase;
            for (int j = 0; j < 16; ++j) { int tmp = wsum[j]; wsum[j] = s; s += tmp; }
            cbase = s;
        }
        __syncthreads();
        if (sel) {
            int pos = wsum[wv] + prefix;
            selidx[g * KKEEP + pos] = n;
            selscr[g * KKEEP + pos] = score[n];
        }
        __syncthreads();
    }
}

// ---------------- readout: branch-free gather over compacted list ----------------
__global__ __launch_bounds__(256) void readout_kernel(
        const u16* __restrict__ x1, const u16* __restrict__ x2,
        const u16* __restrict__ x3,
        const int* __restrict__ selidx, const float* __restrict__ selscr,
        float* __restrict__ sumbuf, int* __restrict__ maxbuf) {
    int g = blockIdx.x, tpart = blockIdx.y, c = blockIdx.z;
    int fcol = threadIdx.x;
    const u16* xt = (tpart == 0) ? x1 : ((tpart == 1) ? x2 : x3);
    __shared__ int   sidx[RCHUNK];
    __shared__ float sscr[RCHUNK];
    int base = g * KKEEP + c * RCHUNK;
    if (fcol < RCHUNK) { sidx[fcol] = selidx[base + fcol]; sscr[fcol] = selscr[base + fcol]; }
    __syncthreads();
    float sum = 0.f, mx = 0.f;
#pragma unroll 1
    for (int j = 0; j < RCHUNK; j += 4) {
        int n0 = sidx[j], n1 = sidx[j + 1], n2 = sidx[j + 2], n3 = sidx[j + 3];
        float s0 = sscr[j], s1 = sscr[j + 1], s2 = sscr[j + 2], s3 = sscr[j + 3];
        float v0 = bf2f(xt[(size_t)n0 * HID + fcol]) * s0;
        float v1 = bf2f(xt[(size_t)n1 * HID + fcol]) * s1;
        float v2 = bf2f(xt[(size_t)n2 * HID + fcol]) * s2;
        float v3 = bf2f(xt[(size_t)n3 * HID + fcol]) * s3;
        sum += v0 + v1 + v2 + v3;
        mx = fmaxf(mx, fmaxf(fmaxf(v0, v1), fmaxf(v2, v3)));
    }
    int o = (g * 3 + tpart) * HID + fcol;
    atomicAdd(&sumbuf[o], sum);
    atomicMax(&maxbuf[o], __float_as_int(mx));
}

// ---------------- MLP layer 1, k-split ----------------
__global__ __launch_bounds__(256) void mlp1_kernel(const float* __restrict__ sumbuf,
                                                   const int* __restrict__ maxbuf,
                                                   const float* __restrict__ lw1,
                                                   float* __restrict__ h1acc) {
    int g = blockIdx.x, ch = blockIdx.y, t = threadIdx.x;
    __shared__ float r[MLPCK];
    int k0 = ch * MLPCK;
    if (t < MLPCK) {
        int i = k0 + t;
        r[t] = (i < 768) ? sumbuf[g * 768 + i] * (1.f / 5000.f)
                         : __int_as_float(maxbuf[g * 768 + (i - 768)]);
    }
    __syncthreads();
    float a0 = 0.f, a1 = 0.f, a2 = 0.f, a3 = 0.f;
#pragma unroll
    for (int i = 0; i < MLPCK; i += 4) {
        a0 += r[i]     * lw1[(size_t)(k0 + i)     * 256 + t];
        a1 += r[i + 1] * lw1[(size_t)(k0 + i + 1) * 256 + t];
        a2 += r[i + 2] * lw1[(size_t)(k0 + i + 2) * 256 + t];
        a3 += r[i + 3] * lw1[(size_t)(k0 + i + 3) * 256 + t];
    }
    atomicAdd(&h1acc[g * 256 + t], (a0 + a1) + (a2 + a3));
}

// ---------------- MLP layers 2+3 ----------------
__global__ __launch_bounds__(256) void mlp2_kernel(const float* __restrict__ h1acc,
                                                   const float* __restrict__ lb1,
                                                   const float* __restrict__ lw2,
                                                   const float* __restrict__ lb2,
                                                   const float* __restrict__ lw3,
                                                   const float* __restrict__ lb3,
                                                   float* __restrict__ out) {
    __shared__ float h1[256];
    __shared__ float part[256];
    __shared__ float h2[128];
    int g = blockIdx.x, t = threadIdx.x;
    h1[t] = fmaxf(h1acc[g * 256 + t] + lb1[t], 0.f);
    __syncthreads();
    int col = t & 127, half = t >> 7;
    float a = 0.f;
#pragma unroll
    for (int i = 0; i < 128; i += 4) {
        int k = half * 128 + i;
        a += h1[k]     * lw2[k * 128 + col]
           + h1[k + 1] * lw2[(k + 1) * 128 + col]
           + h1[k + 2] * lw2[(k + 2) * 128 + col]
           + h1[k + 3] * lw2[(k + 3) * 128 + col];
    }
    part[t] = a;
    __syncthreads();
    if (t < 128) h2[t] = fmaxf(part[t] + part[t + 128] + lb2[t], 0.f);
    __syncthreads();
    if (t < 3) {
        float a3 = lb3[t];
        for (int i = 0; i < 128; ++i) a3 += h2[i] * lw3[i * 3 + t];
        out[g * 3 + t] = a3;
    }
}

extern "C" void kernel_launch(void* const* d_in, const int* in_sizes, int n_in,
                              void* d_out, int out_size, void* d_ws, size_t ws_size,
                              hipStream_t stream) {
    const float* x   = (const float*)d_in[0];
    const int*   ei  = (const int*)d_in[1];
    const float* ew  = (const float*)d_in[2];
    const float* W1  = (const float*)d_in[4];
    const float* b1  = (const float*)d_in[5];
    const float* W2  = (const float*)d_in[6];
    const float* b2  = (const float*)d_in[7];
    const float* pw  = (const float*)d_in[8];
    const float* lw1 = (const float*)d_in[9];
    const float* lb1 = (const float*)d_in[10];
    const float* lw2 = (const float*)d_in[11];
    const float* lb2 = (const float*)d_in[12];
    const float* lw3 = (const float*)d_in[13];
    const float* lb3 = (const float*)d_in[14];
    float* out = (float*)d_out;

    char* p = (char*)d_ws;
    auto alloc = [&](size_t bytes) -> char* {
        char* r = p;
        p += (bytes + 255) & ~(size_t)255;
        return r;
    };
    u16* A0  = (u16*)alloc((size_t)MPAD * CIN * 2);   // x bf16; x1/x2 alias after GEMM1
    u16* x3  = (u16*)alloc((size_t)MPAD * HID * 2);
    u16* xw  = (u16*)alloc((size_t)MPAD * HID * 2);
    u16* Wt1 = (u16*)alloc((size_t)HID * CIN * 2);
    u16* Wt2 = (u16*)alloc((size_t)HID * HID * 2);
    int2*  csr    = (int2*)alloc((size_t)EDGES * 8);
    int*   rowptr = (int*)alloc((size_t)(NODES + 1) * 4);
    int*   rowcur = (int*)alloc((size_t)NODES * 4);
    int*   iscan  = (int*)alloc((size_t)NODES * 4);
    int*   bsum   = (int*)alloc((size_t)SCANB * 4);
    int*   boff   = (int*)alloc((size_t)SCANB * 4);
    u64*   keys   = (u64*)alloc((size_t)NODES * 8);
    float* score  = (float*)alloc((size_t)NODES * 4);
    float* dinv   = (float*)alloc((size_t)NODES * 4);
    int*   selidx = (int*)alloc((size_t)NGRAPH * KKEEP * 4);
    float* selscr = (float*)alloc((size_t)NGRAPH * KKEEP * 4);
    float* invn   = (float*)alloc(256);
    char* zbase = p;                                  // everything below is zero-init
    u64*   degcnt = (u64*)alloc((size_t)NODES * 8);
    float* sumbuf = (float*)alloc(6144 * 4);
    int*   maxbuf = (int*)alloc(6144 * 4);
    float* h1acc  = (float*)alloc((size_t)NGRAPH * 256 * 4);
    size_t zbytes = (size_t)(p - zbase);

    u16* x1 = A0;                         // reuse A0 after GEMM1 consumed it
    u16* x2 = A0 + (size_t)MPAD * HID;

    hipMemsetAsync(zbase, 0, zbytes, stream);

    k1_kernel<<<K1_TOTAL, 256, 0, stream>>>(ei, ew, degcnt, x, A0,
                                            W1, W2, pw, Wt1, Wt2, invn);
    scan1_kernel<<<SCANB, 256, 0, stream>>>(degcnt, iscan, bsum, dinv);
    scan2_kernel<<<1, 256, 0, stream>>>(bsum, boff);
    scan3_kernel<<<SCANB + 1, 256, 0, stream>>>(degcnt, iscan, boff, rowptr, rowcur);
    k2_kernel<<<K2_TOTAL, 256, 0, stream>>>(A0, Wt1, xw, ei, ew, dinv, rowcur, csr);

    dim3 gg(MPAD / 128, HID / 128);
    int aggBlocks = 8 * ((NP_G + 3) / 4);   // graph = blockIdx & 7 (XCD pinning)

    agg_kernel<false><<<aggBlocks, 256, 0, stream>>>(xw, x1, rowptr, csr, dinv, b1,
                                                     nullptr, nullptr, nullptr, nullptr,
                                                     nullptr, nullptr);
    gemm_bt<<<gg, 256, 0, stream>>>(x1, Wt2, xw, HID);
    agg_kernel<false><<<aggBlocks, 256, 0, stream>>>(xw, x2, rowptr, csr, dinv, b2,
                                                     nullptr, nullptr, nullptr, nullptr,
                                                     nullptr, nullptr);
    gemm_bt<<<gg, 256, 0, stream>>>(x2, Wt2, xw, HID);
    agg_kernel<true><<<aggBlocks, 256, 0, stream>>>(xw, x3, rowptr, csr, dinv, b2,
                                                    x1, x2, pw, invn, score, keys);

    selcomp_kernel<<<NGRAPH, 1024, 0, stream>>>(keys, score, selidx, selscr);
    readout_kernel<<<dim3(NGRAPH, 3, KKEEP / RCHUNK), 256, 0, stream>>>(
        x1, x2, x3, selidx, selscr, sumbuf, maxbuf);
    mlp1_kernel<<<dim3(NGRAPH, MLPCH), 256, 0, stream>>>(sumbuf, maxbuf, lw1, h1acc);
    mlp2_kernel<<<NGRAPH, 256, 0, stream>>>(h1acc, lb1, lw2, lb2, lw3, lb3, out);
}

// Round 8
// 488.918 us; speedup vs baseline: 1.8434x; 1.0653x over previous
//
#include <hip/hip_runtime.h>
#include <stdint.h>

#define NODES  50000
#define MPAD   50048      // 391 * 128
#define NGRAPH 8
#define NP_G   6250
#define EPG    100000
#define EDGES  800000
#define KKEEP  5000
#define HID    256
#define CIN    512
#define H3     768
#define SCANB  196        // 196*256 = 50176 >= NODES
#define RCHUNK 200        // KKEEP / 25
#define MLPCH  24         // layer-1 k-chunks
#define MLPCK  64         // 1536 / 24
#define ESL    3125       // edges per slice (EPG/32); also NP_G/2 bucket-half

// K1 block ranges: hist, cast_x, cast_W1, cast_W2, pwnorm
#define K1_HIST  512
#define K1_CAST  25000    // 50000*512/(4*256)
#define K1_W1    512
#define K1_W2    256
#define K1_TOTAL (K1_HIST + K1_CAST + K1_W1 + K1_W2 + 1)
// K2 block ranges: gemm1 + csr fill
#define K2_GEMM  782      // 391*2
#define K2_FILL  256      // 8 graphs * 32 slices
#define K2_TOTAL (K2_GEMM + K2_FILL)

using f32x4  = __attribute__((ext_vector_type(4))) float;
using bf16x8 = __attribute__((ext_vector_type(8))) short;
using u16x8  = __attribute__((ext_vector_type(8))) unsigned short;
typedef unsigned short u16;
typedef unsigned int   u32;
typedef unsigned long long u64;

__device__ __forceinline__ float bf2f(u16 u) {
    return __uint_as_float(((uint32_t)u) << 16);
}
__device__ __forceinline__ u16 f2bf(float f) {     // RNE
    uint32_t u = __float_as_uint(f);
    u += 0x7fffu + ((u >> 16) & 1u);
    return (u16)(u >> 16);
}

// ---------------- K1: LDS edge histograms + x cast + W casts + pwnorm ------------
// hist: 512 blocks = (graph, 32 edge-slices, 2 bucket-halves). No global atomics.
__global__ __launch_bounds__(256) void k1_kernel(
        const int* __restrict__ ei, const float* __restrict__ ew,
        u64* __restrict__ partial,
        const float* __restrict__ x, u16* __restrict__ A0,
        const float* __restrict__ W1, const float* __restrict__ W2,
        const float* __restrict__ pw,
        u16* __restrict__ Wt1, u16* __restrict__ Wt2, float* __restrict__ invn) {
    __shared__ __align__(16) char smem[ESL * 8];   // 25000 B
    int b = blockIdx.x, t = threadIdx.x;
    if (b < K1_HIST) {
        u64* hl = (u64*)smem;                       // 3125 buckets (one half)
        int g  = b >> 6;
        int r  = b & 63;
        int bb = r >> 1;                            // edge slice 0..31
        int h  = r & 1;                             // bucket half
        for (int k = t; k < ESL; k += 256) hl[k] = 0ull;
        __syncthreads();
        int ebase = g * EPG + bb * ESL;
        int lo = h * ESL;
        for (int k = t; k < ESL; k += 256) {
            int e = ebase + k;
            int d = ei[EDGES + e];
            int il = d - g * NP_G - lo;
            if ((unsigned)il < (unsigned)ESL) {
                u64 enc = (1ull << 48) | (u64)(ew[e] * 4294967296.0f);
                atomicAdd(&hl[il], enc);            // LDS atomic
            }
        }
        __syncthreads();
        u64* prow = partial + (size_t)(g * 32 + bb) * NP_G + lo;
        for (int k = t; k < ESL; k += 256) prow[k] = hl[k];
    } else if (b < K1_HIST + K1_CAST) {             // cast x -> bf16 (real rows)
        size_t base = ((size_t)(b - K1_HIST) * 256 + t) * 4;
        float4 v = *(const float4*)(x + base);
        ushort4 o;
        o.x = f2bf(v.x); o.y = f2bf(v.y); o.z = f2bf(v.z); o.w = f2bf(v.w);
        *(ushort4*)(A0 + base) = o;
    } else if (b < K1_HIST + K1_CAST + K1_W1) {     // Wt1[n*512+k] = W1[k*256+n]
        int id = (b - K1_HIST - K1_CAST) * 256 + t;
        int n = id >> 9, k = id & 511;
        Wt1[id] = f2bf(W1[(size_t)k * HID + n]);
    } else if (b < K1_TOTAL - 1) {                  // Wt2[n*256+k] = W2[k*256+n]
        int id = (b - K1_HIST - K1_CAST - K1_W1) * 256 + t;
        int n = id >> 8, k = id & 255;
        Wt2[id] = f2bf(W2[(size_t)k * HID + n]);
    } else {                                        // pwnorm
        float* sh = (float*)smem;
        float s = 0.f;
        for (int i = t; i < H3; i += 256) { float v = pw[i]; s += v * v; }
        sh[t] = s; __syncthreads();
        for (int off = 128; off; off >>= 1) {
            if (t < off) sh[t] += sh[t + off];
            __syncthreads();
        }
        if (t == 0) invn[0] = rsqrtf(sh[0]);
    }
}

// ---- scan1 v2: reduce 32 partials/node -> count + deg; emit per-block prefixes ---
__global__ void scan1_kernel(const u64* __restrict__ partial,
                             u32* __restrict__ blockbase,
                             int* __restrict__ iscan, int* __restrict__ bsum,
                             float* __restrict__ dinv) {
    int b = blockIdx.x, t = threadIdx.x;
    int i = b * 256 + t;
    int c = 0;
    if (i < NODES) {
        int g = i / NP_G, il = i - g * NP_G;
        size_t base = (size_t)(g * 32) * NP_G + il;
        u64 fix = 0ull; u32 cnt = 0;
#pragma unroll 4
        for (int j = 0; j < 32; ++j) {
            size_t idx = base + (size_t)j * NP_G;
            u64 pv = partial[idx];
            blockbase[idx] = cnt;                 // exclusive prefix over blocks
            cnt += (u32)(pv >> 48);
            fix += pv & 0xFFFFFFFFFFFFull;
        }
        c = (int)cnt;
        float deg = (float)fix * (1.0f / 4294967296.0f);
        dinv[i] = rsqrtf(deg + 1.0f);
    }
    int lane = t & 63, wv = t >> 6;
    int v = c;
    for (int off = 1; off < 64; off <<= 1) {
        int u = __shfl_up(v, off);
        if (lane >= off) v += u;
    }
    __shared__ int ws[4];
    if (lane == 63) ws[wv] = v;
    __syncthreads();
    if (t == 0) { int s = 0; for (int k = 0; k < 4; k++) { int tmp = ws[k]; ws[k] = s; s += tmp; } }
    __syncthreads();
    v += ws[wv];
    if (i < NODES) iscan[i] = v - c;              // block-local EXCLUSIVE scan
    if (t == 255) bsum[b] = v;
}

__global__ void scan2_kernel(const int* __restrict__ bsum, int* __restrict__ boff) {
    int t = threadIdx.x;
    int c = (t < SCANB) ? bsum[t] : 0;
    int lane = t & 63, wv = t >> 6;
    int v = c;
    for (int off = 1; off < 64; off <<= 1) {
        int u = __shfl_up(v, off);
        if (lane >= off) v += u;
    }
    __shared__ int ws[4];
    if (lane == 63) ws[wv] = v;
    __syncthreads();
    if (t == 0) { int s = 0; for (int k = 0; k < 4; k++) { int tmp = ws[k]; ws[k] = s; s += tmp; } }
    __syncthreads();
    v += ws[wv];
    if (t < SCANB) boff[t] = v - c;
}

__global__ void scan3_kernel(const int* __restrict__ iscan, const int* __restrict__ boff,
                             int* __restrict__ rowptr) {
    int b = blockIdx.x, t = threadIdx.x;
    int i = b * 256 + t;
    if (i > NODES) return;
    if (i == NODES) { rowptr[NODES] = EDGES; return; }
    rowptr[i] = boff[b] + iscan[i];
}

// ---------------- GEMM body ----------------
__device__ __forceinline__ void gemm_body(const u16* __restrict__ A,
                                          const u16* __restrict__ Bt,
                                          u16* __restrict__ C,
                                          int K, int bm, int bn,
                                          u16* As, u16* Bs) {
    const int tid  = threadIdx.x;
    const int wave = tid >> 6, lane = tid & 63;
    const int wm = wave >> 1, wn = wave & 1;
    const int quad = lane >> 4, l16 = lane & 15;
    const int sr = tid >> 2;
    const int sc = tid & 3;
    const int swz = (sc ^ ((sr >> 1) & 3)) * 8;
    const int rphys = (quad ^ ((l16 >> 1) & 3)) * 8;

    const u16* Ag = A + (size_t)(bm * 128 + sr) * K + sc * 8;
    const u16* Bg = Bt + (size_t)(bn * 128 + sr) * K + sc * 8;

    f32x4 acc[4][4];
#pragma unroll
    for (int i = 0; i < 4; i++)
#pragma unroll
        for (int j = 0; j < 4; j++) { f32x4 z = {0.f, 0.f, 0.f, 0.f}; acc[i][j] = z; }

    for (int k0 = 0; k0 < K; k0 += 32) {
        int4 av0 = *(const int4*)(Ag + k0);
        int4 av1 = *(const int4*)(Ag + (size_t)64 * K + k0);
        int4 bv0 = *(const int4*)(Bg + k0);
        int4 bv1 = *(const int4*)(Bg + (size_t)64 * K + k0);
        __syncthreads();
        *(int4*)(As + sr * 32 + swz)        = av0;
        *(int4*)(As + (sr + 64) * 32 + swz) = av1;
        *(int4*)(Bs + sr * 32 + swz)        = bv0;
        *(int4*)(Bs + (sr + 64) * 32 + swz) = bv1;
        __syncthreads();
        bf16x8 af[4], bfr[4];
#pragma unroll
        for (int i = 0; i < 4; i++)
            af[i] = *(const bf16x8*)(As + (wm * 64 + i * 16 + l16) * 32 + rphys);
#pragma unroll
        for (int j = 0; j < 4; j++)
            bfr[j] = *(const bf16x8*)(Bs + (wn * 64 + j * 16 + l16) * 32 + rphys);
#pragma unroll
        for (int i = 0; i < 4; i++)
#pragma unroll
            for (int j = 0; j < 4; j++)
                acc[i][j] = __builtin_amdgcn_mfma_f32_16x16x32_bf16(af[i], bfr[j], acc[i][j], 0, 0, 0);
    }

    const int crow0 = bm * 128 + wm * 64 + quad * 4;
    const int ccol0 = bn * 128 + wn * 64 + l16;
#pragma unroll
    for (int i = 0; i < 4; i++)
#pragma unroll
        for (int j = 0; j < 4; j++)
#pragma unroll
            for (int r = 0; r < 4; r++)
                C[(size_t)(crow0 + i * 16 + r) * HID + ccol0 + j * 16] = f2bf(acc[i][j][r]);
}

// ---------------- K2: GEMM1 + CSR fill via LDS counting sort ---------------------
__global__ __launch_bounds__(256) void k2_kernel(
        const u16* __restrict__ A0, const u16* __restrict__ Wt1, u16* __restrict__ xw,
        const int* __restrict__ ei, const float* __restrict__ ew,
        const float* __restrict__ dinv, const int* __restrict__ rowptr,
        const u32* __restrict__ blockbase, int2* __restrict__ csr) {
    __shared__ __align__(16) char smem[NP_G * 4];   // 25000 B (>= 16384 for gemm)
    int b = blockIdx.x;
    if (b < K2_GEMM) {
        u16* As = (u16*)smem;
        u16* Bs = (u16*)(smem + 8192);
        gemm_body(A0, Wt1, xw, CIN, b >> 1, b & 1, As, Bs);
    } else {
        u32* cursor = (u32*)smem;                   // 6250 u32
        int fb = b - K2_GEMM;
        int g = fb >> 5, bb = fb & 31;
        const u32* bbase = blockbase + (size_t)(g * 32 + bb) * NP_G;
        const int* rp = rowptr + g * NP_G;
        for (int k = threadIdx.x; k < NP_G; k += 256)
            cursor[k] = (u32)rp[k] + bbase[k];
        __syncthreads();
        int ebase = g * EPG + bb * ESL;
        for (int k = threadIdx.x; k < ESL; k += 256) {
            int e = ebase + k;
            int s = ei[e], d = ei[EDGES + e];
            int il = d - g * NP_G;
            u32 pos = atomicAdd(&cursor[il], 1u);   // LDS atomic
            csr[pos] = make_int2(s, __float_as_int(dinv[s] * ew[e] * dinv[d]));
        }
    }
}

// plain GEMM (layers 2,3)
__global__ __launch_bounds__(256) void gemm_bt(const u16* __restrict__ A,
                                               const u16* __restrict__ Bt,
                                               u16* __restrict__ C, int K) {
    __shared__ u16 As[128 * 32];
    __shared__ u16 Bs[128 * 32];
    gemm_body(A, Bt, C, K, blockIdx.x, blockIdx.y, As, Bs);
}

// ---------------- aggregation: half-wave 16B gathers; SCORE fuses TopK scoring ----
template<bool SCORE>
__global__ void agg_kernel(const u16* __restrict__ xw, u16* __restrict__ xo,
                           const int* __restrict__ rowptr, const int2* __restrict__ csr,
                           const float* __restrict__ dinv, const float* __restrict__ bias,
                           const u16* __restrict__ xs1, const u16* __restrict__ xs2,
                           const float* __restrict__ pw, const float* __restrict__ invn,
                           float* __restrict__ score, u64* __restrict__ keys) {
    int wave = threadIdx.x >> 6;
    int lane = threadIdx.x & 63;
    int g  = blockIdx.x & 7;
    int nl = (blockIdx.x >> 3) * 4 + wave;
    if (nl >= NP_G) return;
    int w = g * NP_G + nl;
    int half = lane >> 5;
    int f8 = (lane & 31) * 8;
    size_t ro = (size_t)w * HID + f8;

    float accA[8], accB[8];
#pragma unroll
    for (int j = 0; j < 8; ++j) { accA[j] = 0.f; accB[j] = 0.f; }

    int p = rowptr[w], p1 = rowptr[w + 1];
    for (; p + 4 <= p1; p += 4) {
        int2 eA = csr[p + half];
        int2 eB = csr[p + 2 + half];
        float wA = __int_as_float(eA.y), wB = __int_as_float(eB.y);
        u16x8 vA = *(const u16x8*)(xw + (size_t)eA.x * HID + f8);
        u16x8 vB = *(const u16x8*)(xw + (size_t)eB.x * HID + f8);
#pragma unroll
        for (int j = 0; j < 8; ++j) {
            accA[j] += wA * bf2f(vA[j]);
            accB[j] += wB * bf2f(vB[j]);
        }
    }
    for (; p < p1; p += 2) {
        int idx = p + half;
        bool valid = idx < p1;
        int2 eA = csr[valid ? idx : p];
        float wA = valid ? __int_as_float(eA.y) : 0.f;
        u16x8 vA = *(const u16x8*)(xw + (size_t)eA.x * HID + f8);
#pragma unroll
        for (int j = 0; j < 8; ++j) accA[j] += wA * bf2f(vA[j]);
    }

#pragma unroll
    for (int j = 0; j < 8; ++j) {
        accA[j] += accB[j];
        accA[j] += __shfl(accA[j], lane ^ 32, 64);
    }

    float di = dinv[w], sw = di * di;
    u16x8 sv = *(const u16x8*)(xw + ro);
    float bb[8];
    {
        float4 t0 = *(const float4*)(bias + f8);
        float4 t1 = *(const float4*)(bias + f8 + 4);
        bb[0] = t0.x; bb[1] = t0.y; bb[2] = t0.z; bb[3] = t0.w;
        bb[4] = t1.x; bb[5] = t1.y; bb[6] = t1.z; bb[7] = t1.w;
    }
    u16x8 o;
    float ov[8];
#pragma unroll
    for (int j = 0; j < 8; ++j) {
        float v = fmaxf(accA[j] + sw * bf2f(sv[j]) + bb[j], 0.f);
        o[j] = f2bf(v);
        ov[j] = bf2f(o[j]);               // post-rounding value (matches stored x3)
    }
    if (half == 0) *(u16x8*)(xo + ro) = o;

    if (SCORE) {
        u16x8 v1 = *(const u16x8*)(xs1 + ro);
        u16x8 v2 = *(const u16x8*)(xs2 + ro);
        float acc = 0.f;
#pragma unroll
        for (int j = 0; j < 8; ++j) {
            acc += bf2f(v1[j]) * pw[f8 + j];
            acc += bf2f(v2[j]) * pw[256 + f8 + j];
            acc += ov[j]       * pw[512 + f8 + j];
        }
#pragma unroll
        for (int off = 1; off < 32; off <<= 1) acc += __shfl_xor(acc, off, 64);
        if (lane == 0) {
            float s = acc * invn[0];
            float sc = 1.f / (1.f + __expf(-s));
            score[w] = sc;
            keys[w] = ((u64)__float_as_uint(sc) << 13) | (unsigned int)(NP_G - 1 - nl);
        }
    }
}

// ---------------- top-K radix select + stable compaction, one block per graph ----
__global__ __launch_bounds__(1024) void selcomp_kernel(
        const u64* __restrict__ keys, const float* __restrict__ score,
        int* __restrict__ selidx, float* __restrict__ selscr) {
    __shared__ u64 kk[NP_G];          // 50 KB
    __shared__ unsigned int hist[4][256];
    __shared__ unsigned int sfx[257];
    __shared__ u64 spref;
    __shared__ unsigned int swant;
    int g = blockIdx.x, t = threadIdx.x;
    const u64* kg = keys + (size_t)g * NP_G;
    for (int i = t; i < NP_G; i += 1024) kk[i] = kg[i];
    if (t == 0) { spref = 0ull; swant = KKEEP; }
    const int wgrp = (t >> 8) & 3;
    u64 mask = 0ull;
    __syncthreads();
    for (int shift = 40; shift >= 0; shift -= 8) {
        if (t < 256) { hist[0][t] = 0; hist[1][t] = 0; hist[2][t] = 0; hist[3][t] = 0; }
        __syncthreads();
        u64 pref = spref;
        for (int i = t; i < NP_G; i += 1024) {
            u64 key = kk[i];
            if ((key & mask) == pref)
                atomicAdd(&hist[wgrp][(unsigned int)(key >> shift) & 255u], 1u);
        }
        __syncthreads();
        if (t < 256) sfx[t] = hist[0][t] + hist[1][t] + hist[2][t] + hist[3][t];
        if (t == 0) sfx[256] = 0;
        __syncthreads();
        for (int off = 1; off < 256; off <<= 1) {
            unsigned int v = 0;
            if (t < 256 && t + off < 256) v = sfx[t + off];
            __syncthreads();
            if (t < 256 && t + off < 256) sfx[t] += v;
            __syncthreads();
        }
        unsigned int want = swant;
        __syncthreads();
        if (t < 256) {
            unsigned int s0 = sfx[t], s1 = sfx[t + 1];
            if (s0 >= want && s1 < want) {
                spref = pref | ((u64)t << shift);
                swant = want - s1;
            }
        }
        __syncthreads();
        mask |= (255ull << shift);
    }
    u64 kth = spref;
    int lane = t & 63, wv = t >> 6;
    __shared__ int wsum[16];
    __shared__ int cbase;
    if (t == 0) cbase = 0;
    __syncthreads();
    for (int k = 0; k < (NP_G + 1023) / 1024; ++k) {
        int i = k * 1024 + t;
        bool sel = (i < NP_G) && (kk[i] >= kth);
        int n = g * NP_G + i;
        u64 bal = __ballot(sel);
        int prefix = __popcll(bal & ((1ull << lane) - 1ull));
        if (lane == 0) wsum[wv] = __popcll(bal);
        __syncthreads();
        if (t == 0) {
            int s = cbase;
            for (int j = 0; j < 16; ++j) { int tmp = wsum[j]; wsum[j] = s; s += tmp; }
            cbase = s;
        }
        __syncthreads();
        if (sel) {
            int pos = wsum[wv] + prefix;
            selidx[g * KKEEP + pos] = n;
            selscr[g * KKEEP + pos] = score[n];
        }
        __syncthreads();
    }
}

// ---------------- readout: branch-free gather over compacted list ----------------
__global__ __launch_bounds__(256) void readout_kernel(
        const u16* __restrict__ x1, const u16* __restrict__ x2,
        const u16* __restrict__ x3,
        const int* __restrict__ selidx, const float* __restrict__ selscr,
        float* __restrict__ sumbuf, int* __restrict__ maxbuf) {
    int g = blockIdx.x, tpart = blockIdx.y, c = blockIdx.z;
    int fcol = threadIdx.x;
    const u16* xt = (tpart == 0) ? x1 : ((tpart == 1) ? x2 : x3);
    __shared__ int   sidx[RCHUNK];
    __shared__ float sscr[RCHUNK];
    int base = g * KKEEP + c * RCHUNK;
    if (fcol < RCHUNK) { sidx[fcol] = selidx[base + fcol]; sscr[fcol] = selscr[base + fcol]; }
    __syncthreads();
    float sum = 0.f, mx = 0.f;
#pragma unroll 1
    for (int j = 0; j < RCHUNK; j += 4) {
        int n0 = sidx[j], n1 = sidx[j + 1], n2 = sidx[j + 2], n3 = sidx[j + 3];
        float s0 = sscr[j], s1 = sscr[j + 1], s2 = sscr[j + 2], s3 = sscr[j + 3];
        float v0 = bf2f(xt[(size_t)n0 * HID + fcol]) * s0;
        float v1 = bf2f(xt[(size_t)n1 * HID + fcol]) * s1;
        float v2 = bf2f(xt[(size_t)n2 * HID + fcol]) * s2;
        float v3 = bf2f(xt[(size_t)n3 * HID + fcol]) * s3;
        sum += v0 + v1 + v2 + v3;
        mx = fmaxf(mx, fmaxf(fmaxf(v0, v1), fmaxf(v2, v3)));
    }
    int o = (g * 3 + tpart) * HID + fcol;
    atomicAdd(&sumbuf[o], sum);
    atomicMax(&maxbuf[o], __float_as_int(mx));
}

// ---------------- MLP layer 1, k-split ----------------
__global__ __launch_bounds__(256) void mlp1_kernel(const float* __restrict__ sumbuf,
                                                   const int* __restrict__ maxbuf,
                                                   const float* __restrict__ lw1,
                                                   float* __restrict__ h1acc) {
    int g = blockIdx.x, ch = blockIdx.y, t = threadIdx.x;
    __shared__ float r[MLPCK];
    int k0 = ch * MLPCK;
    if (t < MLPCK) {
        int i = k0 + t;
        r[t] = (i < 768) ? sumbuf[g * 768 + i] * (1.f / 5000.f)
                         : __int_as_float(maxbuf[g * 768 + (i - 768)]);
    }
    __syncthreads();
    float a0 = 0.f, a1 = 0.f, a2 = 0.f, a3 = 0.f;
#pragma unroll
    for (int i = 0; i < MLPCK; i += 4) {
        a0 += r[i]     * lw1[(size_t)(k0 + i)     * 256 + t];
        a1 += r[i + 1] * lw1[(size_t)(k0 + i + 1) * 256 + t];
        a2 += r[i + 2] * lw1[(size_t)(k0 + i + 2) * 256 + t];
        a3 += r[i + 3] * lw1[(size_t)(k0 + i + 3) * 256 + t];
    }
    atomicAdd(&h1acc[g * 256 + t], (a0 + a1) + (a2 + a3));
}

// ---------------- MLP layers 2+3 ----------------
__global__ __launch_bounds__(256) void mlp2_kernel(const float* __restrict__ h1acc,
                                                   const float* __restrict__ lb1,
                                                   const float* __restrict__ lw2,
                                                   const float* __restrict__ lb2,
                                                   const float* __restrict__ lw3,
                                                   const float* __restrict__ lb3,
                                                   float* __restrict__ out) {
    __shared__ float h1[256];
    __shared__ float part[256];
    __shared__ float h2[128];
    int g = blockIdx.x, t = threadIdx.x;
    h1[t] = fmaxf(h1acc[g * 256 + t] + lb1[t], 0.f);
    __syncthreads();
    int col = t & 127, half = t >> 7;
    float a = 0.f;
#pragma unroll
    for (int i = 0; i < 128; i += 4) {
        int k = half * 128 + i;
        a += h1[k]     * lw2[k * 128 + col]
           + h1[k + 1] * lw2[(k + 1) * 128 + col]
           + h1[k + 2] * lw2[(k + 2) * 128 + col]
           + h1[k + 3] * lw2[(k + 3) * 128 + col];
    }
    part[t] = a;
    __syncthreads();
    if (t < 128) h2[t] = fmaxf(part[t] + part[t + 128] + lb2[t], 0.f);
    __syncthreads();
    if (t < 3) {
        float a3 = lb3[t];
        for (int i = 0; i < 128; ++i) a3 += h2[i] * lw3[i * 3 + t];
        out[g * 3 + t] = a3;
    }
}

extern "C" void kernel_launch(void* const* d_in, const int* in_sizes, int n_in,
                              void* d_out, int out_size, void* d_ws, size_t ws_size,
                              hipStream_t stream) {
    const float* x   = (const float*)d_in[0];
    const int*   ei  = (const int*)d_in[1];
    const float* ew  = (const float*)d_in[2];
    const float* W1  = (const float*)d_in[4];
    const float* b1  = (const float*)d_in[5];
    const float* W2  = (const float*)d_in[6];
    const float* b2  = (const float*)d_in[7];
    const float* pw  = (const float*)d_in[8];
    const float* lw1 = (const float*)d_in[9];
    const float* lb1 = (const float*)d_in[10];
    const float* lw2 = (const float*)d_in[11];
    const float* lb2 = (const float*)d_in[12];
    const float* lw3 = (const float*)d_in[13];
    const float* lb3 = (const float*)d_in[14];
    float* out = (float*)d_out;

    char* p = (char*)d_ws;
    auto alloc = [&](size_t bytes) -> char* {
        char* r = p;
        p += (bytes + 255) & ~(size_t)255;
        return r;
    };
    u16* A0  = (u16*)alloc((size_t)MPAD * CIN * 2);   // x bf16; x1/x2 alias after GEMM1
    u16* x3  = (u16*)alloc((size_t)MPAD * HID * 2);
    u16* xw  = (u16*)alloc((size_t)MPAD * HID * 2);
    u16* Wt1 = (u16*)alloc((size_t)HID * CIN * 2);
    u16* Wt2 = (u16*)alloc((size_t)HID * HID * 2);
    int2*  csr    = (int2*)alloc((size_t)EDGES * 8);
    u64*   partial   = (u64*)alloc((size_t)256 * NP_G * 8);   // 12.8 MB
    u32*   blockbase = (u32*)alloc((size_t)256 * NP_G * 4);   // 6.4 MB
    int*   rowptr = (int*)alloc((size_t)(NODES + 1) * 4);
    int*   iscan  = (int*)alloc((size_t)NODES * 4);
    int*   bsum   = (int*)alloc((size_t)SCANB * 4);
    int*   boff   = (int*)alloc((size_t)SCANB * 4);
    u64*   keys   = (u64*)alloc((size_t)NODES * 8);
    float* score  = (float*)alloc((size_t)NODES * 4);
    float* dinv   = (float*)alloc((size_t)NODES * 4);
    int*   selidx = (int*)alloc((size_t)NGRAPH * KKEEP * 4);
    float* selscr = (float*)alloc((size_t)NGRAPH * KKEEP * 4);
    float* invn   = (float*)alloc(256);
    char* zbase = p;                                  // everything below is zero-init
    float* sumbuf = (float*)alloc(6144 * 4);
    int*   maxbuf = (int*)alloc(6144 * 4);
    float* h1acc  = (float*)alloc((size_t)NGRAPH * 256 * 4);
    size_t zbytes = (size_t)(p - zbase);

    u16* x1 = A0;                         // reuse A0 after GEMM1 consumed it
    u16* x2 = A0 + (size_t)MPAD * HID;

    hipMemsetAsync(zbase, 0, zbytes, stream);

    k1_kernel<<<K1_TOTAL, 256, 0, stream>>>(ei, ew, partial, x, A0,
                                            W1, W2, pw, Wt1, Wt2, invn);
    scan1_kernel<<<SCANB, 256, 0, stream>>>(partial, blockbase, iscan, bsum, dinv);
    scan2_kernel<<<1, 256, 0, stream>>>(bsum, boff);
    scan3_kernel<<<SCANB + 1, 256, 0, stream>>>(iscan, boff, rowptr);
    k2_kernel<<<K2_TOTAL, 256, 0, stream>>>(A0, Wt1, xw, ei, ew, dinv, rowptr,
                                            blockbase, csr);

    dim3 gg(MPAD / 128, HID / 128);
    int aggBlocks = 8 * ((NP_G + 3) / 4);   // graph = blockIdx & 7 (XCD pinning)

    agg_kernel<false><<<aggBlocks, 256, 0, stream>>>(xw, x1, rowptr, csr, dinv, b1,
                                                     nullptr, nullptr, nullptr, nullptr,
                                                     nullptr, nullptr);
    gemm_bt<<<gg, 256, 0, stream>>>(x1, Wt2, xw, HID);
    agg_kernel<false><<<aggBlocks, 256, 0, stream>>>(xw, x2, rowptr, csr, dinv, b2,
                                                     nullptr, nullptr, nullptr, nullptr,
                                                     nullptr, nullptr);
    gemm_bt<<<gg, 256, 0, stream>>>(x2, Wt2, xw, HID);
    agg_kernel<true><<<aggBlocks, 256, 0, stream>>>(xw, x3, rowptr, csr, dinv, b2,
                                                    x1, x2, pw, invn, score, keys);

    selcomp_kernel<<<NGRAPH, 1024, 0, stream>>>(keys, score, selidx, selscr);
    readout_kernel<<<dim3(NGRAPH, 3, KKEEP / RCHUNK), 256, 0, stream>>>(
        x1, x2, x3, selidx, selscr, sumbuf, maxbuf);
    mlp1_kernel<<<dim3(NGRAPH, MLPCH), 256, 0, stream>>>(sumbuf, maxbuf, lw1, h1acc);
    mlp2_kernel<<<NGRAPH, 256, 0, stream>>>(h1acc, lb1, lw2, lb2, lw3, lb3, out);
}

// Round 9
// 480.330 us; speedup vs baseline: 1.8764x; 1.0179x over previous
//
#include <hip/hip_runtime.h>
#include <stdint.h>

#define NODES  50000
#define MPAD   50048      // 391 * 128
#define NGRAPH 8
#define NP_G   6250
#define EPG    100000
#define EDGES  800000
#define KKEEP  5000
#define HID    256
#define CIN    512
#define H3     768
#define SCANB  196        // 196*256 = 50176 >= NODES
#define RCHUNK 200        // KKEEP / 25
#define MLPCH  24         // layer-1 k-chunks
#define MLPCK  64         // 1536 / 24
#define ESL    3125       // edges per slice (EPG/32); also NP_G/2 bucket-half

// K1 block ranges: hist, cast_x, cast_W1, cast_W2, pwnorm
#define K1_HIST  512
#define K1_CAST  25000    // 50000*512/(4*256)
#define K1_W1    512
#define K1_W2    256
#define K1_TOTAL (K1_HIST + K1_CAST + K1_W1 + K1_W2 + 1)
// K2 block ranges: gemm1 + csr fill
#define K2_GEMM  782      // 391*2
#define K2_FILL  256      // 8 graphs * 32 slices
#define K2_TOTAL (K2_GEMM + K2_FILL)

using f32x4  = __attribute__((ext_vector_type(4))) float;
using bf16x8 = __attribute__((ext_vector_type(8))) short;
using u16x8  = __attribute__((ext_vector_type(8))) unsigned short;
typedef unsigned short u16;
typedef unsigned int   u32;
typedef unsigned long long u64;

__device__ __forceinline__ float bf2f(u16 u) {
    return __uint_as_float(((uint32_t)u) << 16);
}
__device__ __forceinline__ u16 f2bf(float f) {     // RNE
    uint32_t u = __float_as_uint(f);
    u += 0x7fffu + ((u >> 16) & 1u);
    return (u16)(u >> 16);
}

// ---------------- K1: LDS edge histograms + x cast + W casts + pwnorm ------------
// hist: 512 blocks = (graph, 32 edge-slices, 2 bucket-halves). No global atomics.
__global__ __launch_bounds__(256) void k1_kernel(
        const int* __restrict__ ei, const float* __restrict__ ew,
        u64* __restrict__ partial,
        const float* __restrict__ x, u16* __restrict__ A0,
        const float* __restrict__ W1, const float* __restrict__ W2,
        const float* __restrict__ pw,
        u16* __restrict__ Wt1, u16* __restrict__ Wt2, float* __restrict__ invn) {
    __shared__ __align__(16) char smem[ESL * 8];   // 25000 B
    int b = blockIdx.x, t = threadIdx.x;
    if (b < K1_HIST) {
        u64* hl = (u64*)smem;                       // 3125 buckets (one half)
        int g  = b >> 6;
        int r  = b & 63;
        int bb = r >> 1;                            // edge slice 0..31
        int h  = r & 1;                             // bucket half
        for (int k = t; k < ESL; k += 256) hl[k] = 0ull;
        __syncthreads();
        int ebase = g * EPG + bb * ESL;
        int lo = h * ESL;
        for (int k = t; k < ESL; k += 256) {
            int e = ebase + k;
            int d = ei[EDGES + e];
            int il = d - g * NP_G - lo;
            if ((unsigned)il < (unsigned)ESL) {
                u64 enc = (1ull << 48) | (u64)(ew[e] * 4294967296.0f);
                atomicAdd(&hl[il], enc);            // LDS atomic
            }
        }
        __syncthreads();
        u64* prow = partial + (size_t)(g * 32 + bb) * NP_G + lo;
        for (int k = t; k < ESL; k += 256) prow[k] = hl[k];
    } else if (b < K1_HIST + K1_CAST) {             // cast x -> bf16 (real rows)
        size_t base = ((size_t)(b - K1_HIST) * 256 + t) * 4;
        float4 v = *(const float4*)(x + base);
        ushort4 o;
        o.x = f2bf(v.x); o.y = f2bf(v.y); o.z = f2bf(v.z); o.w = f2bf(v.w);
        *(ushort4*)(A0 + base) = o;
    } else if (b < K1_HIST + K1_CAST + K1_W1) {     // Wt1[n*512+k] = W1[k*256+n]
        int id = (b - K1_HIST - K1_CAST) * 256 + t;
        int n = id >> 9, k = id & 511;
        Wt1[id] = f2bf(W1[(size_t)k * HID + n]);
    } else if (b < K1_TOTAL - 1) {                  // Wt2[n*256+k] = W2[k*256+n]
        int id = (b - K1_HIST - K1_CAST - K1_W1) * 256 + t;
        int n = id >> 8, k = id & 255;
        Wt2[id] = f2bf(W2[(size_t)k * HID + n]);
    } else {                                        // pwnorm
        float* sh = (float*)smem;
        float s = 0.f;
        for (int i = t; i < H3; i += 256) { float v = pw[i]; s += v * v; }
        sh[t] = s; __syncthreads();
        for (int off = 128; off; off >>= 1) {
            if (t < off) sh[t] += sh[t + off];
            __syncthreads();
        }
        if (t == 0) invn[0] = rsqrtf(sh[0]);
    }
}

// ---- scan1 v2: reduce 32 partials/node -> count + deg; emit per-block prefixes ---
__global__ void scan1_kernel(const u64* __restrict__ partial,
                             u32* __restrict__ blockbase,
                             int* __restrict__ iscan, int* __restrict__ bsum,
                             float* __restrict__ dinv) {
    int b = blockIdx.x, t = threadIdx.x;
    int i = b * 256 + t;
    int c = 0;
    if (i < NODES) {
        int g = i / NP_G, il = i - g * NP_G;
        size_t base = (size_t)(g * 32) * NP_G + il;
        u64 fix = 0ull; u32 cnt = 0;
#pragma unroll 4
        for (int j = 0; j < 32; ++j) {
            size_t idx = base + (size_t)j * NP_G;
            u64 pv = partial[idx];
            blockbase[idx] = cnt;                 // exclusive prefix over blocks
            cnt += (u32)(pv >> 48);
            fix += pv & 0xFFFFFFFFFFFFull;
        }
        c = (int)cnt;
        float deg = (float)fix * (1.0f / 4294967296.0f);
        dinv[i] = rsqrtf(deg + 1.0f);
    }
    int lane = t & 63, wv = t >> 6;
    int v = c;
    for (int off = 1; off < 64; off <<= 1) {
        int u = __shfl_up(v, off);
        if (lane >= off) v += u;
    }
    __shared__ int ws[4];
    if (lane == 63) ws[wv] = v;
    __syncthreads();
    if (t == 0) { int s = 0; for (int k = 0; k < 4; k++) { int tmp = ws[k]; ws[k] = s; s += tmp; } }
    __syncthreads();
    v += ws[wv];
    if (i < NODES) iscan[i] = v - c;              // block-local EXCLUSIVE scan
    if (t == 255) bsum[b] = v;
}

__global__ void scan2_kernel(const int* __restrict__ bsum, int* __restrict__ boff) {
    int t = threadIdx.x;
    int c = (t < SCANB) ? bsum[t] : 0;
    int lane = t & 63, wv = t >> 6;
    int v = c;
    for (int off = 1; off < 64; off <<= 1) {
        int u = __shfl_up(v, off);
        if (lane >= off) v += u;
    }
    __shared__ int ws[4];
    if (lane == 63) ws[wv] = v;
    __syncthreads();
    if (t == 0) { int s = 0; for (int k = 0; k < 4; k++) { int tmp = ws[k]; ws[k] = s; s += tmp; } }
    __syncthreads();
    v += ws[wv];
    if (t < SCANB) boff[t] = v - c;
}

__global__ void scan3_kernel(const int* __restrict__ iscan, const int* __restrict__ boff,
                             int* __restrict__ rowptr) {
    int b = blockIdx.x, t = threadIdx.x;
    int i = b * 256 + t;
    if (i > NODES) return;
    if (i == NODES) { rowptr[NODES] = EDGES; return; }
    rowptr[i] = boff[b] + iscan[i];
}

// ---------------- GEMM body ----------------
__device__ __forceinline__ void gemm_body(const u16* __restrict__ A,
                                          const u16* __restrict__ Bt,
                                          u16* __restrict__ C,
                                          int K, int bm, int bn,
                                          u16* As, u16* Bs) {
    const int tid  = threadIdx.x;
    const int wave = tid >> 6, lane = tid & 63;
    const int wm = wave >> 1, wn = wave & 1;
    const int quad = lane >> 4, l16 = lane & 15;
    const int sr = tid >> 2;
    const int sc = tid & 3;
    const int swz = (sc ^ ((sr >> 1) & 3)) * 8;
    const int rphys = (quad ^ ((l16 >> 1) & 3)) * 8;

    const u16* Ag = A + (size_t)(bm * 128 + sr) * K + sc * 8;
    const u16* Bg = Bt + (size_t)(bn * 128 + sr) * K + sc * 8;

    f32x4 acc[4][4];
#pragma unroll
    for (int i = 0; i < 4; i++)
#pragma unroll
        for (int j = 0; j < 4; j++) { f32x4 z = {0.f, 0.f, 0.f, 0.f}; acc[i][j] = z; }

    for (int k0 = 0; k0 < K; k0 += 32) {
        int4 av0 = *(const int4*)(Ag + k0);
        int4 av1 = *(const int4*)(Ag + (size_t)64 * K + k0);
        int4 bv0 = *(const int4*)(Bg + k0);
        int4 bv1 = *(const int4*)(Bg + (size_t)64 * K + k0);
        __syncthreads();
        *(int4*)(As + sr * 32 + swz)        = av0;
        *(int4*)(As + (sr + 64) * 32 + swz) = av1;
        *(int4*)(Bs + sr * 32 + swz)        = bv0;
        *(int4*)(Bs + (sr + 64) * 32 + swz) = bv1;
        __syncthreads();
        bf16x8 af[4], bfr[4];
#pragma unroll
        for (int i = 0; i < 4; i++)
            af[i] = *(const bf16x8*)(As + (wm * 64 + i * 16 + l16) * 32 + rphys);
#pragma unroll
        for (int j = 0; j < 4; j++)
            bfr[j] = *(const bf16x8*)(Bs + (wn * 64 + j * 16 + l16) * 32 + rphys);
#pragma unroll
        for (int i = 0; i < 4; i++)
#pragma unroll
            for (int j = 0; j < 4; j++)
                acc[i][j] = __builtin_amdgcn_mfma_f32_16x16x32_bf16(af[i], bfr[j], acc[i][j], 0, 0, 0);
    }

    const int crow0 = bm * 128 + wm * 64 + quad * 4;
    const int ccol0 = bn * 128 + wn * 64 + l16;
#pragma unroll
    for (int i = 0; i < 4; i++)
#pragma unroll
        for (int j = 0; j < 4; j++)
#pragma unroll
            for (int r = 0; r < 4; r++)
                C[(size_t)(crow0 + i * 16 + r) * HID + ccol0 + j * 16] = f2bf(acc[i][j][r]);
}

// ---------------- K2: GEMM1 + CSR fill via LDS counting sort ---------------------
// Fill blocks are XCD-pinned: graph = absolute blockIdx & 7, so all 32 writers of
// graph g's csr region land on one XCD and partial 64B lines merge in its L2
// before writeback (kills the ~8x write amplification seen in R8: WRITE 53 MB).
__global__ __launch_bounds__(256) void k2_kernel(
        const u16* __restrict__ A0, const u16* __restrict__ Wt1, u16* __restrict__ xw,
        const int* __restrict__ ei, const float* __restrict__ ew,
        const float* __restrict__ dinv, const int* __restrict__ rowptr,
        const u32* __restrict__ blockbase, int2* __restrict__ csr) {
    __shared__ __align__(16) char smem[NP_G * 4];   // 25000 B (>= 16384 for gemm)
    int b = blockIdx.x;
    if (b < K2_GEMM) {
        u16* As = (u16*)smem;
        u16* Bs = (u16*)(smem + 8192);
        gemm_body(A0, Wt1, xw, CIN, b >> 1, b & 1, As, Bs);
    } else {
        u32* cursor = (u32*)smem;                   // 6250 u32
        int g  = b & 7;                             // XCD-pinned graph
        int bb = (b - K2_GEMM) >> 3;                // slice 0..31
        const u32* bbase = blockbase + (size_t)(g * 32 + bb) * NP_G;
        const int* rp = rowptr + g * NP_G;
        for (int k = threadIdx.x; k < NP_G; k += 256)
            cursor[k] = (u32)rp[k] + bbase[k];
        __syncthreads();
        int ebase = g * EPG + bb * ESL;
#pragma unroll 4
        for (int k = threadIdx.x; k < ESL; k += 256) {
            int e = ebase + k;
            int s = ei[e], d = ei[EDGES + e];
            int il = d - g * NP_G;
            u32 pos = atomicAdd(&cursor[il], 1u);   // LDS atomic
            csr[pos] = make_int2(s, __float_as_int(dinv[s] * ew[e] * dinv[d]));
        }
    }
}

// plain GEMM (layers 2,3)
__global__ __launch_bounds__(256) void gemm_bt(const u16* __restrict__ A,
                                               const u16* __restrict__ Bt,
                                               u16* __restrict__ C, int K) {
    __shared__ u16 As[128 * 32];
    __shared__ u16 Bs[128 * 32];
    gemm_body(A, Bt, C, K, blockIdx.x, blockIdx.y, As, Bs);
}

// ---------------- aggregation: half-wave 16B gathers; SCORE fuses TopK scoring ----
template<bool SCORE>
__global__ void agg_kernel(const u16* __restrict__ xw, u16* __restrict__ xo,
                           const int* __restrict__ rowptr, const int2* __restrict__ csr,
                           const float* __restrict__ dinv, const float* __restrict__ bias,
                           const u16* __restrict__ xs1, const u16* __restrict__ xs2,
                           const float* __restrict__ pw, const float* __restrict__ invn,
                           float* __restrict__ score, u64* __restrict__ keys) {
    int wave = threadIdx.x >> 6;
    int lane = threadIdx.x & 63;
    int g  = blockIdx.x & 7;
    int nl = (blockIdx.x >> 3) * 4 + wave;
    if (nl >= NP_G) return;
    int w = g * NP_G + nl;
    int half = lane >> 5;
    int f8 = (lane & 31) * 8;
    size_t ro = (size_t)w * HID + f8;

    float accA[8], accB[8];
#pragma unroll
    for (int j = 0; j < 8; ++j) { accA[j] = 0.f; accB[j] = 0.f; }

    int p = rowptr[w], p1 = rowptr[w + 1];
    for (; p + 4 <= p1; p += 4) {
        int2 eA = csr[p + half];
        int2 eB = csr[p + 2 + half];
        float wA = __int_as_float(eA.y), wB = __int_as_float(eB.y);
        u16x8 vA = *(const u16x8*)(xw + (size_t)eA.x * HID + f8);
        u16x8 vB = *(const u16x8*)(xw + (size_t)eB.x * HID + f8);
#pragma unroll
        for (int j = 0; j < 8; ++j) {
            accA[j] += wA * bf2f(vA[j]);
            accB[j] += wB * bf2f(vB[j]);
        }
    }
    for (; p < p1; p += 2) {
        int idx = p + half;
        bool valid = idx < p1;
        int2 eA = csr[valid ? idx : p];
        float wA = valid ? __int_as_float(eA.y) : 0.f;
        u16x8 vA = *(const u16x8*)(xw + (size_t)eA.x * HID + f8);
#pragma unroll
        for (int j = 0; j < 8; ++j) accA[j] += wA * bf2f(vA[j]);
    }

#pragma unroll
    for (int j = 0; j < 8; ++j) {
        accA[j] += accB[j];
        accA[j] += __shfl(accA[j], lane ^ 32, 64);
    }

    float di = dinv[w], sw = di * di;
    u16x8 sv = *(const u16x8*)(xw + ro);
    float bb[8];
    {
        float4 t0 = *(const float4*)(bias + f8);
        float4 t1 = *(const float4*)(bias + f8 + 4);
        bb[0] = t0.x; bb[1] = t0.y; bb[2] = t0.z; bb[3] = t0.w;
        bb[4] = t1.x; bb[5] = t1.y; bb[6] = t1.z; bb[7] = t1.w;
    }
    u16x8 o;
    float ov[8];
#pragma unroll
    for (int j = 0; j < 8; ++j) {
        float v = fmaxf(accA[j] + sw * bf2f(sv[j]) + bb[j], 0.f);
        o[j] = f2bf(v);
        ov[j] = bf2f(o[j]);               // post-rounding value (matches stored x3)
    }
    if (half == 0) *(u16x8*)(xo + ro) = o;

    if (SCORE) {
        u16x8 v1 = *(const u16x8*)(xs1 + ro);
        u16x8 v2 = *(const u16x8*)(xs2 + ro);
        float acc = 0.f;
#pragma unroll
        for (int j = 0; j < 8; ++j) {
            acc += bf2f(v1[j]) * pw[f8 + j];
            acc += bf2f(v2[j]) * pw[256 + f8 + j];
            acc += ov[j]       * pw[512 + f8 + j];
        }
#pragma unroll
        for (int off = 1; off < 32; off <<= 1) acc += __shfl_xor(acc, off, 64);
        if (lane == 0) {
            float s = acc * invn[0];
            float sc = 1.f / (1.f + __expf(-s));
            score[w] = sc;
            keys[w] = ((u64)__float_as_uint(sc) << 13) | (unsigned int)(NP_G - 1 - nl);
        }
    }
}

// ---------------- top-K radix select + stable compaction, one block per graph ----
__global__ __launch_bounds__(1024) void selcomp_kernel(
        const u64* __restrict__ keys, const float* __restrict__ score,
        int* __restrict__ selidx, float* __restrict__ selscr) {
    __shared__ u64 kk[NP_G];          // 50 KB
    __shared__ unsigned int hist[4][256];
    __shared__ unsigned int sfx[257];
    __shared__ u64 spref;
    __shared__ unsigned int swant;
    int g = blockIdx.x, t = threadIdx.x;
    const u64* kg = keys + (size_t)g * NP_G;
    for (int i = t; i < NP_G; i += 1024) kk[i] = kg[i];
    if (t == 0) { spref = 0ull; swant = KKEEP; }
    const int wgrp = (t >> 8) & 3;
    u64 mask = 0ull;
    __syncthreads();
    for (int shift = 40; shift >= 0; shift -= 8) {
        if (t < 256) { hist[0][t] = 0; hist[1][t] = 0; hist[2][t] = 0; hist[3][t] = 0; }
        __syncthreads();
        u64 pref = spref;
        for (int i = t; i < NP_G; i += 1024) {
            u64 key = kk[i];
            if ((key & mask) == pref)
                atomicAdd(&hist[wgrp][(unsigned int)(key >> shift) & 255u], 1u);
        }
        __syncthreads();
        if (t < 256) sfx[t] = hist[0][t] + hist[1][t] + hist[2][t] + hist[3][t];
        if (t == 0) sfx[256] = 0;
        __syncthreads();
        for (int off = 1; off < 256; off <<= 1) {
            unsigned int v = 0;
            if (t < 256 && t + off < 256) v = sfx[t + off];
            __syncthreads();
            if (t < 256 && t + off < 256) sfx[t] += v;
            __syncthreads();
        }
        unsigned int want = swant;
        __syncthreads();
        if (t < 256) {
            unsigned int s0 = sfx[t], s1 = sfx[t + 1];
            if (s0 >= want && s1 < want) {
                spref = pref | ((u64)t << shift);
                swant = want - s1;
            }
        }
        __syncthreads();
        mask |= (255ull << shift);
    }
    u64 kth = spref;
    int lane = t & 63, wv = t >> 6;
    __shared__ int wsum[16];
    __shared__ int cbase;
    if (t == 0) cbase = 0;
    __syncthreads();
    for (int k = 0; k < (NP_G + 1023) / 1024; ++k) {
        int i = k * 1024 + t;
        bool sel = (i < NP_G) && (kk[i] >= kth);
        int n = g * NP_G + i;
        u64 bal = __ballot(sel);
        int prefix = __popcll(bal & ((1ull << lane) - 1ull));
        if (lane == 0) wsum[wv] = __popcll(bal);
        __syncthreads();
        if (t == 0) {
            int s = cbase;
            for (int j = 0; j < 16; ++j) { int tmp = wsum[j]; wsum[j] = s; s += tmp; }
            cbase = s;
        }
        __syncthreads();
        if (sel) {
            int pos = wsum[wv] + prefix;
            selidx[g * KKEEP + pos] = n;
            selscr[g * KKEEP + pos] = score[n];
        }
        __syncthreads();
    }
}

// ---------------- readout: branch-free gather over compacted list ----------------
__global__ __launch_bounds__(256) void readout_kernel(
        const u16* __restrict__ x1, const u16* __restrict__ x2,
        const u16* __restrict__ x3,
        const int* __restrict__ selidx, const float* __restrict__ selscr,
        float* __restrict__ sumbuf, int* __restrict__ maxbuf) {
    int g = blockIdx.x, tpart = blockIdx.y, c = blockIdx.z;
    int fcol = threadIdx.x;
    const u16* xt = (tpart == 0) ? x1 : ((tpart == 1) ? x2 : x3);
    __shared__ int   sidx[RCHUNK];
    __shared__ float sscr[RCHUNK];
    int base = g * KKEEP + c * RCHUNK;
    if (fcol < RCHUNK) { sidx[fcol] = selidx[base + fcol]; sscr[fcol] = selscr[base + fcol]; }
    __syncthreads();
    float sum = 0.f, mx = 0.f;
#pragma unroll 1
    for (int j = 0; j < RCHUNK; j += 4) {
        int n0 = sidx[j], n1 = sidx[j + 1], n2 = sidx[j + 2], n3 = sidx[j + 3];
        float s0 = sscr[j], s1 = sscr[j + 1], s2 = sscr[j + 2], s3 = sscr[j + 3];
        float v0 = bf2f(xt[(size_t)n0 * HID + fcol]) * s0;
        float v1 = bf2f(xt[(size_t)n1 * HID + fcol]) * s1;
        float v2 = bf2f(xt[(size_t)n2 * HID + fcol]) * s2;
        float v3 = bf2f(xt[(size_t)n3 * HID + fcol]) * s3;
        sum += v0 + v1 + v2 + v3;
        mx = fmaxf(mx, fmaxf(fmaxf(v0, v1), fmaxf(v2, v3)));
    }
    int o = (g * 3 + tpart) * HID + fcol;
    atomicAdd(&sumbuf[o], sum);
    atomicMax(&maxbuf[o], __float_as_int(mx));
}

// ---------------- MLP layer 1, k-split ----------------
__global__ __launch_bounds__(256) void mlp1_kernel(const float* __restrict__ sumbuf,
                                                   const int* __restrict__ maxbuf,
                                                   const float* __restrict__ lw1,
                                                   float* __restrict__ h1acc) {
    int g = blockIdx.x, ch = blockIdx.y, t = threadIdx.x;
    __shared__ float r[MLPCK];
    int k0 = ch * MLPCK;
    if (t < MLPCK) {
        int i = k0 + t;
        r[t] = (i < 768) ? sumbuf[g * 768 + i] * (1.f / 5000.f)
                         : __int_as_float(maxbuf[g * 768 + (i - 768)]);
    }
    __syncthreads();
    float a0 = 0.f, a1 = 0.f, a2 = 0.f, a3 = 0.f;
#pragma unroll
    for (int i = 0; i < MLPCK; i += 4) {
        a0 += r[i]     * lw1[(size_t)(k0 + i)     * 256 + t];
        a1 += r[i + 1] * lw1[(size_t)(k0 + i + 1) * 256 + t];
        a2 += r[i + 2] * lw1[(size_t)(k0 + i + 2) * 256 + t];
        a3 += r[i + 3] * lw1[(size_t)(k0 + i + 3) * 256 + t];
    }
    atomicAdd(&h1acc[g * 256 + t], (a0 + a1) + (a2 + a3));
}

// ---------------- MLP layers 2+3 ----------------
__global__ __launch_bounds__(256) void mlp2_kernel(const float* __restrict__ h1acc,
                                                   const float* __restrict__ lb1,
                                                   const float* __restrict__ lw2,
                                                   const float* __restrict__ lb2,
                                                   const float* __restrict__ lw3,
                                                   const float* __restrict__ lb3,
                                                   float* __restrict__ out) {
    __shared__ float h1[256];
    __shared__ float part[256];
    __shared__ float h2[128];
    int g = blockIdx.x, t = threadIdx.x;
    h1[t] = fmaxf(h1acc[g * 256 + t] + lb1[t], 0.f);
    __syncthreads();
    int col = t & 127, half = t >> 7;
    float a = 0.f;
#pragma unroll
    for (int i = 0; i < 128; i += 4) {
        int k = half * 128 + i;
        a += h1[k]     * lw2[k * 128 + col]
           + h1[k + 1] * lw2[(k + 1) * 128 + col]
           + h1[k + 2] * lw2[(k + 2) * 128 + col]
           + h1[k + 3] * lw2[(k + 3) * 128 + col];
    }
    part[t] = a;
    __syncthreads();
    if (t < 128) h2[t] = fmaxf(part[t] + part[t + 128] + lb2[t], 0.f);
    __syncthreads();
    if (t < 3) {
        float a3 = lb3[t];
        for (int i = 0; i < 128; ++i) a3 += h2[i] * lw3[i * 3 + t];
        out[g * 3 + t] = a3;
    }
}

extern "C" void kernel_launch(void* const* d_in, const int* in_sizes, int n_in,
                              void* d_out, int out_size, void* d_ws, size_t ws_size,
                              hipStream_t stream) {
    const float* x   = (const float*)d_in[0];
    const int*   ei  = (const int*)d_in[1];
    const float* ew  = (const float*)d_in[2];
    const float* W1  = (const float*)d_in[4];
    const float* b1  = (const float*)d_in[5];
    const float* W2  = (const float*)d_in[6];
    const float* b2  = (const float*)d_in[7];
    const float* pw  = (const float*)d_in[8];
    const float* lw1 = (const float*)d_in[9];
    const float* lb1 = (const float*)d_in[10];
    const float* lw2 = (const float*)d_in[11];
    const float* lb2 = (const float*)d_in[12];
    const float* lw3 = (const float*)d_in[13];
    const float* lb3 = (const float*)d_in[14];
    float* out = (float*)d_out;

    char* p = (char*)d_ws;
    auto alloc = [&](size_t bytes) -> char* {
        char* r = p;
        p += (bytes + 255) & ~(size_t)255;
        return r;
    };
    u16* A0  = (u16*)alloc((size_t)MPAD * CIN * 2);   // x bf16; x1/x2 alias after GEMM1
    u16* x3  = (u16*)alloc((size_t)MPAD * HID * 2);
    u16* xw  = (u16*)alloc((size_t)MPAD * HID * 2);
    u16* Wt1 = (u16*)alloc((size_t)HID * CIN * 2);
    u16* Wt2 = (u16*)alloc((size_t)HID * HID * 2);
    int2*  csr    = (int2*)alloc((size_t)EDGES * 8);
    u64*   partial   = (u64*)alloc((size_t)256 * NP_G * 8);   // 12.8 MB
    u32*   blockbase = (u32*)alloc((size_t)256 * NP_G * 4);   // 6.4 MB
    int*   rowptr = (int*)alloc((size_t)(NODES + 1) * 4);
    int*   iscan  = (int*)alloc((size_t)NODES * 4);
    int*   bsum   = (int*)alloc((size_t)SCANB * 4);
    int*   boff   = (int*)alloc((size_t)SCANB * 4);
    u64*   keys   = (u64*)alloc((size_t)NODES * 8);
    float* score  = (float*)alloc((size_t)NODES * 4);
    float* dinv   = (float*)alloc((size_t)NODES * 4);
    int*   selidx = (int*)alloc((size_t)NGRAPH * KKEEP * 4);
    float* selscr = (float*)alloc((size_t)NGRAPH * KKEEP * 4);
    float* invn   = (float*)alloc(256);
    char* zbase = p;                                  // everything below is zero-init
    float* sumbuf = (float*)alloc(6144 * 4);
    int*   maxbuf = (int*)alloc(6144 * 4);
    float* h1acc  = (float*)alloc((size_t)NGRAPH * 256 * 4);
    size_t zbytes = (size_t)(p - zbase);

    u16* x1 = A0;                         // reuse A0 after GEMM1 consumed it
    u16* x2 = A0 + (size_t)MPAD * HID;

    hipMemsetAsync(zbase, 0, zbytes, stream);

    k1_kernel<<<K1_TOTAL, 256, 0, stream>>>(ei, ew, partial, x, A0,
                                            W1, W2, pw, Wt1, Wt2, invn);
    scan1_kernel<<<SCANB, 256, 0, stream>>>(partial, blockbase, iscan, bsum, dinv);
    scan2_kernel<<<1, 256, 0, stream>>>(bsum, boff);
    scan3_kernel<<<SCANB + 1, 256, 0, stream>>>(iscan, boff, rowptr);
    k2_kernel<<<K2_TOTAL, 256, 0, stream>>>(A0, Wt1, xw, ei, ew, dinv, rowptr,
                                            blockbase, csr);

    dim3 gg(MPAD / 128, HID / 128);
    int aggBlocks = 8 * ((NP_G + 3) / 4);   // graph = blockIdx & 7 (XCD pinning)

    agg_kernel<false><<<aggBlocks, 256, 0, stream>>>(xw, x1, rowptr, csr, dinv, b1,
                                                     nullptr, nullptr, nullptr, nullptr,
                                                     nullptr, nullptr);
    gemm_bt<<<gg, 256, 0, stream>>>(x1, Wt2, xw, HID);
    agg_kernel<false><<<aggBlocks, 256, 0, stream>>>(xw, x2, rowptr, csr, dinv, b2,
                                                     nullptr, nullptr, nullptr, nullptr,
                                                     nullptr, nullptr);
    gemm_bt<<<gg, 256, 0, stream>>>(x2, Wt2, xw, HID);
    agg_kernel<true><<<aggBlocks, 256, 0, stream>>>(xw, x3, rowptr, csr, dinv, b2,
                                                    x1, x2, pw, invn, score, keys);

    selcomp_kernel<<<NGRAPH, 1024, 0, stream>>>(keys, score, selidx, selscr);
    readout_kernel<<<dim3(NGRAPH, 3, KKEEP / RCHUNK), 256, 0, stream>>>(
        x1, x2, x3, selidx, selscr, sumbuf, maxbuf);
    mlp1_kernel<<<dim3(NGRAPH, MLPCH), 256, 0, stream>>>(sumbuf, maxbuf, lw1, h1acc);
    mlp2_kernel<<<NGRAPH, 256, 0, stream>>>(h1acc, lb1, lw2, lb2, lw3, lb3, out);
}